// Round 2
// baseline (2869.565 us; speedup 1.0000x reference)
//
#include <hip/hip_runtime.h>
#include <hip/hip_bf16.h>

// MSCN fused pipeline, MI355X gfx950. Round 1: MFMA kv GEMM + latency-fixed attn.
// B=64, C=512, H=W=7 (N=49), HY=WY=28 (N1=784), heads=8, d=64, SCALE=0.125
// kc1 = 784//2 = 392, kc2 = 784//3 = 261

typedef __hip_bfloat16 bf16;
using bf16x8 = __attribute__((ext_vector_type(8))) short;  // 8 bf16 = 4 VGPRs
using f32x4 = __attribute__((ext_vector_type(4))) float;

#define DI __device__ __forceinline__

DI float bfu(unsigned short u) { return __uint_as_float(((unsigned int)u) << 16); }
DI float blo(unsigned int u) { return __uint_as_float(u << 16); }
DI float bhi(unsigned int u) { return __uint_as_float(u & 0xFFFF0000u); }

DI void unp8(uint4 u, float* f) {
  f[0] = blo(u.x); f[1] = bhi(u.x); f[2] = blo(u.y); f[3] = bhi(u.y);
  f[4] = blo(u.z); f[5] = bhi(u.z); f[6] = blo(u.w); f[7] = bhi(u.w);
}

DI float wave_max_f(float v) {
#pragma unroll
  for (int off = 32; off; off >>= 1) v = fmaxf(v, __shfl_xor(v, off, 64));
  return v;
}
DI float wave_sum_f(float v) {
#pragma unroll
  for (int off = 32; off; off >>= 1) v += __shfl_xor(v, off, 64);
  return v;
}
// monotone float->uint key: ascending key order == ascending float order
DI unsigned int fkey(float f) {
  unsigned int u = __float_as_uint(f);
  return (u & 0x80000000u) ? ~u : (u | 0x80000000u);
}

// kth-largest threshold via bitwise bisection; counts via ballot+popcount
// (scalar pipe, no shuffle chains). Early exit when count==k is exact:
// selection {key >= thr} is then precisely the top-k set (ties fall through
// to full 32-bit bisection, matching reference >= kth-value semantics).
DI unsigned int bisect_topk(const unsigned int key[13], int kth) {
  unsigned int thr = 0u;
  for (int bit = 31; bit >= 0; --bit) {
    unsigned int cand = thr | (1u << bit);
    int c = 0;
#pragma unroll
    for (int i = 0; i < 13; ++i) c += __popcll(__ballot(key[i] >= cand));
    if (c >= kth) {
      thr = cand;
      if (c == kth) break;
    }
  }
  return thr;
}

// ---------------------------------------------------------------- pool
__global__ __launch_bounds__(256) void pool_kernel(const float* __restrict__ y,
                                                   bf16* __restrict__ pooled) {
  const int plane = blockIdx.x;  // b*512 + c
  const float* src = y + (size_t)plane * 784;
  __shared__ float p[784];
  for (int i = threadIdx.x; i < 784; i += 256) p[i] = src[i];
  __syncthreads();
  for (int i = threadIdx.x; i < 784; i += 256) {
    int r = i / 28, c = i - (i / 28) * 28;
    float acc = 0.f;
#pragma unroll
    for (int di = -3; di <= 3; ++di) {
      int rr = r + di;
      if (rr < 0 || rr >= 28) continue;
#pragma unroll
      for (int dj = -3; dj <= 3; ++dj) {
        int cc = c + dj;
        if (cc < 0 || cc >= 28) continue;
        const int adi = di < 0 ? -di : di, adj = dj < 0 ? -dj : dj;
        const float w = 1.0f / 49.0f + ((adi <= 2 && adj <= 2) ? 1.0f / 25.0f : 0.0f) +
                        ((adi <= 1 && adj <= 1) ? 1.0f / 9.0f : 0.0f);
        acc += w * p[rr * 28 + cc];
      }
    }
    pooled[(size_t)plane * 784 + i] = __float2bfloat16(acc);
  }
}

// ---------------------------------------------------------------- layernorm + transpose
__global__ __launch_bounds__(256) void ln_kernel(const bf16* __restrict__ pooled,
                                                 const float* __restrict__ gamma,
                                                 const float* __restrict__ beta,
                                                 bf16* __restrict__ yln) {
  const int b = blockIdx.y;
  const int n0 = blockIdx.x * 16;
  __shared__ float tile[16][520];
  __shared__ float smu[16], srs[16];
  const bf16* src = pooled + (size_t)b * 512 * 784;
  for (int idx = threadIdx.x; idx < 512 * 16; idx += 256) {
    int c = idx >> 4, pp = idx & 15;
    tile[pp][c] = __bfloat162float(src[(size_t)c * 784 + n0 + pp]);
  }
  __syncthreads();
  int pp = threadIdx.x >> 4, l = threadIdx.x & 15;
  float s = 0.f, s2 = 0.f;
  for (int c = l; c < 512; c += 16) {
    float v = tile[pp][c];
    s += v;
    s2 += v * v;
  }
#pragma unroll
  for (int off = 8; off; off >>= 1) {
    s += __shfl_xor(s, off, 64);
    s2 += __shfl_xor(s2, off, 64);
  }
  if (l == 0) {
    float mu = s * (1.f / 512.f);
    float var = s2 * (1.f / 512.f) - mu * mu;
    smu[pp] = mu;
    srs[pp] = rsqrtf(var + 1e-5f);
  }
  __syncthreads();
  bf16* dst = yln + ((size_t)b * 784 + n0) * 512;
  for (int idx = threadIdx.x; idx < 512 * 16; idx += 256) {
    int q = idx >> 9, c = idx & 511;
    float v = (tile[q][c] - smu[q]) * srs[q] * gamma[c] + beta[c];
    dst[(size_t)q * 512 + c] = __float2bfloat16(v);
  }
}

// ---------------------------------------------------------------- x transpose
__global__ __launch_bounds__(256) void xst_kernel(const float* __restrict__ x,
                                                  float* __restrict__ xsT) {
  int idx = blockIdx.x * 256 + threadIdx.x;
  int c = idx & 511;
  int rem = idx >> 9;
  int r = rem % 49, b = rem / 49;
  xsT[idx] = x[((size_t)b * 512 + c) * 49 + r];
}

// ---------------------------------------------------------------- Wkv transpose -> bf16 [1024][512]
__global__ __launch_bounds__(256) void wkvt_kernel(const float* __restrict__ Wkv,
                                                   bf16* __restrict__ WkvT) {
  __shared__ float t[32][33];
  const int n0 = blockIdx.x * 32, k0 = blockIdx.y * 32;
  for (int i = threadIdx.x; i < 1024; i += 256) {
    int kr = i >> 5, nc = i & 31;
    t[kr][nc] = Wkv[(size_t)(k0 + kr) * 1024 + n0 + nc];
  }
  __syncthreads();
  for (int i = threadIdx.x; i < 1024; i += 256) {
    int nr = i >> 5, kc = i & 31;
    WkvT[(size_t)(n0 + nr) * 512 + k0 + kc] = __float2bfloat16(t[kc][nr]);
  }
}

// ---------------------------------------------------------------- f32 GEMM (q, proj)
DI float4 ldg4(const float* p) { return *reinterpret_cast<const float4*>(p); }

// MODE 0: Q  -> o0 f32 [B,8,49,64]
// MODE 2: proj -> o0 f32 [B,512,49] (transposed write) + bias
template <int BM, int BN, int BK, int TM, int TN, int MODE>
__global__ __launch_bounds__(256) void gemm_k(const float* __restrict__ A, const float* __restrict__ B,
                                              int M, int N, int K, float* __restrict__ o0,
                                              const float* __restrict__ bias) {
  __shared__ float As[BK][BM + 4];
  __shared__ float Bs[BK][BN + 4];
  const int tid = threadIdx.x;
  const int tx = tid & 15, ty = tid >> 4;
  const int m0 = blockIdx.y * BM, n0 = blockIdx.x * BN;
  float acc[TM][TN];
#pragma unroll
  for (int i = 0; i < TM; ++i)
#pragma unroll
    for (int j = 0; j < TN; ++j) acc[i][j] = 0.f;

  for (int k0 = 0; k0 < K; k0 += BK) {
#pragma unroll
    for (int t = 0; t < (BM * BK) / 1024; ++t) {
      int lin = tid * 4 + t * 1024;
      int mm = lin / BK, kk = lin % BK;
      float4 v = ldg4(A + (size_t)(m0 + mm) * K + k0 + kk);
      As[kk + 0][mm] = v.x;
      As[kk + 1][mm] = v.y;
      As[kk + 2][mm] = v.z;
      As[kk + 3][mm] = v.w;
    }
#pragma unroll
    for (int t = 0; t < (BN * BK) / 1024; ++t) {
      int lin = tid * 4 + t * 1024;
      int kk = lin / BN, nn = lin % BN;
      *reinterpret_cast<float4*>(&Bs[kk][nn]) = ldg4(B + (size_t)(k0 + kk) * N + n0 + nn);
    }
    __syncthreads();
#pragma unroll
    for (int kk = 0; kk < BK; ++kk) {
      float a[TM], bb[TN];
#pragma unroll
      for (int i = 0; i < TM; i += 4)
        *reinterpret_cast<float4*>(&a[i]) = *reinterpret_cast<const float4*>(&As[kk][ty * TM + i]);
#pragma unroll
      for (int j = 0; j < TN; j += 4)
        *reinterpret_cast<float4*>(&bb[j]) = *reinterpret_cast<const float4*>(&Bs[kk][tx * TN + j]);
#pragma unroll
      for (int i = 0; i < TM; ++i)
#pragma unroll
        for (int j = 0; j < TN; ++j) acc[i][j] = fmaf(a[i], bb[j], acc[i][j]);
    }
    __syncthreads();
  }
#pragma unroll
  for (int i = 0; i < TM; ++i) {
    int m = m0 + ty * TM + i;
#pragma unroll
    for (int j = 0; j < TN; ++j) {
      int n = n0 + tx * TN + j;
      float v = acc[i][j];
      if constexpr (MODE == 0) {
        int b = m / 49, r = m - (m / 49) * 49;
        o0[(((size_t)b * 8 + (n >> 6)) * 49 + r) * 64 + (n & 63)] = v;
      } else {
        int b = m / 49, r = m - (m / 49) * 49;
        o0[((size_t)b * 512 + n) * 49 + r] = v + bias[n];
      }
    }
  }
}

// ---------------------------------------------------------------- kv MFMA GEMM
// A = yln bf16 [50176][512], Bt = WkvT bf16 [1024][512]; out K/V bf16 [B,8,784,64]
#define GLD_LDS16(g, l)                                                              \
  __builtin_amdgcn_global_load_lds((const __attribute__((address_space(1))) unsigned int*)(g), \
                                   (__attribute__((address_space(3))) unsigned int*)(l), 16, 0, 0)

__global__ __launch_bounds__(256) void kv_mfma(const bf16* __restrict__ A,
                                               const bf16* __restrict__ Bt,
                                               bf16* __restrict__ Kb, bf16* __restrict__ Vb) {
  __shared__ __align__(16) bf16 As[128 * 32];
  __shared__ __align__(16) bf16 Bs[128 * 32];
  const int tid = threadIdx.x;
  const int lane = tid & 63;
  const int w = tid >> 6, wr = w >> 1, wc = w & 1;
  const int m0 = blockIdx.y * 128, n0 = blockIdx.x * 128;

  f32x4 acc[4][4];
#pragma unroll
  for (int m = 0; m < 4; ++m)
#pragma unroll
    for (int n = 0; n < 4; ++n) acc[m][n] = f32x4{0.f, 0.f, 0.f, 0.f};

  const int s0 = tid, s1 = tid + 256;  // 16B segments; seg s: row=s>>2, koff=(s&3)*8
  const bf16* Ag0 = A + (size_t)(m0 + (s0 >> 2)) * 512 + (s0 & 3) * 8;
  const bf16* Ag1 = A + (size_t)(m0 + (s1 >> 2)) * 512 + (s1 & 3) * 8;
  const bf16* Bg0 = Bt + (size_t)(n0 + (s0 >> 2)) * 512 + (s0 & 3) * 8;
  const bf16* Bg1 = Bt + (size_t)(n0 + (s1 >> 2)) * 512 + (s1 & 3) * 8;
  bf16* Al0 = As + s0 * 8;
  bf16* Al1 = As + s1 * 8;
  bf16* Bl0 = Bs + s0 * 8;
  bf16* Bl1 = Bs + s1 * 8;

  const int fr = lane & 15;        // fragment row/col within 16
  const int ko = (lane >> 4) * 8;  // k offset within 32

  for (int k0 = 0; k0 < 512; k0 += 32) {
    GLD_LDS16(Ag0 + k0, Al0);
    GLD_LDS16(Ag1 + k0, Al1);
    GLD_LDS16(Bg0 + k0, Bl0);
    GLD_LDS16(Bg1 + k0, Bl1);
    __syncthreads();  // vmcnt drained before barrier
    bf16x8 af[4], bfr[4];
#pragma unroll
    for (int m = 0; m < 4; ++m)
      af[m] = *reinterpret_cast<const bf16x8*>(As + (wr * 64 + m * 16 + fr) * 32 + ko);
#pragma unroll
    for (int n = 0; n < 4; ++n)
      bfr[n] = *reinterpret_cast<const bf16x8*>(Bs + (wc * 64 + n * 16 + fr) * 32 + ko);
#pragma unroll
    for (int m = 0; m < 4; ++m)
#pragma unroll
      for (int n = 0; n < 4; ++n)
        acc[m][n] = __builtin_amdgcn_mfma_f32_16x16x32_bf16(af[m], bfr[n], acc[m][n], 0, 0, 0);
    __syncthreads();
  }

  const int rh = lane >> 4;
#pragma unroll
  for (int m = 0; m < 4; ++m) {
#pragma unroll
    for (int n = 0; n < 4; ++n) {
      int col = n0 + wc * 64 + n * 16 + fr;
      bf16* dst = (col & 512) ? Vb : Kb;
      const size_t cbase = ((size_t)((col >> 6) & 7)) * (784 * 64) + (col & 63);
#pragma unroll
      for (int r = 0; r < 4; ++r) {
        int row = m0 + wr * 64 + m * 16 + rh * 4 + r;
        int b = row / 784, n1 = row - (row / 784) * 784;
        dst[((size_t)b * 8) * (784 * 64) + cbase + (size_t)n1 * 64] = __float2bfloat16(acc[m][n][r]);
      }
    }
  }
}

// ---------------------------------------------------------------- attention
// one block = (b,h, chunk of 7 q-rows).
__global__ __launch_bounds__(256) void attn_kernel(const float* __restrict__ Q,
                                                   const bf16* __restrict__ K,
                                                   const bf16* __restrict__ V,
                                                   const float* __restrict__ aw1p,
                                                   const float* __restrict__ aw2p,
                                                   float* __restrict__ aout) {
  const int bh = blockIdx.x / 7;
  const int chunk = blockIdx.x - bh * 7;
  const int b = bh >> 3, h = bh & 7;
  const int r0 = chunk * 7;
  const int tid = threadIdx.x;
  const int lane = tid & 63, w = tid >> 6;
  __shared__ __align__(16) bf16 sQ[7][64];
  __shared__ __align__(16) float sA[7][784];

  const float* Qp = Q + ((size_t)bh * 49 + r0) * 64;
  for (int i = tid; i < 448; i += 256) sQ[i >> 6][i & 63] = __float2bfloat16(Qp[i]);
  __syncthreads();

  // ---- QK^T: one thread per K-row pair, all 7 q-rows (K row read once/block)
  const bf16* Kp = K + (size_t)bh * (784 * 64);
  for (int mp = tid; mp < 392; mp += 256) {
    const int m0 = mp * 2;
    const uint4* kp = reinterpret_cast<const uint4*>(Kp + (size_t)m0 * 64);
    float acc0[7] = {0, 0, 0, 0, 0, 0, 0}, acc1[7] = {0, 0, 0, 0, 0, 0, 0};
#pragma unroll
    for (int jj = 0; jj < 8; ++jj) {
      uint4 ka = kp[jj], kb = kp[jj + 8];
      float k0f[8], k1f[8], qf[8];
      unp8(ka, k0f);
      unp8(kb, k1f);
#pragma unroll
      for (int r = 0; r < 7; ++r) {
        uint4 qv = *reinterpret_cast<const uint4*>(&sQ[r][jj * 8]);
        unp8(qv, qf);
#pragma unroll
        for (int j = 0; j < 8; ++j) {
          acc0[r] = fmaf(qf[j], k0f[j], acc0[r]);
          acc1[r] = fmaf(qf[j], k1f[j], acc1[r]);
        }
      }
    }
#pragma unroll
    for (int r = 0; r < 7; ++r) {
      sA[r][m0] = acc0[r] * 0.125f;
      sA[r][m0 + 1] = acc1[r] * 0.125f;
    }
  }
  __syncthreads();

  // ---- top-k + softmax weights (per row, one wave)
  const float aw1 = aw1p[0], aw2 = aw2p[0];
  for (int r = w; r < 7; r += 4) {
    float v[13];
    unsigned int key[13];
#pragma unroll
    for (int i = 0; i < 13; ++i) {
      int m = lane + i * 64;
      v[i] = (m < 784) ? sA[r][m] : -INFINITY;
      key[i] = fkey(v[i]);
    }
    float mx = v[0];
#pragma unroll
    for (int i = 1; i < 13; ++i) mx = fmaxf(mx, v[i]);
    mx = wave_max_f(mx);
    unsigned int thr1 = bisect_topk(key, 392);
    unsigned int thr2 = bisect_topk(key, 261);
    float e[13];
    float z1 = 0.f, z2 = 0.f;
#pragma unroll
    for (int i = 0; i < 13; ++i) {
      e[i] = __expf(v[i] - mx);  // pads: exp(-inf)=0
      if (key[i] >= thr1) z1 += e[i];
      if (key[i] >= thr2) z2 += e[i];
    }
    z1 = wave_sum_f(z1);
    z2 = wave_sum_f(z2);
    const float a1 = aw1 / z1, a2 = aw2 / z2;
#pragma unroll
    for (int i = 0; i < 13; ++i) {
      int m = lane + i * 64;
      if (m < 784) {
        float wgt = e[i] * (((key[i] >= thr1) ? a1 : 0.f) + ((key[i] >= thr2) ? a2 : 0.f));
        sA[r][m] = wgt;
      }
    }
  }
  __syncthreads();

  // ---- PV: wave w owns m in [w*196, w*196+196); lane = (msub, dg)
  const bf16* Vp = V + (size_t)bh * (784 * 64);
  const int msub = lane >> 3, dg = lane & 7;
  float acc[7][8];
#pragma unroll
  for (int r = 0; r < 7; ++r)
#pragma unroll
    for (int j = 0; j < 8; ++j) acc[r][j] = 0.f;
#pragma unroll 2
  for (int i = 0; i < 25; ++i) {
    int midx = i * 8 + msub;
    if (midx < 196) {
      int m = w * 196 + midx;
      uint4 vv = *reinterpret_cast<const uint4*>(Vp + (size_t)m * 64 + dg * 8);
      float vf[8];
      unp8(vv, vf);
#pragma unroll
      for (int r = 0; r < 7; ++r) {
        float wt = sA[r][m];
#pragma unroll
        for (int j = 0; j < 8; ++j) acc[r][j] = fmaf(wt, vf[j], acc[r][j]);
      }
    }
  }
  // reduce across msub groups (lane bits 3..5)
#pragma unroll
  for (int r = 0; r < 7; ++r)
#pragma unroll
    for (int j = 0; j < 8; ++j) {
      float s = acc[r][j];
      s += __shfl_xor(s, 8, 64);
      s += __shfl_xor(s, 16, 64);
      s += __shfl_xor(s, 32, 64);
      acc[r][j] = s;
    }
  __syncthreads();  // sA reads done; reuse as partial buffer [w][7][64]
  float* part = &sA[0][0];
  if (msub == 0) {
#pragma unroll
    for (int r = 0; r < 7; ++r) {
      *reinterpret_cast<float4*>(part + (w * 7 + r) * 64 + dg * 8) =
          make_float4(acc[r][0], acc[r][1], acc[r][2], acc[r][3]);
      *reinterpret_cast<float4*>(part + (w * 7 + r) * 64 + dg * 8 + 4) =
          make_float4(acc[r][4], acc[r][5], acc[r][6], acc[r][7]);
    }
  }
  __syncthreads();
  for (int idx = tid; idx < 448; idx += 256) {
    int r = idx >> 6, d = idx & 63;
    float s = part[r * 64 + d] + part[448 + r * 64 + d] + part[896 + r * 64 + d] +
              part[1344 + r * 64 + d];
    aout[((size_t)(b * 49 + r0 + r)) * 512 + h * 64 + d] = s;
  }
}

// ---------------------------------------------------------------- launch
extern "C" void kernel_launch(void* const* d_in, const int* in_sizes, int n_in, void* d_out,
                              int out_size, void* d_ws, size_t ws_size, hipStream_t stream) {
  const float* x = (const float*)d_in[0];
  const float* y = (const float*)d_in[1];
  const float* Wq = (const float*)d_in[2];
  const float* Wkv = (const float*)d_in[3];
  const float* Wproj = (const float*)d_in[4];
  const float* bproj = (const float*)d_in[5];
  const float* gamma = (const float*)d_in[6];
  const float* beta = (const float*)d_in[7];
  const float* aw1 = (const float*)d_in[8];
  const float* aw2 = (const float*)d_in[9];
  float* out = (float*)d_out;

  char* w = (char*)d_ws;
  const size_t SZ = 51380224ull;    // 64*512*784*2 bytes (bf16 plane buffer)
  const size_t SMALL = 6422528ull;  // 3136*512*4 bytes
  bf16* pooled = (bf16*)(w);        // dead after ln
  bf16* yln = (bf16*)(w + SZ);      // dead after kv gemm
  bf16* Kb = (bf16*)(w);            // reuses pooled slot (after ln)
  bf16* Vb = (bf16*)(w + 2 * SZ);
  float* xsT = (float*)(w + 3 * SZ);
  float* Qf = (float*)(w + 3 * SZ + SMALL);
  float* aout = (float*)(w + 3 * SZ + 2 * SMALL);
  bf16* wkvT = (bf16*)(w + 3 * SZ + 2 * SMALL);  // shares aout slot (dead before attn)
  // peak ws use: 3*SZ + 3*SMALL = 173.4 MB (unchanged from round 0)

  wkvt_kernel<<<dim3(32, 16), dim3(256), 0, stream>>>(Wkv, wkvT);
  pool_kernel<<<dim3(32768), dim3(256), 0, stream>>>(y, pooled);
  ln_kernel<<<dim3(49, 64), dim3(256), 0, stream>>>(pooled, gamma, beta, yln);
  xst_kernel<<<dim3(6272), dim3(256), 0, stream>>>(x, xsT);
  gemm_k<64, 64, 16, 4, 4, 0>
      <<<dim3(8, 49), dim3(256), 0, stream>>>(xsT, Wq, 3136, 512, 512, Qf, nullptr);
  kv_mfma<<<dim3(8, 392), dim3(256), 0, stream>>>(yln, wkvT, Kb, Vb);
  attn_kernel<<<dim3(3584), dim3(256), 0, stream>>>(Qf, Kb, Vb, aw1, aw2, aout);
  gemm_k<64, 64, 16, 4, 4, 2>
      <<<dim3(8, 49), dim3(256), 0, stream>>>(aout, Wproj, 3136, 512, 512, out, bproj);
}

// Round 3
// 554.452 us; speedup vs baseline: 5.1755x; 5.1755x over previous
//
#include <hip/hip_runtime.h>
#include <hip/hip_bf16.h>

// MSCN fused pipeline, MI355X gfx950. Round 2: MFMA QK^T + register-disciplined attn.
// B=64, C=512, H=W=7 (N=49), HY=WY=28 (N1=784), heads=8, d=64, SCALE=0.125
// kc1 = 784//2 = 392, kc2 = 784//3 = 261

typedef __hip_bfloat16 bf16;
using bf16x8 = __attribute__((ext_vector_type(8))) short;  // 8 bf16 = 4 VGPRs
using f32x4 = __attribute__((ext_vector_type(4))) float;
using f32x8 = __attribute__((ext_vector_type(8))) float;
using u32x16 = __attribute__((ext_vector_type(16))) unsigned int;

#define DI __device__ __forceinline__

DI float bfu(unsigned short u) { return __uint_as_float(((unsigned int)u) << 16); }
DI float blo(unsigned int u) { return __uint_as_float(u << 16); }
DI float bhi(unsigned int u) { return __uint_as_float(u & 0xFFFF0000u); }

DI f32x8 unp8v(uint4 u) {
  f32x8 f;
  f[0] = blo(u.x); f[1] = bhi(u.x); f[2] = blo(u.y); f[3] = bhi(u.y);
  f[4] = blo(u.z); f[5] = bhi(u.z); f[6] = blo(u.w); f[7] = bhi(u.w);
  return f;
}

DI float wave_max_f(float v) {
#pragma unroll
  for (int off = 32; off; off >>= 1) v = fmaxf(v, __shfl_xor(v, off, 64));
  return v;
}
DI float wave_sum_f(float v) {
#pragma unroll
  for (int off = 32; off; off >>= 1) v += __shfl_xor(v, off, 64);
  return v;
}
// monotone float->uint key: ascending key order == ascending float order
DI unsigned int fkey(float f) {
  unsigned int u = __float_as_uint(f);
  return (u & 0x80000000u) ? ~u : (u | 0x80000000u);
}

// kth-largest threshold via bitwise bisection; counts via ballot+popcount.
// Early exit when count==k is exact (selection {key>=thr} is then precisely
// the top-k set); ties fall through to full 32-bit bisection, matching the
// reference >= kth-value semantics. key passed as ext-vector (registers).
DI unsigned int bisect_topk(u32x16 key, int kth) {
  unsigned int thr = 0u;
  for (int bit = 31; bit >= 0; --bit) {
    unsigned int cand = thr | (1u << bit);
    int c = 0;
#pragma unroll
    for (int i = 0; i < 13; ++i) c += __popcll(__ballot(key[i] >= cand));
    if (c >= kth) {
      thr = cand;
      if (c == kth) break;
    }
  }
  return thr;
}

// ---------------------------------------------------------------- pool
__global__ __launch_bounds__(256) void pool_kernel(const float* __restrict__ y,
                                                   bf16* __restrict__ pooled) {
  const int plane = blockIdx.x;  // b*512 + c
  const float* src = y + (size_t)plane * 784;
  __shared__ float p[784];
  for (int i = threadIdx.x; i < 784; i += 256) p[i] = src[i];
  __syncthreads();
  for (int i = threadIdx.x; i < 784; i += 256) {
    int r = i / 28, c = i - (i / 28) * 28;
    float acc = 0.f;
#pragma unroll
    for (int di = -3; di <= 3; ++di) {
      int rr = r + di;
      if (rr < 0 || rr >= 28) continue;
#pragma unroll
      for (int dj = -3; dj <= 3; ++dj) {
        int cc = c + dj;
        if (cc < 0 || cc >= 28) continue;
        const int adi = di < 0 ? -di : di, adj = dj < 0 ? -dj : dj;
        const float w = 1.0f / 49.0f + ((adi <= 2 && adj <= 2) ? 1.0f / 25.0f : 0.0f) +
                        ((adi <= 1 && adj <= 1) ? 1.0f / 9.0f : 0.0f);
        acc += w * p[rr * 28 + cc];
      }
    }
    pooled[(size_t)plane * 784 + i] = __float2bfloat16(acc);
  }
}

// ---------------------------------------------------------------- layernorm + transpose
__global__ __launch_bounds__(256) void ln_kernel(const bf16* __restrict__ pooled,
                                                 const float* __restrict__ gamma,
                                                 const float* __restrict__ beta,
                                                 bf16* __restrict__ yln) {
  const int b = blockIdx.y;
  const int n0 = blockIdx.x * 16;
  __shared__ float tile[16][520];
  __shared__ float smu[16], srs[16];
  const bf16* src = pooled + (size_t)b * 512 * 784;
  for (int idx = threadIdx.x; idx < 512 * 16; idx += 256) {
    int c = idx >> 4, pp = idx & 15;
    tile[pp][c] = __bfloat162float(src[(size_t)c * 784 + n0 + pp]);
  }
  __syncthreads();
  int pp = threadIdx.x >> 4, l = threadIdx.x & 15;
  float s = 0.f, s2 = 0.f;
  for (int c = l; c < 512; c += 16) {
    float v = tile[pp][c];
    s += v;
    s2 += v * v;
  }
#pragma unroll
  for (int off = 8; off; off >>= 1) {
    s += __shfl_xor(s, off, 64);
    s2 += __shfl_xor(s2, off, 64);
  }
  if (l == 0) {
    float mu = s * (1.f / 512.f);
    float var = s2 * (1.f / 512.f) - mu * mu;
    smu[pp] = mu;
    srs[pp] = rsqrtf(var + 1e-5f);
  }
  __syncthreads();
  bf16* dst = yln + ((size_t)b * 784 + n0) * 512;
  for (int idx = threadIdx.x; idx < 512 * 16; idx += 256) {
    int q = idx >> 9, c = idx & 511;
    float v = (tile[q][c] - smu[q]) * srs[q] * gamma[c] + beta[c];
    dst[(size_t)q * 512 + c] = __float2bfloat16(v);
  }
}

// ---------------------------------------------------------------- x transpose
__global__ __launch_bounds__(256) void xst_kernel(const float* __restrict__ x,
                                                  float* __restrict__ xsT) {
  int idx = blockIdx.x * 256 + threadIdx.x;
  int c = idx & 511;
  int rem = idx >> 9;
  int r = rem % 49, b = rem / 49;
  xsT[idx] = x[((size_t)b * 512 + c) * 49 + r];
}

// ---------------------------------------------------------------- Wkv transpose -> bf16 [1024][512]
__global__ __launch_bounds__(256) void wkvt_kernel(const float* __restrict__ Wkv,
                                                   bf16* __restrict__ WkvT) {
  __shared__ float t[32][33];
  const int n0 = blockIdx.x * 32, k0 = blockIdx.y * 32;
  for (int i = threadIdx.x; i < 1024; i += 256) {
    int kr = i >> 5, nc = i & 31;
    t[kr][nc] = Wkv[(size_t)(k0 + kr) * 1024 + n0 + nc];
  }
  __syncthreads();
  for (int i = threadIdx.x; i < 1024; i += 256) {
    int nr = i >> 5, kc = i & 31;
    WkvT[(size_t)(n0 + nr) * 512 + k0 + kc] = __float2bfloat16(t[kc][nr]);
  }
}

// ---------------------------------------------------------------- f32 GEMM (q, proj)
DI float4 ldg4(const float* p) { return *reinterpret_cast<const float4*>(p); }

// MODE 0: Q  -> o0 f32 [B,8,49,64]
// MODE 2: proj -> o0 f32 [B,512,49] (transposed write) + bias
template <int BM, int BN, int BK, int TM, int TN, int MODE>
__global__ __launch_bounds__(256) void gemm_k(const float* __restrict__ A, const float* __restrict__ B,
                                              int M, int N, int K, float* __restrict__ o0,
                                              const float* __restrict__ bias) {
  __shared__ float As[BK][BM + 4];
  __shared__ float Bs[BK][BN + 4];
  const int tid = threadIdx.x;
  const int tx = tid & 15, ty = tid >> 4;
  const int m0 = blockIdx.y * BM, n0 = blockIdx.x * BN;
  float acc[TM][TN];
#pragma unroll
  for (int i = 0; i < TM; ++i)
#pragma unroll
    for (int j = 0; j < TN; ++j) acc[i][j] = 0.f;

  for (int k0 = 0; k0 < K; k0 += BK) {
#pragma unroll
    for (int t = 0; t < (BM * BK) / 1024; ++t) {
      int lin = tid * 4 + t * 1024;
      int mm = lin / BK, kk = lin % BK;
      float4 v = ldg4(A + (size_t)(m0 + mm) * K + k0 + kk);
      As[kk + 0][mm] = v.x;
      As[kk + 1][mm] = v.y;
      As[kk + 2][mm] = v.z;
      As[kk + 3][mm] = v.w;
    }
#pragma unroll
    for (int t = 0; t < (BN * BK) / 1024; ++t) {
      int lin = tid * 4 + t * 1024;
      int kk = lin / BN, nn = lin % BN;
      *reinterpret_cast<float4*>(&Bs[kk][nn]) = ldg4(B + (size_t)(k0 + kk) * N + n0 + nn);
    }
    __syncthreads();
#pragma unroll
    for (int kk = 0; kk < BK; ++kk) {
      float a[TM], bb[TN];
#pragma unroll
      for (int i = 0; i < TM; i += 4)
        *reinterpret_cast<float4*>(&a[i]) = *reinterpret_cast<const float4*>(&As[kk][ty * TM + i]);
#pragma unroll
      for (int j = 0; j < TN; j += 4)
        *reinterpret_cast<float4*>(&bb[j]) = *reinterpret_cast<const float4*>(&Bs[kk][tx * TN + j]);
#pragma unroll
      for (int i = 0; i < TM; ++i)
#pragma unroll
        for (int j = 0; j < TN; ++j) acc[i][j] = fmaf(a[i], bb[j], acc[i][j]);
    }
    __syncthreads();
  }
#pragma unroll
  for (int i = 0; i < TM; ++i) {
    int m = m0 + ty * TM + i;
#pragma unroll
    for (int j = 0; j < TN; ++j) {
      int n = n0 + tx * TN + j;
      float v = acc[i][j];
      if constexpr (MODE == 0) {
        int b = m / 49, r = m - (m / 49) * 49;
        o0[(((size_t)b * 8 + (n >> 6)) * 49 + r) * 64 + (n & 63)] = v;
      } else {
        int b = m / 49, r = m - (m / 49) * 49;
        o0[((size_t)b * 512 + n) * 49 + r] = v + bias[n];
      }
    }
  }
}

// ---------------------------------------------------------------- kv MFMA GEMM
// A = yln bf16 [50176][512], Bt = WkvT bf16 [1024][512]; out K/V bf16 [B,8,784,64]
#define GLD_LDS16(g, l)                                                              \
  __builtin_amdgcn_global_load_lds((const __attribute__((address_space(1))) unsigned int*)(g), \
                                   (__attribute__((address_space(3))) unsigned int*)(l), 16, 0, 0)

__global__ __launch_bounds__(256) void kv_mfma(const bf16* __restrict__ A,
                                               const bf16* __restrict__ Bt,
                                               bf16* __restrict__ Kb, bf16* __restrict__ Vb) {
  __shared__ __align__(16) bf16 As[128 * 32];
  __shared__ __align__(16) bf16 Bs[128 * 32];
  const int tid = threadIdx.x;
  const int lane = tid & 63;
  const int w = tid >> 6, wr = w >> 1, wc = w & 1;
  const int m0 = blockIdx.y * 128, n0 = blockIdx.x * 128;

  f32x4 acc[4][4];
#pragma unroll
  for (int m = 0; m < 4; ++m)
#pragma unroll
    for (int n = 0; n < 4; ++n) acc[m][n] = f32x4{0.f, 0.f, 0.f, 0.f};

  const int s0 = tid, s1 = tid + 256;  // 16B segments; seg s: row=s>>2, koff=(s&3)*8
  const bf16* Ag0 = A + (size_t)(m0 + (s0 >> 2)) * 512 + (s0 & 3) * 8;
  const bf16* Ag1 = A + (size_t)(m0 + (s1 >> 2)) * 512 + (s1 & 3) * 8;
  const bf16* Bg0 = Bt + (size_t)(n0 + (s0 >> 2)) * 512 + (s0 & 3) * 8;
  const bf16* Bg1 = Bt + (size_t)(n0 + (s1 >> 2)) * 512 + (s1 & 3) * 8;
  bf16* Al0 = As + s0 * 8;
  bf16* Al1 = As + s1 * 8;
  bf16* Bl0 = Bs + s0 * 8;
  bf16* Bl1 = Bs + s1 * 8;

  const int fr = lane & 15;        // fragment row/col within 16
  const int ko = (lane >> 4) * 8;  // k offset within 32

  for (int k0 = 0; k0 < 512; k0 += 32) {
    GLD_LDS16(Ag0 + k0, Al0);
    GLD_LDS16(Ag1 + k0, Al1);
    GLD_LDS16(Bg0 + k0, Bl0);
    GLD_LDS16(Bg1 + k0, Bl1);
    __syncthreads();  // vmcnt drained before barrier
    bf16x8 af[4], bfr[4];
#pragma unroll
    for (int m = 0; m < 4; ++m)
      af[m] = *reinterpret_cast<const bf16x8*>(As + (wr * 64 + m * 16 + fr) * 32 + ko);
#pragma unroll
    for (int n = 0; n < 4; ++n)
      bfr[n] = *reinterpret_cast<const bf16x8*>(Bs + (wc * 64 + n * 16 + fr) * 32 + ko);
#pragma unroll
    for (int m = 0; m < 4; ++m)
#pragma unroll
      for (int n = 0; n < 4; ++n)
        acc[m][n] = __builtin_amdgcn_mfma_f32_16x16x32_bf16(af[m], bfr[n], acc[m][n], 0, 0, 0);
    __syncthreads();
  }

  const int rh = lane >> 4;
#pragma unroll
  for (int m = 0; m < 4; ++m) {
#pragma unroll
    for (int n = 0; n < 4; ++n) {
      int col = n0 + wc * 64 + n * 16 + fr;
      bf16* dst = (col & 512) ? Vb : Kb;
      const size_t cbase = ((size_t)((col >> 6) & 7)) * (784 * 64) + (col & 63);
#pragma unroll
      for (int r = 0; r < 4; ++r) {
        int row = m0 + wr * 64 + m * 16 + rh * 4 + r;
        int b = row / 784, n1 = row - (row / 784) * 784;
        dst[((size_t)b * 8) * (784 * 64) + cbase + (size_t)n1 * 64] = __float2bfloat16(acc[m][n][r]);
      }
    }
  }
}

// ---------------------------------------------------------------- attention
// one block = (b,h, chunk of 7 q-rows). MFMA QK^T, ballot top-k, wave-split PV.
__global__ __launch_bounds__(256, 4) void attn_kernel(const float* __restrict__ Q,
                                                      const bf16* __restrict__ K,
                                                      const bf16* __restrict__ V,
                                                      const float* __restrict__ aw1p,
                                                      const float* __restrict__ aw2p,
                                                      float* __restrict__ aout) {
  const int bh = blockIdx.x / 7;
  const int chunk = blockIdx.x - bh * 7;
  const int b = bh >> 3, h = bh & 7;
  const int r0 = chunk * 7;
  const int tid = threadIdx.x;
  const int lane = tid & 63, w = tid >> 6;
  __shared__ __align__(16) bf16 sQb[16][64];  // rows 7..15 zero
  __shared__ __align__(16) float sA[7][784];
  __shared__ __align__(16) float sP[4][7][64];

  // stage Q (bf16, zero-padded rows)
  const float* Qp = Q + ((size_t)bh * 49 + r0) * 64;
  for (int i = tid; i < 1024; i += 256) {
    int r = i >> 6, d = i & 63;
    sQb[r][d] = __float2bfloat16((r < 7) ? Qp[r * 64 + d] : 0.f);
  }
  __syncthreads();

  // ---- QK^T via MFMA: S[16][784] = Q[16][64] x K^T, NT pattern (K rows = B^T rows)
  const bf16* Kp = K + (size_t)bh * (784 * 64);
  {
    const int fr = lane & 15, ko = (lane >> 4) * 8;
    const bf16x8 aq0 = *reinterpret_cast<const bf16x8*>(&sQb[fr][ko]);
    const bf16x8 aq1 = *reinterpret_cast<const bf16x8*>(&sQb[fr][32 + ko]);
    const int rbase = (lane >> 4) * 4;
    for (int nt = w; nt < 49; nt += 4) {
      const int n0 = nt * 16;
      const bf16* krow = Kp + (size_t)(n0 + fr) * 64 + ko;
      bf16x8 b0 = *reinterpret_cast<const bf16x8*>(krow);
      bf16x8 b1 = *reinterpret_cast<const bf16x8*>(krow + 32);
      f32x4 acc = {0.f, 0.f, 0.f, 0.f};
      acc = __builtin_amdgcn_mfma_f32_16x16x32_bf16(aq0, b0, acc, 0, 0, 0);
      acc = __builtin_amdgcn_mfma_f32_16x16x32_bf16(aq1, b1, acc, 0, 0, 0);
#pragma unroll
      for (int r = 0; r < 4; ++r) {
        int row = rbase + r;
        if (row < 7) sA[row][n0 + fr] = acc[r] * 0.125f;
      }
    }
  }
  __syncthreads();

  // ---- top-k + softmax weights (one wave per row)
  const float aw1 = aw1p[0], aw2 = aw2p[0];
  for (int r = w; r < 7; r += 4) {
    float v[13];
    u32x16 key;
#pragma unroll
    for (int i = 0; i < 13; ++i) {
      int m = lane + i * 64;
      v[i] = (m < 784) ? sA[r][m] : -INFINITY;
      key[i] = fkey(v[i]);
    }
    key[13] = 0u; key[14] = 0u; key[15] = 0u;
    float mx = v[0];
#pragma unroll
    for (int i = 1; i < 13; ++i) mx = fmaxf(mx, v[i]);
    mx = wave_max_f(mx);
    unsigned int thr1 = bisect_topk(key, 392);
    unsigned int thr2 = bisect_topk(key, 261);
    float e[13];
    float z1 = 0.f, z2 = 0.f;
#pragma unroll
    for (int i = 0; i < 13; ++i) {
      e[i] = __expf(v[i] - mx);  // pads: exp(-inf)=0
      if (key[i] >= thr1) z1 += e[i];
      if (key[i] >= thr2) z2 += e[i];
    }
    z1 = wave_sum_f(z1);
    z2 = wave_sum_f(z2);
    const float a1 = aw1 / z1, a2 = aw2 / z2;
#pragma unroll
    for (int i = 0; i < 13; ++i) {
      int m = lane + i * 64;
      if (m < 784) {
        float wgt = e[i] * (((key[i] >= thr1) ? a1 : 0.f) + ((key[i] >= thr2) ? a2 : 0.f));
        sA[r][m] = wgt;
      }
    }
  }
  __syncthreads();

  // ---- PV: wave w owns m in [w*196, w*196+196); lane = (msub 0..7, dg 0..7)
  const bf16* Vp = V + (size_t)bh * (784 * 64);
  const int msub = lane >> 3, dg = lane & 7;
  f32x8 acc0 = 0.f, acc1 = 0.f, acc2 = 0.f, acc3 = 0.f, acc4 = 0.f, acc5 = 0.f, acc6 = 0.f;
  for (int i = 0; i < 25; ++i) {
    int midx = i * 8 + msub;
    if (midx < 196) {
      int m = w * 196 + midx;
      f32x8 vf = unp8v(*reinterpret_cast<const uint4*>(Vp + (size_t)m * 64 + dg * 8));
      acc0 += vf * sA[0][m];
      acc1 += vf * sA[1][m];
      acc2 += vf * sA[2][m];
      acc3 += vf * sA[3][m];
      acc4 += vf * sA[4][m];
      acc5 += vf * sA[5][m];
      acc6 += vf * sA[6][m];
    }
  }
  // reduce across msub (lane bits 3..5)
#pragma unroll
  for (int c = 0; c < 8; ++c) {
    float s0 = acc0[c], s1 = acc1[c], s2 = acc2[c], s3 = acc3[c], s4 = acc4[c], s5 = acc5[c],
          s6 = acc6[c];
#pragma unroll
    for (int off = 8; off <= 32; off <<= 1) {
      s0 += __shfl_xor(s0, off, 64);
      s1 += __shfl_xor(s1, off, 64);
      s2 += __shfl_xor(s2, off, 64);
      s3 += __shfl_xor(s3, off, 64);
      s4 += __shfl_xor(s4, off, 64);
      s5 += __shfl_xor(s5, off, 64);
      s6 += __shfl_xor(s6, off, 64);
    }
    acc0[c] = s0; acc1[c] = s1; acc2[c] = s2; acc3[c] = s3; acc4[c] = s4; acc5[c] = s5;
    acc6[c] = s6;
  }
  if (msub == 0) {
#pragma unroll
    for (int c = 0; c < 8; ++c) {
      sP[w][0][dg * 8 + c] = acc0[c];
      sP[w][1][dg * 8 + c] = acc1[c];
      sP[w][2][dg * 8 + c] = acc2[c];
      sP[w][3][dg * 8 + c] = acc3[c];
      sP[w][4][dg * 8 + c] = acc4[c];
      sP[w][5][dg * 8 + c] = acc5[c];
      sP[w][6][dg * 8 + c] = acc6[c];
    }
  }
  __syncthreads();
  for (int idx = tid; idx < 448; idx += 256) {
    int r = idx >> 6, d = idx & 63;
    float s = sP[0][r][d] + sP[1][r][d] + sP[2][r][d] + sP[3][r][d];
    aout[((size_t)(b * 49 + r0 + r)) * 512 + h * 64 + d] = s;
  }
}

// ---------------------------------------------------------------- launch
extern "C" void kernel_launch(void* const* d_in, const int* in_sizes, int n_in, void* d_out,
                              int out_size, void* d_ws, size_t ws_size, hipStream_t stream) {
  const float* x = (const float*)d_in[0];
  const float* y = (const float*)d_in[1];
  const float* Wq = (const float*)d_in[2];
  const float* Wkv = (const float*)d_in[3];
  const float* Wproj = (const float*)d_in[4];
  const float* bproj = (const float*)d_in[5];
  const float* gamma = (const float*)d_in[6];
  const float* beta = (const float*)d_in[7];
  const float* aw1 = (const float*)d_in[8];
  const float* aw2 = (const float*)d_in[9];
  float* out = (float*)d_out;

  char* w = (char*)d_ws;
  const size_t SZ = 51380224ull;    // 64*512*784*2 bytes (bf16 plane buffer)
  const size_t SMALL = 6422528ull;  // 3136*512*4 bytes
  bf16* pooled = (bf16*)(w);        // dead after ln
  bf16* yln = (bf16*)(w + SZ);      // dead after kv gemm
  bf16* Kb = (bf16*)(w);            // reuses pooled slot (after ln)
  bf16* Vb = (bf16*)(w + 2 * SZ);
  float* xsT = (float*)(w + 3 * SZ);
  float* Qf = (float*)(w + 3 * SZ + SMALL);
  float* aout = (float*)(w + 3 * SZ + 2 * SMALL);
  bf16* wkvT = (bf16*)(w + 3 * SZ + 2 * SMALL);  // shares aout slot (dead before attn)
  // peak ws use: 3*SZ + 3*SMALL = 173.4 MB

  wkvt_kernel<<<dim3(32, 16), dim3(256), 0, stream>>>(Wkv, wkvT);
  pool_kernel<<<dim3(32768), dim3(256), 0, stream>>>(y, pooled);
  ln_kernel<<<dim3(49, 64), dim3(256), 0, stream>>>(pooled, gamma, beta, yln);
  xst_kernel<<<dim3(6272), dim3(256), 0, stream>>>(x, xsT);
  gemm_k<64, 64, 16, 4, 4, 0>
      <<<dim3(8, 49), dim3(256), 0, stream>>>(xsT, Wq, 3136, 512, 512, Qf, nullptr);
  kv_mfma<<<dim3(8, 392), dim3(256), 0, stream>>>(yln, wkvT, Kb, Vb);
  attn_kernel<<<dim3(3584), dim3(256), 0, stream>>>(Qf, Kb, Vb, aw1, aw2, aout);
  gemm_k<64, 64, 16, 4, 4, 2>
      <<<dim3(8, 49), dim3(256), 0, stream>>>(aout, Wproj, 3136, 512, 512, out, bproj);
}

// Round 4
// 525.131 us; speedup vs baseline: 5.4645x; 1.0558x over previous
//
#include <hip/hip_runtime.h>
#include <hip/hip_bf16.h>

// MSCN fused pipeline, MI355X gfx950. Round 3: MFMA PV (V^T in HBM) + XCD swizzles.
// B=64, C=512, H=W=7 (N=49), HY=WY=28 (N1=784), heads=8, d=64, SCALE=0.125
// kc1 = 784//2 = 392, kc2 = 784//3 = 261

typedef __hip_bfloat16 bf16;
using bf16x8 = __attribute__((ext_vector_type(8))) short;  // 8 bf16 = 4 VGPRs
using f32x4 = __attribute__((ext_vector_type(4))) float;
using u32x16 = __attribute__((ext_vector_type(16))) unsigned int;

#define DI __device__ __forceinline__

DI float bfu(unsigned short u) { return __uint_as_float(((unsigned int)u) << 16); }
DI unsigned short b2u(float f) {
  bf16 h = __float2bfloat16(f);
  return *reinterpret_cast<unsigned short*>(&h);
}

DI float wave_max_f(float v) {
#pragma unroll
  for (int off = 32; off; off >>= 1) v = fmaxf(v, __shfl_xor(v, off, 64));
  return v;
}
DI float wave_sum_f(float v) {
#pragma unroll
  for (int off = 32; off; off >>= 1) v += __shfl_xor(v, off, 64);
  return v;
}
// monotone float->uint key: ascending key order == ascending float order
DI unsigned int fkey(float f) {
  unsigned int u = __float_as_uint(f);
  return (u & 0x80000000u) ? ~u : (u | 0x80000000u);
}

// kth-largest threshold via bitwise bisection; counts via ballot+popcount.
// Early exit when count==k is exact; ties fall through to full 32-bit
// bisection, matching reference >= kth-value semantics.
DI unsigned int bisect_topk(u32x16 key, int kth) {
  unsigned int thr = 0u;
  for (int bit = 31; bit >= 0; --bit) {
    unsigned int cand = thr | (1u << bit);
    int c = 0;
#pragma unroll
    for (int i = 0; i < 13; ++i) c += __popcll(__ballot(key[i] >= cand));
    if (c >= kth) {
      thr = cand;
      if (c == kth) break;
    }
  }
  return thr;
}

// ---------------------------------------------------------------- pool
__global__ __launch_bounds__(256) void pool_kernel(const float* __restrict__ y,
                                                   bf16* __restrict__ pooled) {
  const int plane = blockIdx.x;  // b*512 + c
  const float* src = y + (size_t)plane * 784;
  __shared__ float p[784];
  for (int i = threadIdx.x; i < 784; i += 256) p[i] = src[i];
  __syncthreads();
  for (int i = threadIdx.x; i < 784; i += 256) {
    int r = i / 28, c = i - (i / 28) * 28;
    float acc = 0.f;
#pragma unroll
    for (int di = -3; di <= 3; ++di) {
      int rr = r + di;
      if (rr < 0 || rr >= 28) continue;
#pragma unroll
      for (int dj = -3; dj <= 3; ++dj) {
        int cc = c + dj;
        if (cc < 0 || cc >= 28) continue;
        const int adi = di < 0 ? -di : di, adj = dj < 0 ? -dj : dj;
        const float w = 1.0f / 49.0f + ((adi <= 2 && adj <= 2) ? 1.0f / 25.0f : 0.0f) +
                        ((adi <= 1 && adj <= 1) ? 1.0f / 9.0f : 0.0f);
        acc += w * p[rr * 28 + cc];
      }
    }
    pooled[(size_t)plane * 784 + i] = __float2bfloat16(acc);
  }
}

// ---------------------------------------------------------------- layernorm + transpose
__global__ __launch_bounds__(256) void ln_kernel(const bf16* __restrict__ pooled,
                                                 const float* __restrict__ gamma,
                                                 const float* __restrict__ beta,
                                                 bf16* __restrict__ yln) {
  const int b = blockIdx.y;
  const int n0 = blockIdx.x * 16;
  __shared__ float tile[16][520];
  __shared__ float smu[16], srs[16];
  const bf16* src = pooled + (size_t)b * 512 * 784;
  for (int idx = threadIdx.x; idx < 512 * 16; idx += 256) {
    int c = idx >> 4, pp = idx & 15;
    tile[pp][c] = __bfloat162float(src[(size_t)c * 784 + n0 + pp]);
  }
  __syncthreads();
  int pp = threadIdx.x >> 4, l = threadIdx.x & 15;
  float s = 0.f, s2 = 0.f;
  for (int c = l; c < 512; c += 16) {
    float v = tile[pp][c];
    s += v;
    s2 += v * v;
  }
#pragma unroll
  for (int off = 8; off; off >>= 1) {
    s += __shfl_xor(s, off, 64);
    s2 += __shfl_xor(s2, off, 64);
  }
  if (l == 0) {
    float mu = s * (1.f / 512.f);
    float var = s2 * (1.f / 512.f) - mu * mu;
    smu[pp] = mu;
    srs[pp] = rsqrtf(var + 1e-5f);
  }
  __syncthreads();
  bf16* dst = yln + ((size_t)b * 784 + n0) * 512;
  for (int idx = threadIdx.x; idx < 512 * 16; idx += 256) {
    int q = idx >> 9, c = idx & 511;
    float v = (tile[q][c] - smu[q]) * srs[q] * gamma[c] + beta[c];
    dst[(size_t)q * 512 + c] = __float2bfloat16(v);
  }
}

// ---------------------------------------------------------------- x transpose
__global__ __launch_bounds__(256) void xst_kernel(const float* __restrict__ x,
                                                  float* __restrict__ xsT) {
  int idx = blockIdx.x * 256 + threadIdx.x;
  int c = idx & 511;
  int rem = idx >> 9;
  int r = rem % 49, b = rem / 49;
  xsT[idx] = x[((size_t)b * 512 + c) * 49 + r];
}

// ---------------------------------------------------------------- Wkv transpose -> bf16 [1024][512]
__global__ __launch_bounds__(256) void wkvt_kernel(const float* __restrict__ Wkv,
                                                   bf16* __restrict__ WkvT) {
  __shared__ float t[32][33];
  const int n0 = blockIdx.x * 32, k0 = blockIdx.y * 32;
  for (int i = threadIdx.x; i < 1024; i += 256) {
    int kr = i >> 5, nc = i & 31;
    t[kr][nc] = Wkv[(size_t)(k0 + kr) * 1024 + n0 + nc];
  }
  __syncthreads();
  for (int i = threadIdx.x; i < 1024; i += 256) {
    int nr = i >> 5, kc = i & 31;
    WkvT[(size_t)(n0 + nr) * 512 + k0 + kc] = __float2bfloat16(t[kc][nr]);
  }
}

// ---------------------------------------------------------------- Vt pad zeroing
// Vt layout [b*8+h][64 d][800]; cols 784..799 must be zero (PV tail MFMA).
__global__ __launch_bounds__(256) void vtpad_kernel(bf16* __restrict__ Vt) {
  int idx = blockIdx.x * 256 + threadIdx.x;  // 524288 total
  int row = idx >> 4, c = idx & 15;
  Vt[(size_t)row * 800 + 784 + c] = __float2bfloat16(0.f);
}

// ---------------------------------------------------------------- f32 GEMM (q, proj)
DI float4 ldg4(const float* p) { return *reinterpret_cast<const float4*>(p); }

// MODE 0: Q  -> o0 f32 [B,8,49,64]
// MODE 2: proj -> o0 f32 [B,512,49] (transposed write) + bias
template <int BM, int BN, int BK, int TM, int TN, int MODE>
__global__ __launch_bounds__(256) void gemm_k(const float* __restrict__ A, const float* __restrict__ B,
                                              int M, int N, int K, float* __restrict__ o0,
                                              const float* __restrict__ bias) {
  __shared__ float As[BK][BM + 4];
  __shared__ float Bs[BK][BN + 4];
  const int tid = threadIdx.x;
  const int tx = tid & 15, ty = tid >> 4;
  const int m0 = blockIdx.y * BM, n0 = blockIdx.x * BN;
  float acc[TM][TN];
#pragma unroll
  for (int i = 0; i < TM; ++i)
#pragma unroll
    for (int j = 0; j < TN; ++j) acc[i][j] = 0.f;

  for (int k0 = 0; k0 < K; k0 += BK) {
#pragma unroll
    for (int t = 0; t < (BM * BK) / 1024; ++t) {
      int lin = tid * 4 + t * 1024;
      int mm = lin / BK, kk = lin % BK;
      float4 v = ldg4(A + (size_t)(m0 + mm) * K + k0 + kk);
      As[kk + 0][mm] = v.x;
      As[kk + 1][mm] = v.y;
      As[kk + 2][mm] = v.z;
      As[kk + 3][mm] = v.w;
    }
#pragma unroll
    for (int t = 0; t < (BN * BK) / 1024; ++t) {
      int lin = tid * 4 + t * 1024;
      int kk = lin / BN, nn = lin % BN;
      *reinterpret_cast<float4*>(&Bs[kk][nn]) = ldg4(B + (size_t)(k0 + kk) * N + n0 + nn);
    }
    __syncthreads();
#pragma unroll
    for (int kk = 0; kk < BK; ++kk) {
      float a[TM], bb[TN];
#pragma unroll
      for (int i = 0; i < TM; i += 4)
        *reinterpret_cast<float4*>(&a[i]) = *reinterpret_cast<const float4*>(&As[kk][ty * TM + i]);
#pragma unroll
      for (int j = 0; j < TN; j += 4)
        *reinterpret_cast<float4*>(&bb[j]) = *reinterpret_cast<const float4*>(&Bs[kk][tx * TN + j]);
#pragma unroll
      for (int i = 0; i < TM; ++i)
#pragma unroll
        for (int j = 0; j < TN; ++j) acc[i][j] = fmaf(a[i], bb[j], acc[i][j]);
    }
    __syncthreads();
  }
#pragma unroll
  for (int i = 0; i < TM; ++i) {
    int m = m0 + ty * TM + i;
#pragma unroll
    for (int j = 0; j < TN; ++j) {
      int n = n0 + tx * TN + j;
      float v = acc[i][j];
      if constexpr (MODE == 0) {
        int b = m / 49, r = m - (m / 49) * 49;
        o0[(((size_t)b * 8 + (n >> 6)) * 49 + r) * 64 + (n & 63)] = v;
      } else {
        int b = m / 49, r = m - (m / 49) * 49;
        o0[((size_t)b * 512 + n) * 49 + r] = v + bias[n];
      }
    }
  }
}

// ---------------------------------------------------------------- kv MFMA GEMM
// A = yln bf16 [50176][512], Bt = WkvT bf16 [1024][512]
// out: Kb bf16 [B,8,784,64]; Vt bf16 [B*8, 64, 800] (transposed, pad cols 784..799 untouched)
#define GLD_LDS16(g, l)                                                              \
  __builtin_amdgcn_global_load_lds((const __attribute__((address_space(1))) unsigned int*)(g), \
                                   (__attribute__((address_space(3))) unsigned int*)(l), 16, 0, 0)

__global__ __launch_bounds__(256) void kv_mfma(const bf16* __restrict__ A,
                                               const bf16* __restrict__ Bt,
                                               bf16* __restrict__ Kb, bf16* __restrict__ Vt) {
  extern __shared__ __align__(16) bf16 smem[];  // 18432 B dynamic
  bf16* As = smem;                              // [128*32]
  bf16* Bs = smem + 128 * 32;                   // [128*32]
  const int tid = threadIdx.x;
  const int lane = tid & 63;
  const int w = tid >> 6, wr = w >> 1, wc = w & 1;

  // XCD swizzle: XCD c handles y-tiles [c*49, c*49+49), all 8 x-tiles (A-tile L2 reuse)
  const int lin = blockIdx.y * 8 + blockIdx.x;
  const int c8 = lin & 7, j = lin >> 3;
  const int ex = j & 7, ey = c8 * 49 + (j >> 3);
  const int m0 = ey * 128, n0 = ex * 128;

  f32x4 acc[4][4];
#pragma unroll
  for (int m = 0; m < 4; ++m)
#pragma unroll
    for (int n = 0; n < 4; ++n) acc[m][n] = f32x4{0.f, 0.f, 0.f, 0.f};

  const int s0 = tid, s1 = tid + 256;  // 16B segments; seg s: row=s>>2, koff=(s&3)*8
  const bf16* Ag0 = A + (size_t)(m0 + (s0 >> 2)) * 512 + (s0 & 3) * 8;
  const bf16* Ag1 = A + (size_t)(m0 + (s1 >> 2)) * 512 + (s1 & 3) * 8;
  const bf16* Bg0 = Bt + (size_t)(n0 + (s0 >> 2)) * 512 + (s0 & 3) * 8;
  const bf16* Bg1 = Bt + (size_t)(n0 + (s1 >> 2)) * 512 + (s1 & 3) * 8;
  bf16* Al0 = As + s0 * 8;
  bf16* Al1 = As + s1 * 8;
  bf16* Bl0 = Bs + s0 * 8;
  bf16* Bl1 = Bs + s1 * 8;

  const int fr = lane & 15;        // fragment row/col within 16
  const int ko = (lane >> 4) * 8;  // k offset within 32
  const int rh = lane >> 4;

  for (int k0 = 0; k0 < 512; k0 += 32) {
    GLD_LDS16(Ag0 + k0, Al0);
    GLD_LDS16(Ag1 + k0, Al1);
    GLD_LDS16(Bg0 + k0, Bl0);
    GLD_LDS16(Bg1 + k0, Bl1);
    __syncthreads();  // vmcnt drained before barrier
    bf16x8 af[4], bfr[4];
#pragma unroll
    for (int m = 0; m < 4; ++m)
      af[m] = *reinterpret_cast<const bf16x8*>(As + (wr * 64 + m * 16 + fr) * 32 + ko);
#pragma unroll
    for (int n = 0; n < 4; ++n)
      bfr[n] = *reinterpret_cast<const bf16x8*>(Bs + (wc * 64 + n * 16 + fr) * 32 + ko);
#pragma unroll
    for (int m = 0; m < 4; ++m)
#pragma unroll
      for (int n = 0; n < 4; ++n)
        acc[m][n] = __builtin_amdgcn_mfma_f32_16x16x32_bf16(af[m], bfr[n], acc[m][n], 0, 0, 0);
    __syncthreads();
  }

  if (n0 < 512) {
    // ---- K epilogue: coalesced [b,h,m,d] writes
#pragma unroll
    for (int m = 0; m < 4; ++m) {
#pragma unroll
      for (int n = 0; n < 4; ++n) {
        int col = n0 + wc * 64 + n * 16 + fr;
        const size_t cbase = ((size_t)(col >> 6)) * (784 * 64) + (col & 63);
#pragma unroll
        for (int r = 0; r < 4; ++r) {
          int row = m0 + wr * 64 + m * 16 + rh * 4 + r;
          int b = row / 784, n1 = row - (row / 784) * 784;
          Kb[((size_t)b * 8) * (784 * 64) + cbase + (size_t)n1 * 64] = __float2bfloat16(acc[m][n][r]);
        }
      }
    }
  } else {
    // ---- V epilogue: LDS-staged transpose -> Vt [b*8+h][d][800]
    bf16* stage = smem;  // [128 cols][72 rows-padded]
#pragma unroll
    for (int p = 0; p < 2; ++p) {
      __syncthreads();
      if (wr == p) {
#pragma unroll
        for (int m = 0; m < 4; ++m) {
#pragma unroll
          for (int n = 0; n < 4; ++n) {
            int coll = wc * 64 + n * 16 + fr;
            int rowl = m * 16 + rh * 4;
            unsigned int u0 = (unsigned int)b2u(acc[m][n][0]) | ((unsigned int)b2u(acc[m][n][1]) << 16);
            unsigned int u1 = (unsigned int)b2u(acc[m][n][2]) | ((unsigned int)b2u(acc[m][n][3]) << 16);
            *reinterpret_cast<uint2*>(stage + coll * 72 + rowl) = make_uint2(u0, u1);
          }
        }
      }
      __syncthreads();
      const int rbase = m0 + p * 64;
      for (int i = tid; i < 1024; i += 256) {
        int cc = i >> 3, tc = i & 7;
        int colg = n0 + cc;  // >= 512
        int h = (colg >> 6) & 7, d = colg & 63;
        int rs = rbase + tc * 8;
        int b = rs / 784, n1 = rs - b * 784;
        bf16x8 val = *reinterpret_cast<const bf16x8*>(stage + cc * 72 + tc * 8);
        bf16* dst = Vt + (((size_t)b * 8 + h) * 64 + d) * 800 + n1;
        if (n1 <= 776) {
          *reinterpret_cast<bf16x8*>(dst) = val;
        } else {
#pragma unroll
          for (int jj = 0; jj < 8; ++jj) {
            int rr = rs + jj;
            int bb2 = rr / 784, nn1 = rr - bb2 * 784;
            bf16 hv;
            *reinterpret_cast<short*>(&hv) = val[jj];
            Vt[(((size_t)bb2 * 8 + h) * 64 + d) * 800 + nn1] = hv;
          }
        }
      }
    }
  }
}

// ---------------------------------------------------------------- attention
// one block = (b,h, chunk of 7 q-rows). MFMA QK^T + MFMA PV; ballot top-k.
__global__ __launch_bounds__(256, 4) void attn_kernel(const float* __restrict__ Q,
                                                      const bf16* __restrict__ K,
                                                      const bf16* __restrict__ Vt,
                                                      const float* __restrict__ aw1p,
                                                      const float* __restrict__ aw2p,
                                                      float* __restrict__ aout) {
  // XCD swizzle: 3584 = 8*448; XCD c gets wk in [c*448,(c+1)*448) => bh in [c*64,(c+1)*64)
  const int lin = blockIdx.x;
  const int wk = (lin & 7) * 448 + (lin >> 3);
  const int bh = wk / 7;
  const int chunk = wk - bh * 7;
  const int b = bh >> 3, h = bh & 7;
  const int r0 = chunk * 7;
  const int tid = threadIdx.x;
  const int lane = tid & 63, w = tid >> 6;
  __shared__ __align__(16) bf16 sQb[16][72];   // rows 7..15 zero
  __shared__ __align__(16) float sLog[7][784];
  __shared__ __align__(16) bf16 sW[16][808];   // bf16 weights; rows 7..15 & cols>=784 zero

  // stage Q (bf16, zero-padded rows); zero sW rows 7..15
  const float* Qp = Q + ((size_t)bh * 49 + r0) * 64;
  for (int i = tid; i < 1024; i += 256) {
    int r = i >> 6, d = i & 63;
    sQb[r][d] = __float2bfloat16((r < 7) ? Qp[r * 64 + d] : 0.f);
  }
  for (int i = tid; i < 9 * 808; i += 256) {
    int r = i / 808, c = i - r * 808;
    sW[7 + r][c] = __float2bfloat16(0.f);
  }
  __syncthreads();

  // ---- QK^T via MFMA: S[16][784] = Q[16][64] x K^T (NT; K rows = B^T rows)
  const bf16* Kp = K + (size_t)bh * (784 * 64);
  const int fr = lane & 15, ko = (lane >> 4) * 8, rh = lane >> 4;
  {
    const bf16x8 aq0 = *reinterpret_cast<const bf16x8*>(&sQb[fr][ko]);
    const bf16x8 aq1 = *reinterpret_cast<const bf16x8*>(&sQb[fr][32 + ko]);
    const int rbase = rh * 4;
    for (int nt = w; nt < 49; nt += 4) {
      const int n0 = nt * 16;
      const bf16* krow = Kp + (size_t)(n0 + fr) * 64 + ko;
      bf16x8 b0 = *reinterpret_cast<const bf16x8*>(krow);
      bf16x8 b1 = *reinterpret_cast<const bf16x8*>(krow + 32);
      f32x4 acc = {0.f, 0.f, 0.f, 0.f};
      acc = __builtin_amdgcn_mfma_f32_16x16x32_bf16(aq0, b0, acc, 0, 0, 0);
      acc = __builtin_amdgcn_mfma_f32_16x16x32_bf16(aq1, b1, acc, 0, 0, 0);
#pragma unroll
      for (int r = 0; r < 4; ++r) {
        int row = rbase + r;
        if (row < 7) sLog[row][n0 + fr] = acc[r] * 0.125f;
      }
    }
  }
  __syncthreads();

  // ---- top-k + softmax weights (one wave per row) -> bf16 into sW
  const float aw1 = aw1p[0], aw2 = aw2p[0];
  for (int r = w; r < 7; r += 4) {
    float v[13];
    u32x16 key;
#pragma unroll
    for (int i = 0; i < 13; ++i) {
      int m = lane + i * 64;
      v[i] = (m < 784) ? sLog[r][m] : -INFINITY;
      key[i] = fkey(v[i]);
    }
    key[13] = 0u; key[14] = 0u; key[15] = 0u;
    float mx = v[0];
#pragma unroll
    for (int i = 1; i < 13; ++i) mx = fmaxf(mx, v[i]);
    mx = wave_max_f(mx);
    unsigned int thr1 = bisect_topk(key, 392);
    unsigned int thr2 = bisect_topk(key, 261);
    float e[13];
    float z1 = 0.f, z2 = 0.f;
#pragma unroll
    for (int i = 0; i < 13; ++i) {
      e[i] = __expf(v[i] - mx);  // pads: exp(-inf)=0
      if (key[i] >= thr1) z1 += e[i];
      if (key[i] >= thr2) z2 += e[i];
    }
    z1 = wave_sum_f(z1);
    z2 = wave_sum_f(z2);
    const float a1 = aw1 / z1, a2 = aw2 / z2;
#pragma unroll
    for (int i = 0; i < 13; ++i) {
      int m = lane + i * 64;
      if (m < 784) {
        float wgt = e[i] * (((key[i] >= thr1) ? a1 : 0.f) + ((key[i] >= thr2) ? a2 : 0.f));
        sW[r][m] = __float2bfloat16(wgt);
      }
    }
    if (lane < 24) sW[r][784 + lane] = __float2bfloat16(0.f);
  }
  __syncthreads();

  // ---- PV via MFMA: out[16][64] = W[16][800] x V^T; wave w owns d-tile w*16..w*16+16
  const bf16* vbase = Vt + ((size_t)bh * 64 + w * 16 + fr) * 800;
  f32x4 acc = {0.f, 0.f, 0.f, 0.f};
#pragma unroll 5
  for (int ks = 0; ks < 25; ++ks) {
    bf16x8 a = *reinterpret_cast<const bf16x8*>(&sW[fr][ks * 32 + ko]);
    bf16x8 bb = *reinterpret_cast<const bf16x8*>(vbase + ks * 32 + ko);
    acc = __builtin_amdgcn_mfma_f32_16x16x32_bf16(a, bb, acc, 0, 0, 0);
  }
#pragma unroll
  for (int r = 0; r < 4; ++r) {
    int row = rh * 4 + r;
    if (row < 7)
      aout[((size_t)(b * 49 + r0 + row)) * 512 + h * 64 + w * 16 + fr] = acc[r];
  }
}

// ---------------------------------------------------------------- launch
extern "C" void kernel_launch(void* const* d_in, const int* in_sizes, int n_in, void* d_out,
                              int out_size, void* d_ws, size_t ws_size, hipStream_t stream) {
  const float* x = (const float*)d_in[0];
  const float* y = (const float*)d_in[1];
  const float* Wq = (const float*)d_in[2];
  const float* Wkv = (const float*)d_in[3];
  const float* Wproj = (const float*)d_in[4];
  const float* bproj = (const float*)d_in[5];
  const float* gamma = (const float*)d_in[6];
  const float* beta = (const float*)d_in[7];
  const float* aw1 = (const float*)d_in[8];
  const float* aw2 = (const float*)d_in[9];
  float* out = (float*)d_out;

  char* w = (char*)d_ws;
  const size_t SZ = 51380224ull;    // 64*512*784*2 bytes
  const size_t SZV = 52428800ull;   // 64*8*64*800*2 bytes (V^T, padded stride 800)
  const size_t SMALL = 6422528ull;  // 3136*512*4 bytes
  bf16* pooled = (bf16*)(w);        // dead after ln
  bf16* yln = (bf16*)(w + SZ);      // dead after kv gemm
  bf16* Kb = (bf16*)(w);            // reuses pooled slot (after ln)
  bf16* Vt = (bf16*)(w + 2 * SZ);
  float* xsT = (float*)(w + 2 * SZ + SZV);
  float* Qf = (float*)(w + 2 * SZ + SZV + SMALL);
  float* aout = (float*)(w + 2 * SZ + SZV + 2 * SMALL);
  bf16* wkvT = (bf16*)(w + 2 * SZ + SZV + 2 * SMALL);  // shares aout slot (dead before attn)
  // peak ws use: 2*SZ + SZV + 3*SMALL = 174.5 MB

  wkvt_kernel<<<dim3(32, 16), dim3(256), 0, stream>>>(Wkv, wkvT);
  pool_kernel<<<dim3(32768), dim3(256), 0, stream>>>(y, pooled);
  vtpad_kernel<<<dim3(2048), dim3(256), 0, stream>>>(Vt);
  ln_kernel<<<dim3(49, 64), dim3(256), 0, stream>>>(pooled, gamma, beta, yln);
  xst_kernel<<<dim3(6272), dim3(256), 0, stream>>>(x, xsT);
  gemm_k<64, 64, 16, 4, 4, 0>
      <<<dim3(8, 49), dim3(256), 0, stream>>>(xsT, Wq, 3136, 512, 512, Qf, nullptr);
  kv_mfma<<<dim3(8, 392), dim3(256), 18432, stream>>>(yln, wkvT, Kb, Vt);
  attn_kernel<<<dim3(3584), dim3(256), 0, stream>>>(Qf, Kb, Vt, aw1, aw2, aout);
  gemm_k<64, 64, 16, 4, 4, 2>
      <<<dim3(8, 49), dim3(256), 0, stream>>>(aout, Wproj, 3136, 512, 512, out, bproj);
}

// Round 5
// 413.159 us; speedup vs baseline: 6.9454x; 1.2710x over previous
//
#include <hip/hip_runtime.h>
#include <hip/hip_bf16.h>

// MSCN fused pipeline, MI355X gfx950. Round 4: integral-image pool + MFMA Q-GEMM.
// B=64, C=512, H=W=7 (N=49), HY=WY=28 (N1=784), heads=8, d=64, SCALE=0.125
// kc1 = 784//2 = 392, kc2 = 784//3 = 261

typedef __hip_bfloat16 bf16;
using bf16x8 = __attribute__((ext_vector_type(8))) short;  // 8 bf16 = 4 VGPRs
using f32x4 = __attribute__((ext_vector_type(4))) float;
using u32x16 = __attribute__((ext_vector_type(16))) unsigned int;

#define DI __device__ __forceinline__

DI unsigned short b2u(float f) {
  bf16 h = __float2bfloat16(f);
  return *reinterpret_cast<unsigned short*>(&h);
}

DI float wave_max_f(float v) {
#pragma unroll
  for (int off = 32; off; off >>= 1) v = fmaxf(v, __shfl_xor(v, off, 64));
  return v;
}
DI float wave_sum_f(float v) {
#pragma unroll
  for (int off = 32; off; off >>= 1) v += __shfl_xor(v, off, 64);
  return v;
}
// monotone float->uint key: ascending key order == ascending float order
DI unsigned int fkey(float f) {
  unsigned int u = __float_as_uint(f);
  return (u & 0x80000000u) ? ~u : (u | 0x80000000u);
}

// kth-largest threshold via bitwise bisection; counts via ballot+popcount.
// Early exit when count==k is exact; ties fall through to full 32-bit
// bisection, matching reference >= kth-value semantics.
DI unsigned int bisect_topk(u32x16 key, int kth) {
  unsigned int thr = 0u;
  for (int bit = 31; bit >= 0; --bit) {
    unsigned int cand = thr | (1u << bit);
    int c = 0;
#pragma unroll
    for (int i = 0; i < 13; ++i) c += __popcll(__ballot(key[i] >= cand));
    if (c >= kth) {
      thr = cand;
      if (c == kth) break;
    }
  }
  return thr;
}

// ---------------------------------------------------------------- pool (integral image)
// 8 planes per block; padded 2D prefix sum in LDS, 3 box sums = 12 lookups.
__global__ __launch_bounds__(256) void pool2_kernel(const float* __restrict__ y,
                                                    bf16* __restrict__ pooled) {
  const int b = blockIdx.x >> 6, cg = blockIdx.x & 63;
  const float* src = y + ((size_t)b * 512 + cg * 8) * 784;
  bf16* dst = pooled + ((size_t)b * 512 + cg * 8) * 784;
  __shared__ float I[8][870];  // [plane][29 rows * 30 cols], I[r+1][c+1] = inclusive psum
  const int tid = threadIdx.x;
  for (int i = tid; i < 6272; i += 256) {
    int p = i / 784, j = i - p * 784;
    int r = j / 28, c = j - r * 28;
    I[p][(r + 1) * 30 + c + 1] = src[p * 784 + j];
  }
  for (int i = tid; i < 8 * 58; i += 256) {
    int p = i / 58, e = i - p * 58;
    if (e < 30) I[p][e] = 0.f;           // row 0
    else I[p][(e - 29) * 30] = 0.f;      // col 0, rows 1..28
  }
  __syncthreads();
  if (tid < 224) {  // row prefix
    int p = tid / 28, r = tid - (tid / 28) * 28;
    float run = 0.f;
    float* row = &I[p][(r + 1) * 30 + 1];
#pragma unroll
    for (int c = 0; c < 28; ++c) { run += row[c]; row[c] = run; }
  }
  __syncthreads();
  if (tid < 224) {  // col prefix
    int p = tid / 28, c = tid - (tid / 28) * 28;
    float run = 0.f;
    float* col = &I[p][30 + c + 1];
#pragma unroll
    for (int r = 0; r < 28; ++r) { run += col[r * 30]; col[r * 30] = run; }
  }
  __syncthreads();
  for (int i = tid; i < 6272; i += 256) {
    int p = i / 784, j = i - p * 784;
    int r = j / 28, c = j - r * 28;
    const float* Ip = I[p];
    float acc = 0.f;
#pragma unroll
    for (int pk = 1; pk <= 3; ++pk) {
      int r0 = max(r - pk, 0), r1 = min(r + pk, 27) + 1;
      int c0 = max(c - pk, 0), c1 = min(c + pk, 27) + 1;
      float s = Ip[r1 * 30 + c1] - Ip[r0 * 30 + c1] - Ip[r1 * 30 + c0] + Ip[r0 * 30 + c0];
      acc += s * ((pk == 1) ? (1.f / 9.f) : (pk == 2) ? (1.f / 25.f) : (1.f / 49.f));
    }
    dst[p * 784 + j] = __float2bfloat16(acc);
  }
}

// ---------------------------------------------------------------- layernorm + transpose
__global__ __launch_bounds__(256) void ln_kernel(const bf16* __restrict__ pooled,
                                                 const float* __restrict__ gamma,
                                                 const float* __restrict__ beta,
                                                 bf16* __restrict__ yln) {
  const int b = blockIdx.y;
  const int n0 = blockIdx.x * 16;
  __shared__ float tile[16][520];
  __shared__ float smu[16], srs[16];
  const bf16* src = pooled + (size_t)b * 512 * 784;
  for (int idx = threadIdx.x; idx < 512 * 16; idx += 256) {
    int c = idx >> 4, pp = idx & 15;
    tile[pp][c] = __bfloat162float(src[(size_t)c * 784 + n0 + pp]);
  }
  __syncthreads();
  int pp = threadIdx.x >> 4, l = threadIdx.x & 15;
  float s = 0.f, s2 = 0.f;
  for (int c = l; c < 512; c += 16) {
    float v = tile[pp][c];
    s += v;
    s2 += v * v;
  }
#pragma unroll
  for (int off = 8; off; off >>= 1) {
    s += __shfl_xor(s, off, 64);
    s2 += __shfl_xor(s2, off, 64);
  }
  if (l == 0) {
    float mu = s * (1.f / 512.f);
    float var = s2 * (1.f / 512.f) - mu * mu;
    smu[pp] = mu;
    srs[pp] = rsqrtf(var + 1e-5f);
  }
  __syncthreads();
  bf16* dst = yln + ((size_t)b * 784 + n0) * 512;
  for (int idx = threadIdx.x; idx < 512 * 16; idx += 256) {
    int q = idx >> 9, c = idx & 511;
    float v = (tile[q][c] - smu[q]) * srs[q] * gamma[c] + beta[c];
    dst[(size_t)q * 512 + c] = __float2bfloat16(v);
  }
}

// ---------------------------------------------------------------- x transpose (bf16 out)
__global__ __launch_bounds__(256) void xst_kernel(const float* __restrict__ x,
                                                  bf16* __restrict__ xsTb) {
  int idx = blockIdx.x * 256 + threadIdx.x;
  int c = idx & 511;
  int rem = idx >> 9;
  int r = rem % 49, b = rem / 49;
  xsTb[idx] = __float2bfloat16(x[((size_t)b * 512 + c) * 49 + r]);
}

// ---------------------------------------------------------------- W transpose -> bf16 [N][512]
__global__ __launch_bounds__(256) void wt_kernel(const float* __restrict__ W,
                                                 bf16* __restrict__ WT, int N) {
  __shared__ float t[32][33];
  const int n0 = blockIdx.x * 32, k0 = blockIdx.y * 32;
  for (int i = threadIdx.x; i < 1024; i += 256) {
    int kr = i >> 5, nc = i & 31;
    t[kr][nc] = W[(size_t)(k0 + kr) * N + n0 + nc];
  }
  __syncthreads();
  for (int i = threadIdx.x; i < 1024; i += 256) {
    int nr = i >> 5, kc = i & 31;
    WT[(size_t)(n0 + nr) * 512 + k0 + kc] = __float2bfloat16(t[kc][nr]);
  }
}

// ---------------------------------------------------------------- Vt pad zeroing
__global__ __launch_bounds__(256) void vtpad_kernel(bf16* __restrict__ Vt) {
  int idx = blockIdx.x * 256 + threadIdx.x;  // 524288 total
  int row = idx >> 4, c = idx & 15;
  Vt[(size_t)row * 800 + 784 + c] = __float2bfloat16(0.f);
}

// ---------------------------------------------------------------- f32 GEMM (proj only)
DI float4 ldg4(const float* p) { return *reinterpret_cast<const float4*>(p); }

// proj -> o0 f32 [B,512,49] (transposed write) + bias
template <int BM, int BN, int BK, int TM, int TN>
__global__ __launch_bounds__(256) void gemm_k(const float* __restrict__ A, const float* __restrict__ B,
                                              int M, int N, int K, float* __restrict__ o0,
                                              const float* __restrict__ bias) {
  __shared__ float As[BK][BM + 4];
  __shared__ float Bs[BK][BN + 4];
  const int tid = threadIdx.x;
  const int tx = tid & 15, ty = tid >> 4;
  const int m0 = blockIdx.y * BM, n0 = blockIdx.x * BN;
  float acc[TM][TN];
#pragma unroll
  for (int i = 0; i < TM; ++i)
#pragma unroll
    for (int j = 0; j < TN; ++j) acc[i][j] = 0.f;

  for (int k0 = 0; k0 < K; k0 += BK) {
#pragma unroll
    for (int t = 0; t < (BM * BK) / 1024; ++t) {
      int lin = tid * 4 + t * 1024;
      int mm = lin / BK, kk = lin % BK;
      float4 v = ldg4(A + (size_t)(m0 + mm) * K + k0 + kk);
      As[kk + 0][mm] = v.x;
      As[kk + 1][mm] = v.y;
      As[kk + 2][mm] = v.z;
      As[kk + 3][mm] = v.w;
    }
#pragma unroll
    for (int t = 0; t < (BN * BK) / 1024; ++t) {
      int lin = tid * 4 + t * 1024;
      int kk = lin / BN, nn = lin % BN;
      *reinterpret_cast<float4*>(&Bs[kk][nn]) = ldg4(B + (size_t)(k0 + kk) * N + n0 + nn);
    }
    __syncthreads();
#pragma unroll
    for (int kk = 0; kk < BK; ++kk) {
      float a[TM], bb[TN];
#pragma unroll
      for (int i = 0; i < TM; i += 4)
        *reinterpret_cast<float4*>(&a[i]) = *reinterpret_cast<const float4*>(&As[kk][ty * TM + i]);
#pragma unroll
      for (int j = 0; j < TN; j += 4)
        *reinterpret_cast<float4*>(&bb[j]) = *reinterpret_cast<const float4*>(&Bs[kk][tx * TN + j]);
#pragma unroll
      for (int i = 0; i < TM; ++i)
#pragma unroll
        for (int j = 0; j < TN; ++j) acc[i][j] = fmaf(a[i], bb[j], acc[i][j]);
    }
    __syncthreads();
  }
#pragma unroll
  for (int i = 0; i < TM; ++i) {
    int m = m0 + ty * TM + i;
#pragma unroll
    for (int j = 0; j < TN; ++j) {
      int n = n0 + tx * TN + j;
      int b = m / 49, r = m - (m / 49) * 49;
      o0[((size_t)b * 512 + n) * 49 + r] = acc[i][j] + bias[n];
    }
  }
}

// ---------------------------------------------------------------- kv MFMA GEMM
// A = yln bf16 [50176][512], Bt = WkvT bf16 [1024][512]
// out: Kb bf16 [B,8,784,64]; Vt bf16 [B*8, 64, 800] (transposed, pad cols zeroed separately)
#define GLD_LDS16(g, l)                                                              \
  __builtin_amdgcn_global_load_lds((const __attribute__((address_space(1))) unsigned int*)(g), \
                                   (__attribute__((address_space(3))) unsigned int*)(l), 16, 0, 0)

__global__ __launch_bounds__(256) void kv_mfma(const bf16* __restrict__ A,
                                               const bf16* __restrict__ Bt,
                                               bf16* __restrict__ Kb, bf16* __restrict__ Vt) {
  extern __shared__ __align__(16) bf16 smem[];  // 18432 B dynamic
  bf16* As = smem;                              // [128*32]
  bf16* Bs = smem + 128 * 32;                   // [128*32]
  const int tid = threadIdx.x;
  const int lane = tid & 63;
  const int w = tid >> 6, wr = w >> 1, wc = w & 1;

  // XCD swizzle: XCD c handles y-tiles [c*49, c*49+49), all 8 x-tiles (A-tile L2 reuse)
  const int lin = blockIdx.y * 8 + blockIdx.x;
  const int c8 = lin & 7, j = lin >> 3;
  const int ex = j & 7, ey = c8 * 49 + (j >> 3);
  const int m0 = ey * 128, n0 = ex * 128;

  f32x4 acc[4][4];
#pragma unroll
  for (int m = 0; m < 4; ++m)
#pragma unroll
    for (int n = 0; n < 4; ++n) acc[m][n] = f32x4{0.f, 0.f, 0.f, 0.f};

  const int s0 = tid, s1 = tid + 256;  // 16B segments; seg s: row=s>>2, koff=(s&3)*8
  const bf16* Ag0 = A + (size_t)(m0 + (s0 >> 2)) * 512 + (s0 & 3) * 8;
  const bf16* Ag1 = A + (size_t)(m0 + (s1 >> 2)) * 512 + (s1 & 3) * 8;
  const bf16* Bg0 = Bt + (size_t)(n0 + (s0 >> 2)) * 512 + (s0 & 3) * 8;
  const bf16* Bg1 = Bt + (size_t)(n0 + (s1 >> 2)) * 512 + (s1 & 3) * 8;
  bf16* Al0 = As + s0 * 8;
  bf16* Al1 = As + s1 * 8;
  bf16* Bl0 = Bs + s0 * 8;
  bf16* Bl1 = Bs + s1 * 8;

  const int fr = lane & 15;        // fragment row/col within 16
  const int ko = (lane >> 4) * 8;  // k offset within 32
  const int rh = lane >> 4;

  for (int k0 = 0; k0 < 512; k0 += 32) {
    GLD_LDS16(Ag0 + k0, Al0);
    GLD_LDS16(Ag1 + k0, Al1);
    GLD_LDS16(Bg0 + k0, Bl0);
    GLD_LDS16(Bg1 + k0, Bl1);
    __syncthreads();  // vmcnt drained before barrier
    bf16x8 af[4], bfr[4];
#pragma unroll
    for (int m = 0; m < 4; ++m)
      af[m] = *reinterpret_cast<const bf16x8*>(As + (wr * 64 + m * 16 + fr) * 32 + ko);
#pragma unroll
    for (int n = 0; n < 4; ++n)
      bfr[n] = *reinterpret_cast<const bf16x8*>(Bs + (wc * 64 + n * 16 + fr) * 32 + ko);
#pragma unroll
    for (int m = 0; m < 4; ++m)
#pragma unroll
      for (int n = 0; n < 4; ++n)
        acc[m][n] = __builtin_amdgcn_mfma_f32_16x16x32_bf16(af[m], bfr[n], acc[m][n], 0, 0, 0);
    __syncthreads();
  }

  if (n0 < 512) {
    // ---- K epilogue: coalesced [b,h,m,d] writes
#pragma unroll
    for (int m = 0; m < 4; ++m) {
#pragma unroll
      for (int n = 0; n < 4; ++n) {
        int col = n0 + wc * 64 + n * 16 + fr;
        const size_t cbase = ((size_t)(col >> 6)) * (784 * 64) + (col & 63);
#pragma unroll
        for (int r = 0; r < 4; ++r) {
          int row = m0 + wr * 64 + m * 16 + rh * 4 + r;
          int b = row / 784, n1 = row - (row / 784) * 784;
          Kb[((size_t)b * 8) * (784 * 64) + cbase + (size_t)n1 * 64] = __float2bfloat16(acc[m][n][r]);
        }
      }
    }
  } else {
    // ---- V epilogue: LDS-staged transpose -> Vt [b*8+h][d][800]
    bf16* stage = smem;  // [128 cols][72 rows-padded]
#pragma unroll
    for (int p = 0; p < 2; ++p) {
      __syncthreads();
      if (wr == p) {
#pragma unroll
        for (int m = 0; m < 4; ++m) {
#pragma unroll
          for (int n = 0; n < 4; ++n) {
            int coll = wc * 64 + n * 16 + fr;
            int rowl = m * 16 + rh * 4;
            unsigned int u0 = (unsigned int)b2u(acc[m][n][0]) | ((unsigned int)b2u(acc[m][n][1]) << 16);
            unsigned int u1 = (unsigned int)b2u(acc[m][n][2]) | ((unsigned int)b2u(acc[m][n][3]) << 16);
            *reinterpret_cast<uint2*>(stage + coll * 72 + rowl) = make_uint2(u0, u1);
          }
        }
      }
      __syncthreads();
      const int rbase = m0 + p * 64;
      for (int i = tid; i < 1024; i += 256) {
        int cc = i >> 3, tc = i & 7;
        int colg = n0 + cc;  // >= 512
        int h = (colg >> 6) & 7, d = colg & 63;
        int rs = rbase + tc * 8;
        int b = rs / 784, n1 = rs - b * 784;
        bf16x8 val = *reinterpret_cast<const bf16x8*>(stage + cc * 72 + tc * 8);
        bf16* dst = Vt + (((size_t)b * 8 + h) * 64 + d) * 800 + n1;
        if (n1 <= 776) {
          *reinterpret_cast<bf16x8*>(dst) = val;
        } else {
#pragma unroll
          for (int jj = 0; jj < 8; ++jj) {
            int rr = rs + jj;
            int bb2 = rr / 784, nn1 = rr - bb2 * 784;
            bf16 hv;
            *reinterpret_cast<short*>(&hv) = val[jj];
            Vt[(((size_t)bb2 * 8 + h) * 64 + d) * 800 + nn1] = hv;
          }
        }
      }
    }
  }
}

// ---------------------------------------------------------------- Q MFMA GEMM
// A = xsTb bf16 [3200][512] (rows 3136..3199 garbage, stores guarded),
// Bt = WqT bf16 [512][512]; out Qb bf16 [B,8,49,64]
__global__ __launch_bounds__(256) void q_mfma(const bf16* __restrict__ A,
                                              const bf16* __restrict__ Bt,
                                              bf16* __restrict__ Qb) {
  __shared__ __align__(16) bf16 As[128 * 32];
  __shared__ __align__(16) bf16 Bs[128 * 32];
  const int tid = threadIdx.x;
  const int lane = tid & 63;
  const int w = tid >> 6, wr = w >> 1, wc = w & 1;
  const int m0 = blockIdx.y * 128, n0 = blockIdx.x * 128;

  f32x4 acc[4][4];
#pragma unroll
  for (int m = 0; m < 4; ++m)
#pragma unroll
    for (int n = 0; n < 4; ++n) acc[m][n] = f32x4{0.f, 0.f, 0.f, 0.f};

  const int s0 = tid, s1 = tid + 256;
  const bf16* Ag0 = A + (size_t)(m0 + (s0 >> 2)) * 512 + (s0 & 3) * 8;
  const bf16* Ag1 = A + (size_t)(m0 + (s1 >> 2)) * 512 + (s1 & 3) * 8;
  const bf16* Bg0 = Bt + (size_t)(n0 + (s0 >> 2)) * 512 + (s0 & 3) * 8;
  const bf16* Bg1 = Bt + (size_t)(n0 + (s1 >> 2)) * 512 + (s1 & 3) * 8;
  bf16* Al0 = As + s0 * 8;
  bf16* Al1 = As + s1 * 8;
  bf16* Bl0 = Bs + s0 * 8;
  bf16* Bl1 = Bs + s1 * 8;

  const int fr = lane & 15;
  const int ko = (lane >> 4) * 8;
  const int rh = lane >> 4;

  for (int k0 = 0; k0 < 512; k0 += 32) {
    GLD_LDS16(Ag0 + k0, Al0);
    GLD_LDS16(Ag1 + k0, Al1);
    GLD_LDS16(Bg0 + k0, Bl0);
    GLD_LDS16(Bg1 + k0, Bl1);
    __syncthreads();
    bf16x8 af[4], bfr[4];
#pragma unroll
    for (int m = 0; m < 4; ++m)
      af[m] = *reinterpret_cast<const bf16x8*>(As + (wr * 64 + m * 16 + fr) * 32 + ko);
#pragma unroll
    for (int n = 0; n < 4; ++n)
      bfr[n] = *reinterpret_cast<const bf16x8*>(Bs + (wc * 64 + n * 16 + fr) * 32 + ko);
#pragma unroll
    for (int m = 0; m < 4; ++m)
#pragma unroll
      for (int n = 0; n < 4; ++n)
        acc[m][n] = __builtin_amdgcn_mfma_f32_16x16x32_bf16(af[m], bfr[n], acc[m][n], 0, 0, 0);
    __syncthreads();
  }

#pragma unroll
  for (int m = 0; m < 4; ++m) {
#pragma unroll
    for (int n = 0; n < 4; ++n) {
      int col = n0 + wc * 64 + n * 16 + fr;  // 0..511: h=col>>6, d=col&63
      const size_t cbase = ((size_t)(col >> 6)) * (49 * 64) + (col & 63);
#pragma unroll
      for (int r = 0; r < 4; ++r) {
        int row = m0 + wr * 64 + m * 16 + rh * 4 + r;
        if (row < 3136) {
          int b = row / 49, rr = row - (row / 49) * 49;
          Qb[((size_t)b * 8) * (49 * 64) + cbase + (size_t)rr * 64] = __float2bfloat16(acc[m][n][r]);
        }
      }
    }
  }
}

// ---------------------------------------------------------------- attention
// one block = (b,h, chunk of 7 q-rows). MFMA QK^T + MFMA PV; ballot top-k.
__global__ __launch_bounds__(256, 4) void attn_kernel(const bf16* __restrict__ Qb,
                                                      const bf16* __restrict__ K,
                                                      const bf16* __restrict__ Vt,
                                                      const float* __restrict__ aw1p,
                                                      const float* __restrict__ aw2p,
                                                      float* __restrict__ aout) {
  // XCD swizzle: 3584 = 8*448; XCD c gets wk in [c*448,(c+1)*448) => bh in [c*64,(c+1)*64)
  const int lin = blockIdx.x;
  const int wk = (lin & 7) * 448 + (lin >> 3);
  const int bh = wk / 7;
  const int chunk = wk - bh * 7;
  const int b = bh >> 3, h = bh & 7;
  const int r0 = chunk * 7;
  const int tid = threadIdx.x;
  const int lane = tid & 63, w = tid >> 6;
  __shared__ __align__(16) bf16 sQb[16][72];   // rows 7..15 zero
  __shared__ __align__(16) float sLog[7][784];
  __shared__ __align__(16) bf16 sW[16][808];   // bf16 weights; rows 7..15 & cols>=784 zero

  // stage Q (bf16 direct); zero sW rows 7..15
  const bf16* Qp = Qb + ((size_t)bh * 49 + r0) * 64;
  for (int i = tid; i < 1024; i += 256) {
    int r = i >> 6, d = i & 63;
    sQb[r][d] = (r < 7) ? Qp[r * 64 + d] : __float2bfloat16(0.f);
  }
  for (int i = tid; i < 9 * 808; i += 256) {
    int r = i / 808, c = i - r * 808;
    sW[7 + r][c] = __float2bfloat16(0.f);
  }
  __syncthreads();

  // ---- QK^T via MFMA: S[16][784] = Q[16][64] x K^T (NT; K rows = B^T rows)
  const bf16* Kp = K + (size_t)bh * (784 * 64);
  const int fr = lane & 15, ko = (lane >> 4) * 8, rh = lane >> 4;
  {
    const bf16x8 aq0 = *reinterpret_cast<const bf16x8*>(&sQb[fr][ko]);
    const bf16x8 aq1 = *reinterpret_cast<const bf16x8*>(&sQb[fr][32 + ko]);
    const int rbase = rh * 4;
    for (int nt = w; nt < 49; nt += 4) {
      const int n0 = nt * 16;
      const bf16* krow = Kp + (size_t)(n0 + fr) * 64 + ko;
      bf16x8 b0 = *reinterpret_cast<const bf16x8*>(krow);
      bf16x8 b1 = *reinterpret_cast<const bf16x8*>(krow + 32);
      f32x4 acc = {0.f, 0.f, 0.f, 0.f};
      acc = __builtin_amdgcn_mfma_f32_16x16x32_bf16(aq0, b0, acc, 0, 0, 0);
      acc = __builtin_amdgcn_mfma_f32_16x16x32_bf16(aq1, b1, acc, 0, 0, 0);
#pragma unroll
      for (int r = 0; r < 4; ++r) {
        int row = rbase + r;
        if (row < 7) sLog[row][n0 + fr] = acc[r] * 0.125f;
      }
    }
  }
  __syncthreads();

  // ---- top-k + softmax weights (one wave per row) -> bf16 into sW
  const float aw1 = aw1p[0], aw2 = aw2p[0];
  for (int r = w; r < 7; r += 4) {
    float v[13];
    u32x16 key;
#pragma unroll
    for (int i = 0; i < 13; ++i) {
      int m = lane + i * 64;
      v[i] = (m < 784) ? sLog[r][m] : -INFINITY;
      key[i] = fkey(v[i]);
    }
    key[13] = 0u; key[14] = 0u; key[15] = 0u;
    float mx = v[0];
#pragma unroll
    for (int i = 1; i < 13; ++i) mx = fmaxf(mx, v[i]);
    mx = wave_max_f(mx);
    unsigned int thr1 = bisect_topk(key, 392);
    unsigned int thr2 = bisect_topk(key, 261);
    float e[13];
    float z1 = 0.f, z2 = 0.f;
#pragma unroll
    for (int i = 0; i < 13; ++i) {
      e[i] = __expf(v[i] - mx);  // pads: exp(-inf)=0
      if (key[i] >= thr1) z1 += e[i];
      if (key[i] >= thr2) z2 += e[i];
    }
    z1 = wave_sum_f(z1);
    z2 = wave_sum_f(z2);
    const float a1 = aw1 / z1, a2 = aw2 / z2;
#pragma unroll
    for (int i = 0; i < 13; ++i) {
      int m = lane + i * 64;
      if (m < 784) {
        float wgt = e[i] * (((key[i] >= thr1) ? a1 : 0.f) + ((key[i] >= thr2) ? a2 : 0.f));
        sW[r][m] = __float2bfloat16(wgt);
      }
    }
    if (lane < 24) sW[r][784 + lane] = __float2bfloat16(0.f);
  }
  __syncthreads();

  // ---- PV via MFMA: out[16][64] = W[16][800] x V^T; wave w owns d-tile w*16..w*16+16
  const bf16* vbase = Vt + ((size_t)bh * 64 + w * 16 + fr) * 800;
  f32x4 acc = {0.f, 0.f, 0.f, 0.f};
#pragma unroll 5
  for (int ks = 0; ks < 25; ++ks) {
    bf16x8 a = *reinterpret_cast<const bf16x8*>(&sW[fr][ks * 32 + ko]);
    bf16x8 bb = *reinterpret_cast<const bf16x8*>(vbase + ks * 32 + ko);
    acc = __builtin_amdgcn_mfma_f32_16x16x32_bf16(a, bb, acc, 0, 0, 0);
  }
#pragma unroll
  for (int r = 0; r < 4; ++r) {
    int row = rh * 4 + r;
    if (row < 7)
      aout[((size_t)(b * 49 + r0 + row)) * 512 + h * 64 + w * 16 + fr] = acc[r];
  }
}

// ---------------------------------------------------------------- launch
extern "C" void kernel_launch(void* const* d_in, const int* in_sizes, int n_in, void* d_out,
                              int out_size, void* d_ws, size_t ws_size, hipStream_t stream) {
  const float* x = (const float*)d_in[0];
  const float* y = (const float*)d_in[1];
  const float* Wq = (const float*)d_in[2];
  const float* Wkv = (const float*)d_in[3];
  const float* Wproj = (const float*)d_in[4];
  const float* bproj = (const float*)d_in[5];
  const float* gamma = (const float*)d_in[6];
  const float* beta = (const float*)d_in[7];
  const float* aw1 = (const float*)d_in[8];
  const float* aw2 = (const float*)d_in[9];
  float* out = (float*)d_out;

  char* w = (char*)d_ws;
  const size_t SZ = 51380224ull;    // 64*512*784*2 bytes
  const size_t SZV = 52428800ull;   // 64*8*64*800*2 bytes (V^T, padded stride 800)
  bf16* pooled = (bf16*)(w);        // dead after ln
  bf16* yln = (bf16*)(w + SZ);      // dead after kv gemm
  bf16* Kb = (bf16*)(w);            // reuses pooled slot (after ln)
  bf16* Vt = (bf16*)(w + 2 * SZ);
  size_t off = 2 * SZ + SZV;
  bf16* xsTb = (bf16*)(w + off);    off += 3276800;   // [3200][512] bf16 (64 pad rows)
  bf16* Qb = (bf16*)(w + off);      off += 3276800;   // [B,8,49,64] bf16
  float* aout = (float*)(w + off);  off += 6422528;   // [B,49,512] f32
  bf16* wkvT = (bf16*)(w + off);    off += 1048576;   // [1024][512] bf16
  bf16* wqT = (bf16*)(w + off);     off += 524288;    // [512][512] bf16
  // peak ws use: ~162 MB (< prior 174.5 MB)

  wt_kernel<<<dim3(32, 16), dim3(256), 0, stream>>>(Wkv, wkvT, 1024);
  wt_kernel<<<dim3(16, 16), dim3(256), 0, stream>>>(Wq, wqT, 512);
  pool2_kernel<<<dim3(4096), dim3(256), 0, stream>>>(y, pooled);
  vtpad_kernel<<<dim3(2048), dim3(256), 0, stream>>>(Vt);
  ln_kernel<<<dim3(49, 64), dim3(256), 0, stream>>>(pooled, gamma, beta, yln);
  xst_kernel<<<dim3(6272), dim3(256), 0, stream>>>(x, xsTb);
  q_mfma<<<dim3(4, 25), dim3(256), 0, stream>>>(xsTb, wqT, Qb);
  kv_mfma<<<dim3(8, 392), dim3(256), 18432, stream>>>(yln, wkvT, Kb, Vt);
  attn_kernel<<<dim3(3584), dim3(256), 0, stream>>>(Qb, Kb, Vt, aw1, aw2, aout);
  gemm_k<64, 64, 16, 4, 4>
      <<<dim3(8, 49), dim3(256), 0, stream>>>(aout, Wproj, 3136, 512, 512, out, bproj);
}

// Round 6
// 408.529 us; speedup vs baseline: 7.0241x; 1.0113x over previous
//
#include <hip/hip_runtime.h>
#include <hip/hip_bf16.h>

// MSCN fused pipeline, MI355X gfx950. Round 5: attn occupancy (37KB LDS) +
// 4-chain interleaved top-k bisection.
// B=64, C=512, H=W=7 (N=49), HY=WY=28 (N1=784), heads=8, d=64, SCALE=0.125
// kc1 = 784//2 = 392, kc2 = 784//3 = 261

typedef __hip_bfloat16 bf16;
using bf16x8 = __attribute__((ext_vector_type(8))) short;  // 8 bf16 = 4 VGPRs
using f32x4 = __attribute__((ext_vector_type(4))) float;
using u32x16 = __attribute__((ext_vector_type(16))) unsigned int;

#define DI __device__ __forceinline__

DI unsigned short b2u(float f) {
  bf16 h = __float2bfloat16(f);
  return *reinterpret_cast<unsigned short*>(&h);
}

// monotone float->uint key: ascending key order == ascending float order
DI unsigned int fkey(float f) {
  unsigned int u = __float_as_uint(f);
  return (u & 0x80000000u) ? ~u : (u | 0x80000000u);
}
DI float unkey(unsigned int k) {
  unsigned int u = (k & 0x80000000u) ? (k & 0x7FFFFFFFu) : ~k;
  return __uint_as_float(u);
}

// ---------------------------------------------------------------- pool (integral image)
__global__ __launch_bounds__(256) void pool2_kernel(const float* __restrict__ y,
                                                    bf16* __restrict__ pooled) {
  const int b = blockIdx.x >> 6, cg = blockIdx.x & 63;
  const float* src = y + ((size_t)b * 512 + cg * 8) * 784;
  bf16* dst = pooled + ((size_t)b * 512 + cg * 8) * 784;
  __shared__ float I[8][870];  // [plane][29 rows * 30 cols], I[r+1][c+1] = inclusive psum
  const int tid = threadIdx.x;
  for (int i = tid; i < 6272; i += 256) {
    int p = i / 784, j = i - p * 784;
    int r = j / 28, c = j - r * 28;
    I[p][(r + 1) * 30 + c + 1] = src[p * 784 + j];
  }
  for (int i = tid; i < 8 * 58; i += 256) {
    int p = i / 58, e = i - p * 58;
    if (e < 30) I[p][e] = 0.f;           // row 0
    else I[p][(e - 29) * 30] = 0.f;      // col 0, rows 1..28
  }
  __syncthreads();
  if (tid < 224) {  // row prefix
    int p = tid / 28, r = tid - (tid / 28) * 28;
    float run = 0.f;
    float* row = &I[p][(r + 1) * 30 + 1];
#pragma unroll
    for (int c = 0; c < 28; ++c) { run += row[c]; row[c] = run; }
  }
  __syncthreads();
  if (tid < 224) {  // col prefix
    int p = tid / 28, c = tid - (tid / 28) * 28;
    float run = 0.f;
    float* col = &I[p][30 + c + 1];
#pragma unroll
    for (int r = 0; r < 28; ++r) { run += col[r * 30]; col[r * 30] = run; }
  }
  __syncthreads();
  for (int i = tid; i < 6272; i += 256) {
    int p = i / 784, j = i - p * 784;
    int r = j / 28, c = j - r * 28;
    const float* Ip = I[p];
    float acc = 0.f;
#pragma unroll
    for (int pk = 1; pk <= 3; ++pk) {
      int r0 = max(r - pk, 0), r1 = min(r + pk, 27) + 1;
      int c0 = max(c - pk, 0), c1 = min(c + pk, 27) + 1;
      float s = Ip[r1 * 30 + c1] - Ip[r0 * 30 + c1] - Ip[r1 * 30 + c0] + Ip[r0 * 30 + c0];
      acc += s * ((pk == 1) ? (1.f / 9.f) : (pk == 2) ? (1.f / 25.f) : (1.f / 49.f));
    }
    dst[p * 784 + j] = __float2bfloat16(acc);
  }
}

// ---------------------------------------------------------------- layernorm + transpose
__global__ __launch_bounds__(256) void ln_kernel(const bf16* __restrict__ pooled,
                                                 const float* __restrict__ gamma,
                                                 const float* __restrict__ beta,
                                                 bf16* __restrict__ yln) {
  const int b = blockIdx.y;
  const int n0 = blockIdx.x * 16;
  __shared__ float tile[16][520];
  __shared__ float smu[16], srs[16];
  const bf16* src = pooled + (size_t)b * 512 * 784;
  for (int idx = threadIdx.x; idx < 512 * 16; idx += 256) {
    int c = idx >> 4, pp = idx & 15;
    tile[pp][c] = __bfloat162float(src[(size_t)c * 784 + n0 + pp]);
  }
  __syncthreads();
  int pp = threadIdx.x >> 4, l = threadIdx.x & 15;
  float s = 0.f, s2 = 0.f;
  for (int c = l; c < 512; c += 16) {
    float v = tile[pp][c];
    s += v;
    s2 += v * v;
  }
#pragma unroll
  for (int off = 8; off; off >>= 1) {
    s += __shfl_xor(s, off, 64);
    s2 += __shfl_xor(s2, off, 64);
  }
  if (l == 0) {
    float mu = s * (1.f / 512.f);
    float var = s2 * (1.f / 512.f) - mu * mu;
    smu[pp] = mu;
    srs[pp] = rsqrtf(var + 1e-5f);
  }
  __syncthreads();
  bf16* dst = yln + ((size_t)b * 784 + n0) * 512;
  for (int idx = threadIdx.x; idx < 512 * 16; idx += 256) {
    int q = idx >> 9, c = idx & 511;
    float v = (tile[q][c] - smu[q]) * srs[q] * gamma[c] + beta[c];
    dst[(size_t)q * 512 + c] = __float2bfloat16(v);
  }
}

// ---------------------------------------------------------------- x transpose (bf16 out)
__global__ __launch_bounds__(256) void xst_kernel(const float* __restrict__ x,
                                                  bf16* __restrict__ xsTb) {
  int idx = blockIdx.x * 256 + threadIdx.x;
  int c = idx & 511;
  int rem = idx >> 9;
  int r = rem % 49, b = rem / 49;
  xsTb[idx] = __float2bfloat16(x[((size_t)b * 512 + c) * 49 + r]);
}

// ---------------------------------------------------------------- W transpose -> bf16 [N][512]
__global__ __launch_bounds__(256) void wt_kernel(const float* __restrict__ W,
                                                 bf16* __restrict__ WT, int N) {
  __shared__ float t[32][33];
  const int n0 = blockIdx.x * 32, k0 = blockIdx.y * 32;
  for (int i = threadIdx.x; i < 1024; i += 256) {
    int kr = i >> 5, nc = i & 31;
    t[kr][nc] = W[(size_t)(k0 + kr) * N + n0 + nc];
  }
  __syncthreads();
  for (int i = threadIdx.x; i < 1024; i += 256) {
    int nr = i >> 5, kc = i & 31;
    WT[(size_t)(n0 + nr) * 512 + k0 + kc] = __float2bfloat16(t[kc][nr]);
  }
}

// ---------------------------------------------------------------- Vt pad zeroing
__global__ __launch_bounds__(256) void vtpad_kernel(bf16* __restrict__ Vt) {
  int idx = blockIdx.x * 256 + threadIdx.x;  // 524288 total
  int row = idx >> 4, c = idx & 15;
  Vt[(size_t)row * 800 + 784 + c] = __float2bfloat16(0.f);
}

// ---------------------------------------------------------------- f32 GEMM (proj only)
DI float4 ldg4(const float* p) { return *reinterpret_cast<const float4*>(p); }

// proj -> o0 f32 [B,512,49] (transposed write) + bias
template <int BM, int BN, int BK, int TM, int TN>
__global__ __launch_bounds__(256) void gemm_k(const float* __restrict__ A, const float* __restrict__ B,
                                              int M, int N, int K, float* __restrict__ o0,
                                              const float* __restrict__ bias) {
  __shared__ float As[BK][BM + 4];
  __shared__ float Bs[BK][BN + 4];
  const int tid = threadIdx.x;
  const int tx = tid & 15, ty = tid >> 4;
  const int m0 = blockIdx.y * BM, n0 = blockIdx.x * BN;
  float acc[TM][TN];
#pragma unroll
  for (int i = 0; i < TM; ++i)
#pragma unroll
    for (int j = 0; j < TN; ++j) acc[i][j] = 0.f;

  for (int k0 = 0; k0 < K; k0 += BK) {
#pragma unroll
    for (int t = 0; t < (BM * BK) / 1024; ++t) {
      int lin = tid * 4 + t * 1024;
      int mm = lin / BK, kk = lin % BK;
      float4 v = ldg4(A + (size_t)(m0 + mm) * K + k0 + kk);
      As[kk + 0][mm] = v.x;
      As[kk + 1][mm] = v.y;
      As[kk + 2][mm] = v.z;
      As[kk + 3][mm] = v.w;
    }
#pragma unroll
    for (int t = 0; t < (BN * BK) / 1024; ++t) {
      int lin = tid * 4 + t * 1024;
      int kk = lin / BN, nn = lin % BN;
      *reinterpret_cast<float4*>(&Bs[kk][nn]) = ldg4(B + (size_t)(k0 + kk) * N + n0 + nn);
    }
    __syncthreads();
#pragma unroll
    for (int kk = 0; kk < BK; ++kk) {
      float a[TM], bb[TN];
#pragma unroll
      for (int i = 0; i < TM; i += 4)
        *reinterpret_cast<float4*>(&a[i]) = *reinterpret_cast<const float4*>(&As[kk][ty * TM + i]);
#pragma unroll
      for (int j = 0; j < TN; j += 4)
        *reinterpret_cast<float4*>(&bb[j]) = *reinterpret_cast<const float4*>(&Bs[kk][tx * TN + j]);
#pragma unroll
      for (int i = 0; i < TM; ++i)
#pragma unroll
        for (int j = 0; j < TN; ++j) acc[i][j] = fmaf(a[i], bb[j], acc[i][j]);
    }
    __syncthreads();
  }
#pragma unroll
  for (int i = 0; i < TM; ++i) {
    int m = m0 + ty * TM + i;
#pragma unroll
    for (int j = 0; j < TN; ++j) {
      int n = n0 + tx * TN + j;
      int b = m / 49, r = m - (m / 49) * 49;
      o0[((size_t)b * 512 + n) * 49 + r] = acc[i][j] + bias[n];
    }
  }
}

// ---------------------------------------------------------------- kv MFMA GEMM
#define GLD_LDS16(g, l)                                                              \
  __builtin_amdgcn_global_load_lds((const __attribute__((address_space(1))) unsigned int*)(g), \
                                   (__attribute__((address_space(3))) unsigned int*)(l), 16, 0, 0)

__global__ __launch_bounds__(256) void kv_mfma(const bf16* __restrict__ A,
                                               const bf16* __restrict__ Bt,
                                               bf16* __restrict__ Kb, bf16* __restrict__ Vt) {
  extern __shared__ __align__(16) bf16 smem[];  // 18432 B dynamic
  bf16* As = smem;                              // [128*32]
  bf16* Bs = smem + 128 * 32;                   // [128*32]
  const int tid = threadIdx.x;
  const int lane = tid & 63;
  const int w = tid >> 6, wr = w >> 1, wc = w & 1;

  // XCD swizzle: XCD c handles y-tiles [c*49, c*49+49), all 8 x-tiles (A-tile L2 reuse)
  const int lin = blockIdx.y * 8 + blockIdx.x;
  const int c8 = lin & 7, j = lin >> 3;
  const int ex = j & 7, ey = c8 * 49 + (j >> 3);
  const int m0 = ey * 128, n0 = ex * 128;

  f32x4 acc[4][4];
#pragma unroll
  for (int m = 0; m < 4; ++m)
#pragma unroll
    for (int n = 0; n < 4; ++n) acc[m][n] = f32x4{0.f, 0.f, 0.f, 0.f};

  const int s0 = tid, s1 = tid + 256;  // 16B segments; seg s: row=s>>2, koff=(s&3)*8
  const bf16* Ag0 = A + (size_t)(m0 + (s0 >> 2)) * 512 + (s0 & 3) * 8;
  const bf16* Ag1 = A + (size_t)(m0 + (s1 >> 2)) * 512 + (s1 & 3) * 8;
  const bf16* Bg0 = Bt + (size_t)(n0 + (s0 >> 2)) * 512 + (s0 & 3) * 8;
  const bf16* Bg1 = Bt + (size_t)(n0 + (s1 >> 2)) * 512 + (s1 & 3) * 8;
  bf16* Al0 = As + s0 * 8;
  bf16* Al1 = As + s1 * 8;
  bf16* Bl0 = Bs + s0 * 8;
  bf16* Bl1 = Bs + s1 * 8;

  const int fr = lane & 15;        // fragment row/col within 16
  const int ko = (lane >> 4) * 8;  // k offset within 32
  const int rh = lane >> 4;

  for (int k0 = 0; k0 < 512; k0 += 32) {
    GLD_LDS16(Ag0 + k0, Al0);
    GLD_LDS16(Ag1 + k0, Al1);
    GLD_LDS16(Bg0 + k0, Bl0);
    GLD_LDS16(Bg1 + k0, Bl1);
    __syncthreads();  // vmcnt drained before barrier
    bf16x8 af[4], bfr[4];
#pragma unroll
    for (int m = 0; m < 4; ++m)
      af[m] = *reinterpret_cast<const bf16x8*>(As + (wr * 64 + m * 16 + fr) * 32 + ko);
#pragma unroll
    for (int n = 0; n < 4; ++n)
      bfr[n] = *reinterpret_cast<const bf16x8*>(Bs + (wc * 64 + n * 16 + fr) * 32 + ko);
#pragma unroll
    for (int m = 0; m < 4; ++m)
#pragma unroll
      for (int n = 0; n < 4; ++n)
        acc[m][n] = __builtin_amdgcn_mfma_f32_16x16x32_bf16(af[m], bfr[n], acc[m][n], 0, 0, 0);
    __syncthreads();
  }

  if (n0 < 512) {
    // ---- K epilogue: coalesced [b,h,m,d] writes
#pragma unroll
    for (int m = 0; m < 4; ++m) {
#pragma unroll
      for (int n = 0; n < 4; ++n) {
        int col = n0 + wc * 64 + n * 16 + fr;
        const size_t cbase = ((size_t)(col >> 6)) * (784 * 64) + (col & 63);
#pragma unroll
        for (int r = 0; r < 4; ++r) {
          int row = m0 + wr * 64 + m * 16 + rh * 4 + r;
          int b = row / 784, n1 = row - (row / 784) * 784;
          Kb[((size_t)b * 8) * (784 * 64) + cbase + (size_t)n1 * 64] = __float2bfloat16(acc[m][n][r]);
        }
      }
    }
  } else {
    // ---- V epilogue: LDS-staged transpose -> Vt [b*8+h][d][800]
    bf16* stage = smem;  // [128 cols][72 rows-padded]
#pragma unroll
    for (int p = 0; p < 2; ++p) {
      __syncthreads();
      if (wr == p) {
#pragma unroll
        for (int m = 0; m < 4; ++m) {
#pragma unroll
          for (int n = 0; n < 4; ++n) {
            int coll = wc * 64 + n * 16 + fr;
            int rowl = m * 16 + rh * 4;
            unsigned int u0 = (unsigned int)b2u(acc[m][n][0]) | ((unsigned int)b2u(acc[m][n][1]) << 16);
            unsigned int u1 = (unsigned int)b2u(acc[m][n][2]) | ((unsigned int)b2u(acc[m][n][3]) << 16);
            *reinterpret_cast<uint2*>(stage + coll * 72 + rowl) = make_uint2(u0, u1);
          }
        }
      }
      __syncthreads();
      const int rbase = m0 + p * 64;
      for (int i = tid; i < 1024; i += 256) {
        int cc = i >> 3, tc = i & 7;
        int colg = n0 + cc;  // >= 512
        int h = (colg >> 6) & 7, d = colg & 63;
        int rs = rbase + tc * 8;
        int b = rs / 784, n1 = rs - b * 784;
        bf16x8 val = *reinterpret_cast<const bf16x8*>(stage + cc * 72 + tc * 8);
        bf16* dst = Vt + (((size_t)b * 8 + h) * 64 + d) * 800 + n1;
        if (n1 <= 776) {
          *reinterpret_cast<bf16x8*>(dst) = val;
        } else {
#pragma unroll
          for (int jj = 0; jj < 8; ++jj) {
            int rr = rs + jj;
            int bb2 = rr / 784, nn1 = rr - bb2 * 784;
            bf16 hv;
            *reinterpret_cast<short*>(&hv) = val[jj];
            Vt[(((size_t)bb2 * 8 + h) * 64 + d) * 800 + nn1] = hv;
          }
        }
      }
    }
  }
}

// ---------------------------------------------------------------- Q MFMA GEMM
__global__ __launch_bounds__(256) void q_mfma(const bf16* __restrict__ A,
                                              const bf16* __restrict__ Bt,
                                              bf16* __restrict__ Qb) {
  __shared__ __align__(16) bf16 As[128 * 32];
  __shared__ __align__(16) bf16 Bs[128 * 32];
  const int tid = threadIdx.x;
  const int lane = tid & 63;
  const int w = tid >> 6, wr = w >> 1, wc = w & 1;
  const int m0 = blockIdx.y * 128, n0 = blockIdx.x * 128;

  f32x4 acc[4][4];
#pragma unroll
  for (int m = 0; m < 4; ++m)
#pragma unroll
    for (int n = 0; n < 4; ++n) acc[m][n] = f32x4{0.f, 0.f, 0.f, 0.f};

  const int s0 = tid, s1 = tid + 256;
  const bf16* Ag0 = A + (size_t)(m0 + (s0 >> 2)) * 512 + (s0 & 3) * 8;
  const bf16* Ag1 = A + (size_t)(m0 + (s1 >> 2)) * 512 + (s1 & 3) * 8;
  const bf16* Bg0 = Bt + (size_t)(n0 + (s0 >> 2)) * 512 + (s0 & 3) * 8;
  const bf16* Bg1 = Bt + (size_t)(n0 + (s1 >> 2)) * 512 + (s1 & 3) * 8;
  bf16* Al0 = As + s0 * 8;
  bf16* Al1 = As + s1 * 8;
  bf16* Bl0 = Bs + s0 * 8;
  bf16* Bl1 = Bs + s1 * 8;

  const int fr = lane & 15;
  const int ko = (lane >> 4) * 8;
  const int rh = lane >> 4;

  for (int k0 = 0; k0 < 512; k0 += 32) {
    GLD_LDS16(Ag0 + k0, Al0);
    GLD_LDS16(Ag1 + k0, Al1);
    GLD_LDS16(Bg0 + k0, Bl0);
    GLD_LDS16(Bg1 + k0, Bl1);
    __syncthreads();
    bf16x8 af[4], bfr[4];
#pragma unroll
    for (int m = 0; m < 4; ++m)
      af[m] = *reinterpret_cast<const bf16x8*>(As + (wr * 64 + m * 16 + fr) * 32 + ko);
#pragma unroll
    for (int n = 0; n < 4; ++n)
      bfr[n] = *reinterpret_cast<const bf16x8*>(Bs + (wc * 64 + n * 16 + fr) * 32 + ko);
#pragma unroll
    for (int m = 0; m < 4; ++m)
#pragma unroll
      for (int n = 0; n < 4; ++n)
        acc[m][n] = __builtin_amdgcn_mfma_f32_16x16x32_bf16(af[m], bfr[n], acc[m][n], 0, 0, 0);
    __syncthreads();
  }

#pragma unroll
  for (int m = 0; m < 4; ++m) {
#pragma unroll
    for (int n = 0; n < 4; ++n) {
      int col = n0 + wc * 64 + n * 16 + fr;  // 0..511: h=col>>6, d=col&63
      const size_t cbase = ((size_t)(col >> 6)) * (49 * 64) + (col & 63);
#pragma unroll
      for (int r = 0; r < 4; ++r) {
        int row = m0 + wr * 64 + m * 16 + rh * 4 + r;
        if (row < 3136) {
          int b = row / 49, rr = row - (row / 49) * 49;
          Qb[((size_t)b * 8) * (49 * 64) + cbase + (size_t)rr * 64] = __float2bfloat16(acc[m][n][r]);
        }
      }
    }
  }
}

// ---------------------------------------------------------------- attention
// one block = (b,h, chunk of 7 q-rows). MFMA QK^T + MFMA PV; 4-chain ballot top-k.
__global__ __launch_bounds__(256, 4) void attn_kernel(const bf16* __restrict__ Qb,
                                                      const bf16* __restrict__ K,
                                                      const bf16* __restrict__ Vt,
                                                      const float* __restrict__ aw1p,
                                                      const float* __restrict__ aw2p,
                                                      float* __restrict__ aout) {
  // XCD swizzle: 3584 = 8*448; XCD c gets wk in [c*448,(c+1)*448) => bh in [c*64,(c+1)*64)
  const int lin = blockIdx.x;
  const int wk = (lin & 7) * 448 + (lin >> 3);
  const int bh = wk / 7;
  const int chunk = wk - bh * 7;
  const int b = bh >> 3, h = bh & 7;
  const int r0 = chunk * 7;
  const int tid = threadIdx.x;
  const int lane = tid & 63, w = tid >> 6;
  __shared__ __align__(16) bf16 sQb[16][72];   // rows 7..15 zero
  __shared__ __align__(16) float sLog[7][784]; // logits, then e values (in place)
  __shared__ __align__(16) bf16 sW[8][808];    // weights rows 0..6; row 7 zero; cols>=784 zero
  // LDS total: 2304 + 21952 + 12928 = 37184 B -> 4 blocks/CU

  // stage Q (bf16 direct); zero sW row 7
  const bf16* Qp = Qb + ((size_t)bh * 49 + r0) * 64;
  for (int i = tid; i < 1024; i += 256) {
    int r = i >> 6, d = i & 63;
    sQb[r][d] = (r < 7) ? Qp[r * 64 + d] : __float2bfloat16(0.f);
  }
  for (int i = tid; i < 808; i += 256) sW[7][i] = __float2bfloat16(0.f);
  __syncthreads();

  // ---- QK^T via MFMA: S[16][784] = Q[16][64] x K^T (NT; K rows = B^T rows)
  const bf16* Kp = K + (size_t)bh * (784 * 64);
  const int fr = lane & 15, ko = (lane >> 4) * 8, rh = lane >> 4;
  {
    const bf16x8 aq0 = *reinterpret_cast<const bf16x8*>(&sQb[fr][ko]);
    const bf16x8 aq1 = *reinterpret_cast<const bf16x8*>(&sQb[fr][32 + ko]);
    const int rbase = rh * 4;
    for (int nt = w; nt < 49; nt += 4) {
      const int n0 = nt * 16;
      const bf16* krow = Kp + (size_t)(n0 + fr) * 64 + ko;
      bf16x8 b0 = *reinterpret_cast<const bf16x8*>(krow);
      bf16x8 b1 = *reinterpret_cast<const bf16x8*>(krow + 32);
      f32x4 acc = {0.f, 0.f, 0.f, 0.f};
      acc = __builtin_amdgcn_mfma_f32_16x16x32_bf16(aq0, b0, acc, 0, 0, 0);
      acc = __builtin_amdgcn_mfma_f32_16x16x32_bf16(aq1, b1, acc, 0, 0, 0);
#pragma unroll
      for (int r = 0; r < 4; ++r) {
        int row = rbase + r;
        if (row < 7) sLog[row][n0 + fr] = acc[r] * 0.125f;
      }
    }
  }
  __syncthreads();

  // ---- top-k + softmax weights: wave w owns rows {w, w+4}; 4 bisect chains in flight
  const float aw1 = aw1p[0], aw2 = aw2p[0];
  {
    const int ra = w;
    const int rb = (w + 4 < 7) ? (w + 4) : w;  // wave 3 duplicates its row (benign)
    u32x16 ka, kb;
#pragma unroll
    for (int i = 0; i < 13; ++i) {
      int m = lane + i * 64;
      float va = (m < 784) ? sLog[ra][m] : -INFINITY;
      float vb = (m < 784) ? sLog[rb][m] : -INFINITY;
      ka[i] = fkey(va);
      kb[i] = fkey(vb);
    }
    ka[13] = ka[14] = ka[15] = 0u;
    kb[13] = kb[14] = kb[15] = 0u;
    // row max via keys (monotone)
    unsigned int mka = ka[0], mkb = kb[0];
#pragma unroll
    for (int i = 1; i < 13; ++i) {
      mka = max(mka, (unsigned int)ka[i]);
      mkb = max(mkb, (unsigned int)kb[i]);
    }
#pragma unroll
    for (int off = 32; off; off >>= 1) {
      mka = max(mka, (unsigned int)__shfl_xor((int)mka, off, 64));
      mkb = max(mkb, (unsigned int)__shfl_xor((int)mkb, off, 64));
    }
    const float mxa = unkey(mka), mxb = unkey(mkb);
    // 4 interleaved bisections (exact; early-exit per chain when count==k)
    unsigned int t1a = 0u, t2a = 0u, t1b = 0u, t2b = 0u;
    bool d1a = false, d2a = false, d1b = false, d2b = false;
    for (int bit = 31; bit >= 0; --bit) {
      const unsigned int mb = 1u << bit;
      const unsigned int c1a = t1a | mb, c2a = t2a | mb, c1b = t1b | mb, c2b = t2b | mb;
      int n1a = 0, n2a = 0, n1b = 0, n2b = 0;
#pragma unroll
      for (int i = 0; i < 13; ++i) {
        n1a += __popcll(__ballot(ka[i] >= c1a));
        n2a += __popcll(__ballot(ka[i] >= c2a));
        n1b += __popcll(__ballot(kb[i] >= c1b));
        n2b += __popcll(__ballot(kb[i] >= c2b));
      }
      if (!d1a && n1a >= 392) { t1a = c1a; d1a = (n1a == 392); }
      if (!d2a && n2a >= 261) { t2a = c2a; d2a = (n2a == 261); }
      if (!d1b && n1b >= 392) { t1b = c1b; d1b = (n1b == 392); }
      if (!d2b && n2b >= 261) { t2b = c2b; d2b = (n2b == 261); }
      if (d1a & d2a & d1b & d2b) break;
    }
    // pass 1: e = exp(v - mx) written back to sLog; accumulate z per threshold
    float z1a = 0.f, z2a = 0.f, z1b = 0.f, z2b = 0.f;
#pragma unroll
    for (int i = 0; i < 13; ++i) {
      int m = lane + i * 64;
      if (m < 784) {
        float ea = __expf(sLog[ra][m] - mxa);
        float eb = __expf(sLog[rb][m] - mxb);
        sLog[ra][m] = ea;
        sLog[rb][m] = eb;
        if (ka[i] >= t1a) z1a += ea;
        if (ka[i] >= t2a) z2a += ea;
        if (kb[i] >= t1b) z1b += eb;
        if (kb[i] >= t2b) z2b += eb;
      }
    }
#pragma unroll
    for (int off = 32; off; off >>= 1) {
      z1a += __shfl_xor(z1a, off, 64);
      z2a += __shfl_xor(z2a, off, 64);
      z1b += __shfl_xor(z1b, off, 64);
      z2b += __shfl_xor(z2b, off, 64);
    }
    const float a1a = aw1 / z1a, a2a = aw2 / z2a;
    const float a1b = aw1 / z1b, a2b = aw2 / z2b;
    // pass 2: weights -> bf16 sW
#pragma unroll
    for (int i = 0; i < 13; ++i) {
      int m = lane + i * 64;
      if (m < 784) {
        float ea = sLog[ra][m];
        float wa = ea * (((ka[i] >= t1a) ? a1a : 0.f) + ((ka[i] >= t2a) ? a2a : 0.f));
        sW[ra][m] = __float2bfloat16(wa);
        float eb = sLog[rb][m];
        float wb = eb * (((kb[i] >= t1b) ? a1b : 0.f) + ((kb[i] >= t2b) ? a2b : 0.f));
        sW[rb][m] = __float2bfloat16(wb);
      }
    }
    if (lane < 24) {
      sW[ra][784 + lane] = __float2bfloat16(0.f);
      sW[rb][784 + lane] = __float2bfloat16(0.f);
    }
  }
  __syncthreads();

  // ---- PV via MFMA: out[16][64] = W[16][800] x V^T; wave w owns d-tile w*16..w*16+16
  // A-operand rows 7..15 are zero => alias them to zeroed row 7 (LDS broadcast)
  const bf16* wrow = sW[fr < 7 ? fr : 7];
  const bf16* vbase = Vt + ((size_t)bh * 64 + w * 16 + fr) * 800;
  f32x4 acc = {0.f, 0.f, 0.f, 0.f};
#pragma unroll 5
  for (int ks = 0; ks < 25; ++ks) {
    bf16x8 a = *reinterpret_cast<const bf16x8*>(wrow + ks * 32 + ko);
    bf16x8 bb = *reinterpret_cast<const bf16x8*>(vbase + ks * 32 + ko);
    acc = __builtin_amdgcn_mfma_f32_16x16x32_bf16(a, bb, acc, 0, 0, 0);
  }
#pragma unroll
  for (int r = 0; r < 4; ++r) {
    int row = rh * 4 + r;
    if (row < 7)
      aout[((size_t)(b * 49 + r0 + row)) * 512 + h * 64 + w * 16 + fr] = acc[r];
  }
}

// ---------------------------------------------------------------- launch
extern "C" void kernel_launch(void* const* d_in, const int* in_sizes, int n_in, void* d_out,
                              int out_size, void* d_ws, size_t ws_size, hipStream_t stream) {
  const float* x = (const float*)d_in[0];
  const float* y = (const float*)d_in[1];
  const float* Wq = (const float*)d_in[2];
  const float* Wkv = (const float*)d_in[3];
  const float* Wproj = (const float*)d_in[4];
  const float* bproj = (const float*)d_in[5];
  const float* gamma = (const float*)d_in[6];
  const float* beta = (const float*)d_in[7];
  const float* aw1 = (const float*)d_in[8];
  const float* aw2 = (const float*)d_in[9];
  float* out = (float*)d_out;

  char* w = (char*)d_ws;
  const size_t SZ = 51380224ull;    // 64*512*784*2 bytes
  const size_t SZV = 52428800ull;   // 64*8*64*800*2 bytes (V^T, padded stride 800)
  bf16* pooled = (bf16*)(w);        // dead after ln
  bf16* yln = (bf16*)(w + SZ);      // dead after kv gemm
  bf16* Kb = (bf16*)(w);            // reuses pooled slot (after ln)
  bf16* Vt = (bf16*)(w + 2 * SZ);
  size_t off = 2 * SZ + SZV;
  bf16* xsTb = (bf16*)(w + off);    off += 3276800;   // [3200][512] bf16 (64 pad rows)
  bf16* Qb = (bf16*)(w + off);      off += 3276800;   // [B,8,49,64] bf16
  float* aout = (float*)(w + off);  off += 6422528;   // [B,49,512] f32
  bf16* wkvT = (bf16*)(w + off);    off += 1048576;   // [1024][512] bf16
  bf16* wqT = (bf16*)(w + off);     off += 524288;    // [512][512] bf16
  // peak ws use: ~162 MB

  wt_kernel<<<dim3(32, 16), dim3(256), 0, stream>>>(Wkv, wkvT, 1024);
  wt_kernel<<<dim3(16, 16), dim3(256), 0, stream>>>(Wq, wqT, 512);
  pool2_kernel<<<dim3(4096), dim3(256), 0, stream>>>(y, pooled);
  vtpad_kernel<<<dim3(2048), dim3(256), 0, stream>>>(Vt);
  ln_kernel<<<dim3(49, 64), dim3(256), 0, stream>>>(pooled, gamma, beta, yln);
  xst_kernel<<<dim3(6272), dim3(256), 0, stream>>>(x, xsTb);
  q_mfma<<<dim3(4, 25), dim3(256), 0, stream>>>(xsTb, wqT, Qb);
  kv_mfma<<<dim3(8, 392), dim3(256), 18432, stream>>>(yln, wkvT, Kb, Vt);
  attn_kernel<<<dim3(3584), dim3(256), 0, stream>>>(Qb, Kb, Vt, aw1, aw2, aout);
  gemm_k<64, 64, 16, 4, 4>
      <<<dim3(8, 49), dim3(256), 0, stream>>>(aout, Wproj, 3136, 512, 512, out, bproj);
}

// Round 7
// 353.264 us; speedup vs baseline: 8.1230x; 1.1564x over previous
//
#include <hip/hip_runtime.h>
#include <hip/hip_bf16.h>

// MSCN fused pipeline, MI355X gfx950. Round 6: attn LDS-alias + float-domain
// bisection; transposed pool + row LN; proj via hi/lo-split bf16 MFMA.
// B=64, C=512, H=W=7 (N=49), HY=WY=28 (N1=784), heads=8, d=64, SCALE=0.125
// kc1 = 784//2 = 392, kc2 = 784//3 = 261

typedef __hip_bfloat16 bf16;
using bf16x8 = __attribute__((ext_vector_type(8))) short;  // 8 bf16 = 4 VGPRs
using f32x4 = __attribute__((ext_vector_type(4))) float;

#define DI __device__ __forceinline__

DI unsigned short b2u(float f) {
  bf16 h = __float2bfloat16(f);
  return *reinterpret_cast<unsigned short*>(&h);
}
DI float u2f(short s) { return __uint_as_float(((unsigned int)(unsigned short)s) << 16); }

// inverse of the monotone float->uint key map (key = sign? ~u : u|0x80000000)
DI float unkey(unsigned int k) {
  unsigned int u = (k & 0x80000000u) ? (k & 0x7FFFFFFFu) : ~k;
  return __uint_as_float(u);
}

// ---------------------------------------------------------------- pool (integral image, transposed out)
// 8 planes per block; out pooledT [b][784 pixels][512 c] bf16 (16B per pixel-group)
__global__ __launch_bounds__(256) void pool2t_kernel(const float* __restrict__ y,
                                                     bf16* __restrict__ pooledT) {
  const int b = blockIdx.x >> 6, cg = blockIdx.x & 63;
  const float* src = y + ((size_t)b * 512 + cg * 8) * 784;
  bf16* drow = pooledT + ((size_t)b * 784) * 512 + cg * 8;
  __shared__ float I[8][870];  // [plane][29 rows * 30 cols], I[r+1][c+1] = inclusive psum
  const int tid = threadIdx.x;
  for (int i = tid; i < 6272; i += 256) {
    int p = i / 784, j = i - p * 784;
    int r = j / 28, c = j - r * 28;
    I[p][(r + 1) * 30 + c + 1] = src[p * 784 + j];
  }
  for (int i = tid; i < 8 * 58; i += 256) {
    int p = i / 58, e = i - p * 58;
    if (e < 30) I[p][e] = 0.f;           // row 0
    else I[p][(e - 29) * 30] = 0.f;      // col 0, rows 1..28
  }
  __syncthreads();
  if (tid < 224) {  // row prefix
    int p = tid / 28, r = tid - (tid / 28) * 28;
    float run = 0.f;
    float* row = &I[p][(r + 1) * 30 + 1];
#pragma unroll
    for (int c = 0; c < 28; ++c) { run += row[c]; row[c] = run; }
  }
  __syncthreads();
  if (tid < 224) {  // col prefix
    int p = tid / 28, c = tid - (tid / 28) * 28;
    float run = 0.f;
    float* col = &I[p][30 + c + 1];
#pragma unroll
    for (int r = 0; r < 28; ++r) { run += col[r * 30]; col[r * 30] = run; }
  }
  __syncthreads();
  for (int j = tid; j < 784; j += 256) {
    int r = j / 28, c = j - (j / 28) * 28;
    int r0[3], r1[3], c0[3], c1[3];
#pragma unroll
    for (int pk = 1; pk <= 3; ++pk) {
      r0[pk - 1] = max(r - pk, 0) * 30;
      r1[pk - 1] = (min(r + pk, 27) + 1) * 30;
      c0[pk - 1] = max(c - pk, 0);
      c1[pk - 1] = min(c + pk, 27) + 1;
    }
    unsigned int u[4];
#pragma unroll
    for (int q = 0; q < 4; ++q) {
      float vv[2];
#pragma unroll
      for (int t = 0; t < 2; ++t) {
        const float* Ip = I[q * 2 + t];
        float acc = 0.f;
#pragma unroll
        for (int k = 0; k < 3; ++k) {
          float s = Ip[r1[k] + c1[k]] - Ip[r0[k] + c1[k]] - Ip[r1[k] + c0[k]] + Ip[r0[k] + c0[k]];
          acc += s * ((k == 0) ? (1.f / 9.f) : (k == 1) ? (1.f / 25.f) : (1.f / 49.f));
        }
        vv[t] = acc;
      }
      u[q] = (unsigned int)b2u(vv[0]) | ((unsigned int)b2u(vv[1]) << 16);
    }
    *reinterpret_cast<uint4*>(drow + (size_t)j * 512) = make_uint4(u[0], u[1], u[2], u[3]);
  }
}

// ---------------------------------------------------------------- row LayerNorm
// pooledT [50176 rows][512] bf16 -> yln same layout; one wave per row
__global__ __launch_bounds__(256) void lnrow_kernel(const bf16* __restrict__ pooledT,
                                                    const float* __restrict__ gamma,
                                                    const float* __restrict__ beta,
                                                    bf16* __restrict__ yln) {
  const int row = blockIdx.x * 4 + (threadIdx.x >> 6);
  const int lane = threadIdx.x & 63;
  bf16x8 raw = *reinterpret_cast<const bf16x8*>(pooledT + (size_t)row * 512 + lane * 8);
  float v[8];
  float s = 0.f, s2 = 0.f;
#pragma unroll
  for (int j = 0; j < 8; ++j) {
    v[j] = u2f(raw[j]);
    s += v[j];
    s2 += v[j] * v[j];
  }
#pragma unroll
  for (int off = 32; off; off >>= 1) {
    s += __shfl_xor(s, off, 64);
    s2 += __shfl_xor(s2, off, 64);
  }
  float mu = s * (1.f / 512.f);
  float rs = rsqrtf(s2 * (1.f / 512.f) - mu * mu + 1e-5f);
  float4 g0 = *reinterpret_cast<const float4*>(gamma + lane * 8);
  float4 g1 = *reinterpret_cast<const float4*>(gamma + lane * 8 + 4);
  float4 e0 = *reinterpret_cast<const float4*>(beta + lane * 8);
  float4 e1 = *reinterpret_cast<const float4*>(beta + lane * 8 + 4);
  float gg[8] = {g0.x, g0.y, g0.z, g0.w, g1.x, g1.y, g1.z, g1.w};
  float bb[8] = {e0.x, e0.y, e0.z, e0.w, e1.x, e1.y, e1.z, e1.w};
  unsigned int u[4];
#pragma unroll
  for (int q = 0; q < 4; ++q) {
    float o0 = (v[2 * q] - mu) * rs * gg[2 * q] + bb[2 * q];
    float o1 = (v[2 * q + 1] - mu) * rs * gg[2 * q + 1] + bb[2 * q + 1];
    u[q] = (unsigned int)b2u(o0) | ((unsigned int)b2u(o1) << 16);
  }
  *reinterpret_cast<uint4*>(yln + (size_t)row * 512 + lane * 8) = make_uint4(u[0], u[1], u[2], u[3]);
}

// ---------------------------------------------------------------- x transpose (bf16 out)
__global__ __launch_bounds__(256) void xst_kernel(const float* __restrict__ x,
                                                  bf16* __restrict__ xsTb) {
  int idx = blockIdx.x * 256 + threadIdx.x;
  int c = idx & 511;
  int rem = idx >> 9;
  int r = rem % 49, b = rem / 49;
  xsTb[idx] = __float2bfloat16(x[((size_t)b * 512 + c) * 49 + r]);
}

// ---------------------------------------------------------------- W transpose -> bf16 [N][512]
__global__ __launch_bounds__(256) void wt_kernel(const float* __restrict__ W,
                                                 bf16* __restrict__ WT, int N) {
  __shared__ float t[32][33];
  const int n0 = blockIdx.x * 32, k0 = blockIdx.y * 32;
  for (int i = threadIdx.x; i < 1024; i += 256) {
    int kr = i >> 5, nc = i & 31;
    t[kr][nc] = W[(size_t)(k0 + kr) * N + n0 + nc];
  }
  __syncthreads();
  for (int i = threadIdx.x; i < 1024; i += 256) {
    int nr = i >> 5, kc = i & 31;
    WT[(size_t)(n0 + nr) * 512 + k0 + kc] = __float2bfloat16(t[kc][nr]);
  }
}

// ---------------------------------------------------------------- Vt pad zeroing
__global__ __launch_bounds__(256) void vtpad_kernel(bf16* __restrict__ Vt) {
  int idx = blockIdx.x * 256 + threadIdx.x;  // 524288 total
  int row = idx >> 4, c = idx & 15;
  Vt[(size_t)row * 800 + 784 + c] = __float2bfloat16(0.f);
}

// ---------------------------------------------------------------- kv MFMA GEMM
#define GLD_LDS16(g, l)                                                              \
  __builtin_amdgcn_global_load_lds((const __attribute__((address_space(1))) unsigned int*)(g), \
                                   (__attribute__((address_space(3))) unsigned int*)(l), 16, 0, 0)

__global__ __launch_bounds__(256) void kv_mfma(const bf16* __restrict__ A,
                                               const bf16* __restrict__ Bt,
                                               bf16* __restrict__ Kb, bf16* __restrict__ Vt) {
  extern __shared__ __align__(16) bf16 smem[];  // 18432 B dynamic
  bf16* As = smem;                              // [128*32]
  bf16* Bs = smem + 128 * 32;                   // [128*32]
  const int tid = threadIdx.x;
  const int lane = tid & 63;
  const int w = tid >> 6, wr = w >> 1, wc = w & 1;

  // XCD swizzle: XCD c handles y-tiles [c*49, c*49+49), all 8 x-tiles (A-tile L2 reuse)
  const int lin = blockIdx.y * 8 + blockIdx.x;
  const int c8 = lin & 7, j = lin >> 3;
  const int ex = j & 7, ey = c8 * 49 + (j >> 3);
  const int m0 = ey * 128, n0 = ex * 128;

  f32x4 acc[4][4];
#pragma unroll
  for (int m = 0; m < 4; ++m)
#pragma unroll
    for (int n = 0; n < 4; ++n) acc[m][n] = f32x4{0.f, 0.f, 0.f, 0.f};

  const int s0 = tid, s1 = tid + 256;  // 16B segments; seg s: row=s>>2, koff=(s&3)*8
  const bf16* Ag0 = A + (size_t)(m0 + (s0 >> 2)) * 512 + (s0 & 3) * 8;
  const bf16* Ag1 = A + (size_t)(m0 + (s1 >> 2)) * 512 + (s1 & 3) * 8;
  const bf16* Bg0 = Bt + (size_t)(n0 + (s0 >> 2)) * 512 + (s0 & 3) * 8;
  const bf16* Bg1 = Bt + (size_t)(n0 + (s1 >> 2)) * 512 + (s1 & 3) * 8;
  bf16* Al0 = As + s0 * 8;
  bf16* Al1 = As + s1 * 8;
  bf16* Bl0 = Bs + s0 * 8;
  bf16* Bl1 = Bs + s1 * 8;

  const int fr = lane & 15;        // fragment row/col within 16
  const int ko = (lane >> 4) * 8;  // k offset within 32
  const int rh = lane >> 4;

  for (int k0 = 0; k0 < 512; k0 += 32) {
    GLD_LDS16(Ag0 + k0, Al0);
    GLD_LDS16(Ag1 + k0, Al1);
    GLD_LDS16(Bg0 + k0, Bl0);
    GLD_LDS16(Bg1 + k0, Bl1);
    __syncthreads();  // vmcnt drained before barrier
    bf16x8 af[4], bfr[4];
#pragma unroll
    for (int m = 0; m < 4; ++m)
      af[m] = *reinterpret_cast<const bf16x8*>(As + (wr * 64 + m * 16 + fr) * 32 + ko);
#pragma unroll
    for (int n = 0; n < 4; ++n)
      bfr[n] = *reinterpret_cast<const bf16x8*>(Bs + (wc * 64 + n * 16 + fr) * 32 + ko);
#pragma unroll
    for (int m = 0; m < 4; ++m)
#pragma unroll
      for (int n = 0; n < 4; ++n)
        acc[m][n] = __builtin_amdgcn_mfma_f32_16x16x32_bf16(af[m], bfr[n], acc[m][n], 0, 0, 0);
    __syncthreads();
  }

  if (n0 < 512) {
    // ---- K epilogue: coalesced [b,h,m,d] writes
#pragma unroll
    for (int m = 0; m < 4; ++m) {
#pragma unroll
      for (int n = 0; n < 4; ++n) {
        int col = n0 + wc * 64 + n * 16 + fr;
        const size_t cbase = ((size_t)(col >> 6)) * (784 * 64) + (col & 63);
#pragma unroll
        for (int r = 0; r < 4; ++r) {
          int row = m0 + wr * 64 + m * 16 + rh * 4 + r;
          int b = row / 784, n1 = row - (row / 784) * 784;
          Kb[((size_t)b * 8) * (784 * 64) + cbase + (size_t)n1 * 64] = __float2bfloat16(acc[m][n][r]);
        }
      }
    }
  } else {
    // ---- V epilogue: LDS-staged transpose -> Vt [b*8+h][d][800]
    bf16* stage = smem;  // [128 cols][72 rows-padded]
#pragma unroll
    for (int p = 0; p < 2; ++p) {
      __syncthreads();
      if (wr == p) {
#pragma unroll
        for (int m = 0; m < 4; ++m) {
#pragma unroll
          for (int n = 0; n < 4; ++n) {
            int coll = wc * 64 + n * 16 + fr;
            int rowl = m * 16 + rh * 4;
            unsigned int u0 = (unsigned int)b2u(acc[m][n][0]) | ((unsigned int)b2u(acc[m][n][1]) << 16);
            unsigned int u1 = (unsigned int)b2u(acc[m][n][2]) | ((unsigned int)b2u(acc[m][n][3]) << 16);
            *reinterpret_cast<uint2*>(stage + coll * 72 + rowl) = make_uint2(u0, u1);
          }
        }
      }
      __syncthreads();
      const int rbase = m0 + p * 64;
      for (int i = tid; i < 1024; i += 256) {
        int cc = i >> 3, tc = i & 7;
        int colg = n0 + cc;  // >= 512
        int h = (colg >> 6) & 7, d = colg & 63;
        int rs = rbase + tc * 8;
        int b = rs / 784, n1 = rs - b * 784;
        bf16x8 val = *reinterpret_cast<const bf16x8*>(stage + cc * 72 + tc * 8);
        bf16* dst = Vt + (((size_t)b * 8 + h) * 64 + d) * 800 + n1;
        if (n1 <= 776) {
          *reinterpret_cast<bf16x8*>(dst) = val;
        } else {
#pragma unroll
          for (int jj = 0; jj < 8; ++jj) {
            int rr = rs + jj;
            int bb2 = rr / 784, nn1 = rr - bb2 * 784;
            bf16 hv;
            *reinterpret_cast<short*>(&hv) = val[jj];
            Vt[(((size_t)bb2 * 8 + h) * 64 + d) * 800 + nn1] = hv;
          }
        }
      }
    }
  }
}

// ---------------------------------------------------------------- Q MFMA GEMM
__global__ __launch_bounds__(256) void q_mfma(const bf16* __restrict__ A,
                                              const bf16* __restrict__ Bt,
                                              bf16* __restrict__ Qb) {
  __shared__ __align__(16) bf16 As[128 * 32];
  __shared__ __align__(16) bf16 Bs[128 * 32];
  const int tid = threadIdx.x;
  const int lane = tid & 63;
  const int w = tid >> 6, wr = w >> 1, wc = w & 1;
  const int m0 = blockIdx.y * 128, n0 = blockIdx.x * 128;

  f32x4 acc[4][4];
#pragma unroll
  for (int m = 0; m < 4; ++m)
#pragma unroll
    for (int n = 0; n < 4; ++n) acc[m][n] = f32x4{0.f, 0.f, 0.f, 0.f};

  const int s0 = tid, s1 = tid + 256;
  const bf16* Ag0 = A + (size_t)(m0 + (s0 >> 2)) * 512 + (s0 & 3) * 8;
  const bf16* Ag1 = A + (size_t)(m0 + (s1 >> 2)) * 512 + (s1 & 3) * 8;
  const bf16* Bg0 = Bt + (size_t)(n0 + (s0 >> 2)) * 512 + (s0 & 3) * 8;
  const bf16* Bg1 = Bt + (size_t)(n0 + (s1 >> 2)) * 512 + (s1 & 3) * 8;
  bf16* Al0 = As + s0 * 8;
  bf16* Al1 = As + s1 * 8;
  bf16* Bl0 = Bs + s0 * 8;
  bf16* Bl1 = Bs + s1 * 8;

  const int fr = lane & 15;
  const int ko = (lane >> 4) * 8;
  const int rh = lane >> 4;

  for (int k0 = 0; k0 < 512; k0 += 32) {
    GLD_LDS16(Ag0 + k0, Al0);
    GLD_LDS16(Ag1 + k0, Al1);
    GLD_LDS16(Bg0 + k0, Bl0);
    GLD_LDS16(Bg1 + k0, Bl1);
    __syncthreads();
    bf16x8 af[4], bfr[4];
#pragma unroll
    for (int m = 0; m < 4; ++m)
      af[m] = *reinterpret_cast<const bf16x8*>(As + (wr * 64 + m * 16 + fr) * 32 + ko);
#pragma unroll
    for (int n = 0; n < 4; ++n)
      bfr[n] = *reinterpret_cast<const bf16x8*>(Bs + (wc * 64 + n * 16 + fr) * 32 + ko);
#pragma unroll
    for (int m = 0; m < 4; ++m)
#pragma unroll
      for (int n = 0; n < 4; ++n)
        acc[m][n] = __builtin_amdgcn_mfma_f32_16x16x32_bf16(af[m], bfr[n], acc[m][n], 0, 0, 0);
    __syncthreads();
  }

#pragma unroll
  for (int m = 0; m < 4; ++m) {
#pragma unroll
    for (int n = 0; n < 4; ++n) {
      int col = n0 + wc * 64 + n * 16 + fr;  // 0..511: h=col>>6, d=col&63
      const size_t cbase = ((size_t)(col >> 6)) * (49 * 64) + (col & 63);
#pragma unroll
      for (int r = 0; r < 4; ++r) {
        int row = m0 + wr * 64 + m * 16 + rh * 4 + r;
        if (row < 3136) {
          int b = row / 49, rr = row - (row / 49) * 49;
          Qb[((size_t)b * 8) * (49 * 64) + cbase + (size_t)rr * 64] = __float2bfloat16(acc[m][n][r]);
        }
      }
    }
  }
}

// ---------------------------------------------------------------- proj MFMA GEMM
// A = aoutHL bf16 [3200][1024] (hi cols 0..511, lo cols 512..1023; rows>=3136 garbage),
// Bt = wpT bf16 [512][512]; emulates K=1024 with W stacked twice via (k & 511).
// out f32 [B,512,49] transposed + bias.
__global__ __launch_bounds__(256) void proj_mfma(const bf16* __restrict__ A,
                                                 const bf16* __restrict__ Bt,
                                                 const float* __restrict__ bias,
                                                 float* __restrict__ out) {
  __shared__ __align__(16) bf16 As[128 * 32];
  __shared__ __align__(16) bf16 Bs[128 * 32];
  const int tid = threadIdx.x;
  const int lane = tid & 63;
  const int w = tid >> 6, wr = w >> 1, wc = w & 1;
  const int m0 = blockIdx.y * 128, n0 = blockIdx.x * 128;

  f32x4 acc[4][4];
#pragma unroll
  for (int m = 0; m < 4; ++m)
#pragma unroll
    for (int n = 0; n < 4; ++n) acc[m][n] = f32x4{0.f, 0.f, 0.f, 0.f};

  const int s0 = tid, s1 = tid + 256;
  const bf16* Ag0 = A + (size_t)(m0 + (s0 >> 2)) * 1024 + (s0 & 3) * 8;
  const bf16* Ag1 = A + (size_t)(m0 + (s1 >> 2)) * 1024 + (s1 & 3) * 8;
  const bf16* Bg0 = Bt + (size_t)(n0 + (s0 >> 2)) * 512 + (s0 & 3) * 8;
  const bf16* Bg1 = Bt + (size_t)(n0 + (s1 >> 2)) * 512 + (s1 & 3) * 8;
  bf16* Al0 = As + s0 * 8;
  bf16* Al1 = As + s1 * 8;
  bf16* Bl0 = Bs + s0 * 8;
  bf16* Bl1 = Bs + s1 * 8;

  const int fr = lane & 15;
  const int ko = (lane >> 4) * 8;
  const int rh = lane >> 4;

  for (int k0 = 0; k0 < 1024; k0 += 32) {
    GLD_LDS16(Ag0 + k0, Al0);
    GLD_LDS16(Ag1 + k0, Al1);
    GLD_LDS16(Bg0 + (k0 & 511), Bl0);
    GLD_LDS16(Bg1 + (k0 & 511), Bl1);
    __syncthreads();
    bf16x8 af[4], bfr[4];
#pragma unroll
    for (int m = 0; m < 4; ++m)
      af[m] = *reinterpret_cast<const bf16x8*>(As + (wr * 64 + m * 16 + fr) * 32 + ko);
#pragma unroll
    for (int n = 0; n < 4; ++n)
      bfr[n] = *reinterpret_cast<const bf16x8*>(Bs + (wc * 64 + n * 16 + fr) * 32 + ko);
#pragma unroll
    for (int m = 0; m < 4; ++m)
#pragma unroll
      for (int n = 0; n < 4; ++n)
        acc[m][n] = __builtin_amdgcn_mfma_f32_16x16x32_bf16(af[m], bfr[n], acc[m][n], 0, 0, 0);
    __syncthreads();
  }

#pragma unroll
  for (int m = 0; m < 4; ++m) {
#pragma unroll
    for (int n = 0; n < 4; ++n) {
      int col = n0 + wc * 64 + n * 16 + fr;
      float bv = bias[col];
#pragma unroll
      for (int r = 0; r < 4; ++r) {
        int row = m0 + wr * 64 + m * 16 + rh * 4 + r;
        if (row < 3136) {
          int b = row / 49, rr = row - (row / 49) * 49;
          out[((size_t)b * 512 + col) * 49 + rr] = acc[m][n][r] + bv;
        }
      }
    }
  }
}

// ---------------------------------------------------------------- attention
// one block = (b,h, chunk of 7 q-rows). MFMA QK^T + MFMA PV; float-domain
// bisection top-k; sW aliases sLog (logits consumed into registers first).
__global__ __launch_bounds__(256, 6) void attn_kernel(const bf16* __restrict__ Qb,
                                                      const bf16* __restrict__ K,
                                                      const bf16* __restrict__ Vt,
                                                      const float* __restrict__ aw1p,
                                                      const float* __restrict__ aw2p,
                                                      bf16* __restrict__ aoutHL) {
  // XCD swizzle: 3584 = 8*448; XCD c gets wk in [c*448,(c+1)*448) => bh in [c*64,(c+1)*64)
  const int lin = blockIdx.x;
  const int wk = (lin & 7) * 448 + (lin >> 3);
  const int bh = wk / 7;
  const int chunk = wk - bh * 7;
  const int b = bh >> 3, h = bh & 7;
  const int r0 = chunk * 7;
  const int tid = threadIdx.x;
  const int lane = tid & 63, w = tid >> 6;
  __shared__ __align__(16) bf16 sQb[16][72];        // 2304 B, rows 7..15 zero
  __shared__ __align__(16) unsigned char sMem[21952];  // union: sLog f32[7][784] / sW bf16[8][808]
  float* sLog = reinterpret_cast<float*>(sMem);
  bf16* sW = reinterpret_cast<bf16*>(sMem);
  // LDS total ~24.3 KB -> 6 blocks/CU

  // stage Q (bf16 direct, zero-padded rows)
  const bf16* Qp = Qb + ((size_t)bh * 49 + r0) * 64;
  for (int i = tid; i < 1024; i += 256) {
    int r = i >> 6, d = i & 63;
    sQb[r][d] = (r < 7) ? Qp[r * 64 + d] : __float2bfloat16(0.f);
  }
  __syncthreads();

  // ---- QK^T via MFMA: S[16][784] = Q[16][64] x K^T (NT; K rows = B^T rows)
  const bf16* Kp = K + (size_t)bh * (784 * 64);
  const int fr = lane & 15, ko = (lane >> 4) * 8, rh = lane >> 4;
  {
    const bf16x8 aq0 = *reinterpret_cast<const bf16x8*>(&sQb[fr][ko]);
    const bf16x8 aq1 = *reinterpret_cast<const bf16x8*>(&sQb[fr][32 + ko]);
    const int rbase = rh * 4;
    for (int nt = w; nt < 49; nt += 4) {
      const int n0 = nt * 16;
      const bf16* krow = Kp + (size_t)(n0 + fr) * 64 + ko;
      bf16x8 b0 = *reinterpret_cast<const bf16x8*>(krow);
      bf16x8 b1 = *reinterpret_cast<const bf16x8*>(krow + 32);
      f32x4 acc = {0.f, 0.f, 0.f, 0.f};
      acc = __builtin_amdgcn_mfma_f32_16x16x32_bf16(aq0, b0, acc, 0, 0, 0);
      acc = __builtin_amdgcn_mfma_f32_16x16x32_bf16(aq1, b1, acc, 0, 0, 0);
#pragma unroll
      for (int r = 0; r < 4; ++r) {
        int row = rbase + r;
        if (row < 7) sLog[row * 784 + n0 + fr] = acc[r] * 0.125f;
      }
    }
  }
  __syncthreads();

  // ---- load logits for this wave's two rows into registers
  const int ra = w;
  const int rb = (w + 4 < 7) ? (w + 4) : w;  // wave 3 duplicates its row (benign)
  float va[13], vb[13];
#pragma unroll
  for (int i = 0; i < 13; ++i) {
    int m = lane + i * 64;
    va[i] = (m < 784) ? sLog[ra * 784 + m] : -INFINITY;
    vb[i] = (m < 784) ? sLog[rb * 784 + m] : -INFINITY;
  }
  __syncthreads();  // sLog fully consumed; sW aliasing writes may begin

  // row max
  float mxa = va[0], mxb = vb[0];
#pragma unroll
  for (int i = 1; i < 13; ++i) {
    mxa = fmaxf(mxa, va[i]);
    mxb = fmaxf(mxb, vb[i]);
  }
#pragma unroll
  for (int off = 32; off; off >>= 1) {
    mxa = fmaxf(mxa, __shfl_xor(mxa, off, 64));
    mxb = fmaxf(mxb, __shfl_xor(mxb, off, 64));
  }

  // ---- 4 bisection chains in key space, compares in the float domain.
  // Equivalence: v >= unkey(cand) <=> key(v) >= cand (monotone bijection on
  // finite floats; candidates stay in the finite-key region for finite data).
  // Early exit when count==k is exact; ties fall to full bisection -> >= kth
  // semantics identical to reference.
  unsigned int t1a = 0u, t2a = 0u, t1b = 0u, t2b = 0u;
  bool d1a = false, d2a = false, d1b = false, d2b = false;
  for (int bit = 31; bit >= 0; --bit) {
    const unsigned int mb = 1u << bit;
    if (!d1a) {
      float cf = unkey(t1a | mb);
      int n = 0;
#pragma unroll
      for (int i = 0; i < 13; ++i) n += __popcll(__ballot(va[i] >= cf));
      if (n >= 392) { t1a |= mb; d1a = (n == 392); }
    }
    if (!d2a) {
      float cf = unkey(t2a | mb);
      int n = 0;
#pragma unroll
      for (int i = 0; i < 13; ++i) n += __popcll(__ballot(va[i] >= cf));
      if (n >= 261) { t2a |= mb; d2a = (n == 261); }
    }
    if (!d1b) {
      float cf = unkey(t1b | mb);
      int n = 0;
#pragma unroll
      for (int i = 0; i < 13; ++i) n += __popcll(__ballot(vb[i] >= cf));
      if (n >= 392) { t1b |= mb; d1b = (n == 392); }
    }
    if (!d2b) {
      float cf = unkey(t2b | mb);
      int n = 0;
#pragma unroll
      for (int i = 0; i < 13; ++i) n += __popcll(__ballot(vb[i] >= cf));
      if (n >= 261) { t2b |= mb; d2b = (n == 261); }
    }
    if (d1a & d2a & d1b & d2b) break;
  }
  const float T1a = unkey(t1a), T2a = unkey(t2a);
  const float T1b = unkey(t1b), T2b = unkey(t2b);

  // ---- fused exp + z + weights (e kept in registers)
  const float aw1 = aw1p[0], aw2 = aw2p[0];
  float ea[13], eb[13];
  float z1a = 0.f, z2a = 0.f, z1b = 0.f, z2b = 0.f;
#pragma unroll
  for (int i = 0; i < 13; ++i) {
    ea[i] = __expf(va[i] - mxa);  // pads: exp(-inf)=0
    eb[i] = __expf(vb[i] - mxb);
    if (va[i] >= T1a) z1a += ea[i];
    if (va[i] >= T2a) z2a += ea[i];
    if (vb[i] >= T1b) z1b += eb[i];
    if (vb[i] >= T2b) z2b += eb[i];
  }
#pragma unroll
  for (int off = 32; off; off >>= 1) {
    z1a += __shfl_xor(z1a, off, 64);
    z2a += __shfl_xor(z2a, off, 64);
    z1b += __shfl_xor(z1b, off, 64);
    z2b += __shfl_xor(z2b, off, 64);
  }
  const float a1a = aw1 / z1a, a2a = aw2 / z2a;
  const float a1b = aw1 / z1b, a2b = aw2 / z2b;
#pragma unroll
  for (int i = 0; i < 13; ++i) {
    int m = lane + i * 64;
    if (m < 784) {
      float wa = ea[i] * (((va[i] >= T1a) ? a1a : 0.f) + ((va[i] >= T2a) ? a2a : 0.f));
      sW[ra * 808 + m] = __float2bfloat16(wa);
      float wb = eb[i] * (((vb[i] >= T1b) ? a1b : 0.f) + ((vb[i] >= T2b) ? a2b : 0.f));
      sW[rb * 808 + m] = __float2bfloat16(wb);
    }
  }
  if (lane < 16) {
    sW[ra * 808 + 784 + lane] = __float2bfloat16(0.f);
    sW[rb * 808 + 784 + lane] = __float2bfloat16(0.f);
  }
  if (w == 3)
    for (int i = lane; i < 808; i += 64) sW[7 * 808 + i] = __float2bfloat16(0.f);
  __syncthreads();

  // ---- PV via MFMA: out[16][64] = W[16][800] x V^T; wave w owns d-tile w*16..w*16+16
  // A-operand rows 7..15 are zero => alias to zeroed row 7 (LDS broadcast)
  const bf16* wrow = sW + (fr < 7 ? fr : 7) * 808;
  const bf16* vbase = Vt + ((size_t)bh * 64 + w * 16 + fr) * 800;
  f32x4 acc = {0.f, 0.f, 0.f, 0.f};
#pragma unroll 5
  for (int ks = 0; ks < 25; ++ks) {
    bf16x8 a = *reinterpret_cast<const bf16x8*>(wrow + ks * 32 + ko);
    bf16x8 bb = *reinterpret_cast<const bf16x8*>(vbase + ks * 32 + ko);
    acc = __builtin_amdgcn_mfma_f32_16x16x32_bf16(a, bb, acc, 0, 0, 0);
  }
#pragma unroll
  for (int r = 0; r < 4; ++r) {
    int row = rh * 4 + r;
    if (row < 7) {
      float v = acc[r];
      bf16 hi = __float2bfloat16(v);
      bf16 lo = __float2bfloat16(v - __bfloat162float(hi));
      size_t base = ((size_t)(b * 49 + r0 + row)) * 1024 + h * 64 + w * 16 + fr;
      aoutHL[base] = hi;
      aoutHL[base + 512] = lo;
    }
  }
}

// ---------------------------------------------------------------- launch
extern "C" void kernel_launch(void* const* d_in, const int* in_sizes, int n_in, void* d_out,
                              int out_size, void* d_ws, size_t ws_size, hipStream_t stream) {
  const float* x = (const float*)d_in[0];
  const float* y = (const float*)d_in[1];
  const float* Wq = (const float*)d_in[2];
  const float* Wkv = (const float*)d_in[3];
  const float* Wproj = (const float*)d_in[4];
  const float* bproj = (const float*)d_in[5];
  const float* gamma = (const float*)d_in[6];
  const float* beta = (const float*)d_in[7];
  const float* aw1 = (const float*)d_in[8];
  const float* aw2 = (const float*)d_in[9];
  float* out = (float*)d_out;

  char* w = (char*)d_ws;
  const size_t SZ = 51380224ull;    // 64*784*512*2 bytes
  const size_t SZV = 52428800ull;   // 64*8*64*800*2 bytes (V^T, padded stride 800)
  bf16* pooledT = (bf16*)(w);       // [50176][512]; dead after lnrow
  bf16* yln = (bf16*)(w + SZ);      // [50176][512]; dead after kv gemm
  bf16* Kb = (bf16*)(w);            // reuses pooledT slot (after lnrow)
  bf16* Vt = (bf16*)(w + 2 * SZ);
  size_t off = 2 * SZ + SZV;
  bf16* xsTb = (bf16*)(w + off);    off += 3276800;   // [3200][512] bf16 (64 pad rows)
  bf16* Qb = (bf16*)(w + off);      off += 3276800;   // [B,8,49,64] bf16
  bf16* aoutHL = (bf16*)(w + off);  off += 6553600;   // [3200][1024] bf16 (hi|lo)
  bf16* wkvT = (bf16*)(w + off);    off += 1048576;   // [1024][512] bf16
  bf16* wqT = (bf16*)(w + off);     off += 524288;    // [512][512] bf16
  bf16* wpT = (bf16*)(w + off);     off += 524288;    // [512][512] bf16
  // peak ws use: ~170.4 MB

  wt_kernel<<<dim3(32, 16), dim3(256), 0, stream>>>(Wkv, wkvT, 1024);
  wt_kernel<<<dim3(16, 16), dim3(256), 0, stream>>>(Wq, wqT, 512);
  wt_kernel<<<dim3(16, 16), dim3(256), 0, stream>>>(Wproj, wpT, 512);
  pool2t_kernel<<<dim3(4096), dim3(256), 0, stream>>>(y, pooledT);
  vtpad_kernel<<<dim3(2048), dim3(256), 0, stream>>>(Vt);
  lnrow_kernel<<<dim3(12544), dim3(256), 0, stream>>>(pooledT, gamma, beta, yln);
  xst_kernel<<<dim3(6272), dim3(256), 0, stream>>>(x, xsTb);
  q_mfma<<<dim3(4, 25), dim3(256), 0, stream>>>(xsTb, wqT, Qb);
  kv_mfma<<<dim3(8, 392), dim3(256), 18432, stream>>>(yln, wkvT, Kb, Vt);
  attn_kernel<<<dim3(3584), dim3(256), 0, stream>>>(Qb, Kb, Vt, aw1, aw2, aoutHL);
  proj_mfma<<<dim3(4, 25), dim3(256), 0, stream>>>(aoutHL, wpT, bproj, out);
}

// Round 8
// 346.213 us; speedup vs baseline: 8.2884x; 1.0204x over previous
//
#include <hip/hip_runtime.h>
#include <hip/hip_bf16.h>

// MSCN fused pipeline, MI355X gfx950. Round 7: attn global-load software
// pipeline (4-deep register queues in QK^T and PV).
// B=64, C=512, H=W=7 (N=49), HY=WY=28 (N1=784), heads=8, d=64, SCALE=0.125
// kc1 = 784//2 = 392, kc2 = 784//3 = 261

typedef __hip_bfloat16 bf16;
using bf16x8 = __attribute__((ext_vector_type(8))) short;  // 8 bf16 = 4 VGPRs
using f32x4 = __attribute__((ext_vector_type(4))) float;

#define DI __device__ __forceinline__

DI unsigned short b2u(float f) {
  bf16 h = __float2bfloat16(f);
  return *reinterpret_cast<unsigned short*>(&h);
}
DI float u2f(short s) { return __uint_as_float(((unsigned int)(unsigned short)s) << 16); }

// inverse of the monotone float->uint key map (key = sign? ~u : u|0x80000000)
DI float unkey(unsigned int k) {
  unsigned int u = (k & 0x80000000u) ? (k & 0x7FFFFFFFu) : ~k;
  return __uint_as_float(u);
}

// ---------------------------------------------------------------- pool (integral image, transposed out)
__global__ __launch_bounds__(256) void pool2t_kernel(const float* __restrict__ y,
                                                     bf16* __restrict__ pooledT) {
  const int b = blockIdx.x >> 6, cg = blockIdx.x & 63;
  const float* src = y + ((size_t)b * 512 + cg * 8) * 784;
  bf16* drow = pooledT + ((size_t)b * 784) * 512 + cg * 8;
  __shared__ float I[8][870];  // [plane][29 rows * 30 cols], I[r+1][c+1] = inclusive psum
  const int tid = threadIdx.x;
  for (int i = tid; i < 6272; i += 256) {
    int p = i / 784, j = i - p * 784;
    int r = j / 28, c = j - r * 28;
    I[p][(r + 1) * 30 + c + 1] = src[p * 784 + j];
  }
  for (int i = tid; i < 8 * 58; i += 256) {
    int p = i / 58, e = i - p * 58;
    if (e < 30) I[p][e] = 0.f;           // row 0
    else I[p][(e - 29) * 30] = 0.f;      // col 0, rows 1..28
  }
  __syncthreads();
  if (tid < 224) {  // row prefix
    int p = tid / 28, r = tid - (tid / 28) * 28;
    float run = 0.f;
    float* row = &I[p][(r + 1) * 30 + 1];
#pragma unroll
    for (int c = 0; c < 28; ++c) { run += row[c]; row[c] = run; }
  }
  __syncthreads();
  if (tid < 224) {  // col prefix
    int p = tid / 28, c = tid - (tid / 28) * 28;
    float run = 0.f;
    float* col = &I[p][30 + c + 1];
#pragma unroll
    for (int r = 0; r < 28; ++r) { run += col[r * 30]; col[r * 30] = run; }
  }
  __syncthreads();
  for (int j = tid; j < 784; j += 256) {
    int r = j / 28, c = j - (j / 28) * 28;
    int r0[3], r1[3], c0[3], c1[3];
#pragma unroll
    for (int pk = 1; pk <= 3; ++pk) {
      r0[pk - 1] = max(r - pk, 0) * 30;
      r1[pk - 1] = (min(r + pk, 27) + 1) * 30;
      c0[pk - 1] = max(c - pk, 0);
      c1[pk - 1] = min(c + pk, 27) + 1;
    }
    unsigned int u[4];
#pragma unroll
    for (int q = 0; q < 4; ++q) {
      float vv[2];
#pragma unroll
      for (int t = 0; t < 2; ++t) {
        const float* Ip = I[q * 2 + t];
        float acc = 0.f;
#pragma unroll
        for (int k = 0; k < 3; ++k) {
          float s = Ip[r1[k] + c1[k]] - Ip[r0[k] + c1[k]] - Ip[r1[k] + c0[k]] + Ip[r0[k] + c0[k]];
          acc += s * ((k == 0) ? (1.f / 9.f) : (k == 1) ? (1.f / 25.f) : (1.f / 49.f));
        }
        vv[t] = acc;
      }
      u[q] = (unsigned int)b2u(vv[0]) | ((unsigned int)b2u(vv[1]) << 16);
    }
    *reinterpret_cast<uint4*>(drow + (size_t)j * 512) = make_uint4(u[0], u[1], u[2], u[3]);
  }
}

// ---------------------------------------------------------------- row LayerNorm
__global__ __launch_bounds__(256) void lnrow_kernel(const bf16* __restrict__ pooledT,
                                                    const float* __restrict__ gamma,
                                                    const float* __restrict__ beta,
                                                    bf16* __restrict__ yln) {
  const int row = blockIdx.x * 4 + (threadIdx.x >> 6);
  const int lane = threadIdx.x & 63;
  bf16x8 raw = *reinterpret_cast<const bf16x8*>(pooledT + (size_t)row * 512 + lane * 8);
  float v[8];
  float s = 0.f, s2 = 0.f;
#pragma unroll
  for (int j = 0; j < 8; ++j) {
    v[j] = u2f(raw[j]);
    s += v[j];
    s2 += v[j] * v[j];
  }
#pragma unroll
  for (int off = 32; off; off >>= 1) {
    s += __shfl_xor(s, off, 64);
    s2 += __shfl_xor(s2, off, 64);
  }
  float mu = s * (1.f / 512.f);
  float rs = rsqrtf(s2 * (1.f / 512.f) - mu * mu + 1e-5f);
  float4 g0 = *reinterpret_cast<const float4*>(gamma + lane * 8);
  float4 g1 = *reinterpret_cast<const float4*>(gamma + lane * 8 + 4);
  float4 e0 = *reinterpret_cast<const float4*>(beta + lane * 8);
  float4 e1 = *reinterpret_cast<const float4*>(beta + lane * 8 + 4);
  float gg[8] = {g0.x, g0.y, g0.z, g0.w, g1.x, g1.y, g1.z, g1.w};
  float bb[8] = {e0.x, e0.y, e0.z, e0.w, e1.x, e1.y, e1.z, e1.w};
  unsigned int u[4];
#pragma unroll
  for (int q = 0; q < 4; ++q) {
    float o0 = (v[2 * q] - mu) * rs * gg[2 * q] + bb[2 * q];
    float o1 = (v[2 * q + 1] - mu) * rs * gg[2 * q + 1] + bb[2 * q + 1];
    u[q] = (unsigned int)b2u(o0) | ((unsigned int)b2u(o1) << 16);
  }
  *reinterpret_cast<uint4*>(yln + (size_t)row * 512 + lane * 8) = make_uint4(u[0], u[1], u[2], u[3]);
}

// ---------------------------------------------------------------- x transpose (bf16 out)
__global__ __launch_bounds__(256) void xst_kernel(const float* __restrict__ x,
                                                  bf16* __restrict__ xsTb) {
  int idx = blockIdx.x * 256 + threadIdx.x;
  int c = idx & 511;
  int rem = idx >> 9;
  int r = rem % 49, b = rem / 49;
  xsTb[idx] = __float2bfloat16(x[((size_t)b * 512 + c) * 49 + r]);
}

// ---------------------------------------------------------------- W transpose -> bf16 [N][512]
__global__ __launch_bounds__(256) void wt_kernel(const float* __restrict__ W,
                                                 bf16* __restrict__ WT, int N) {
  __shared__ float t[32][33];
  const int n0 = blockIdx.x * 32, k0 = blockIdx.y * 32;
  for (int i = threadIdx.x; i < 1024; i += 256) {
    int kr = i >> 5, nc = i & 31;
    t[kr][nc] = W[(size_t)(k0 + kr) * N + n0 + nc];
  }
  __syncthreads();
  for (int i = threadIdx.x; i < 1024; i += 256) {
    int nr = i >> 5, kc = i & 31;
    WT[(size_t)(n0 + nr) * 512 + k0 + kc] = __float2bfloat16(t[kc][nr]);
  }
}

// ---------------------------------------------------------------- Vt pad zeroing
__global__ __launch_bounds__(256) void vtpad_kernel(bf16* __restrict__ Vt) {
  int idx = blockIdx.x * 256 + threadIdx.x;  // 524288 total
  int row = idx >> 4, c = idx & 15;
  Vt[(size_t)row * 800 + 784 + c] = __float2bfloat16(0.f);
}

// ---------------------------------------------------------------- kv MFMA GEMM
#define GLD_LDS16(g, l)                                                              \
  __builtin_amdgcn_global_load_lds((const __attribute__((address_space(1))) unsigned int*)(g), \
                                   (__attribute__((address_space(3))) unsigned int*)(l), 16, 0, 0)

__global__ __launch_bounds__(256) void kv_mfma(const bf16* __restrict__ A,
                                               const bf16* __restrict__ Bt,
                                               bf16* __restrict__ Kb, bf16* __restrict__ Vt) {
  extern __shared__ __align__(16) bf16 smem[];  // 18432 B dynamic
  bf16* As = smem;                              // [128*32]
  bf16* Bs = smem + 128 * 32;                   // [128*32]
  const int tid = threadIdx.x;
  const int lane = tid & 63;
  const int w = tid >> 6, wr = w >> 1, wc = w & 1;

  // XCD swizzle: XCD c handles y-tiles [c*49, c*49+49), all 8 x-tiles (A-tile L2 reuse)
  const int lin = blockIdx.y * 8 + blockIdx.x;
  const int c8 = lin & 7, j = lin >> 3;
  const int ex = j & 7, ey = c8 * 49 + (j >> 3);
  const int m0 = ey * 128, n0 = ex * 128;

  f32x4 acc[4][4];
#pragma unroll
  for (int m = 0; m < 4; ++m)
#pragma unroll
    for (int n = 0; n < 4; ++n) acc[m][n] = f32x4{0.f, 0.f, 0.f, 0.f};

  const int s0 = tid, s1 = tid + 256;  // 16B segments; seg s: row=s>>2, koff=(s&3)*8
  const bf16* Ag0 = A + (size_t)(m0 + (s0 >> 2)) * 512 + (s0 & 3) * 8;
  const bf16* Ag1 = A + (size_t)(m0 + (s1 >> 2)) * 512 + (s1 & 3) * 8;
  const bf16* Bg0 = Bt + (size_t)(n0 + (s0 >> 2)) * 512 + (s0 & 3) * 8;
  const bf16* Bg1 = Bt + (size_t)(n0 + (s1 >> 2)) * 512 + (s1 & 3) * 8;
  bf16* Al0 = As + s0 * 8;
  bf16* Al1 = As + s1 * 8;
  bf16* Bl0 = Bs + s0 * 8;
  bf16* Bl1 = Bs + s1 * 8;

  const int fr = lane & 15;        // fragment row/col within 16
  const int ko = (lane >> 4) * 8;  // k offset within 32
  const int rh = lane >> 4;

  for (int k0 = 0; k0 < 512; k0 += 32) {
    GLD_LDS16(Ag0 + k0, Al0);
    GLD_LDS16(Ag1 + k0, Al1);
    GLD_LDS16(Bg0 + k0, Bl0);
    GLD_LDS16(Bg1 + k0, Bl1);
    __syncthreads();  // vmcnt drained before barrier
    bf16x8 af[4], bfr[4];
#pragma unroll
    for (int m = 0; m < 4; ++m)
      af[m] = *reinterpret_cast<const bf16x8*>(As + (wr * 64 + m * 16 + fr) * 32 + ko);
#pragma unroll
    for (int n = 0; n < 4; ++n)
      bfr[n] = *reinterpret_cast<const bf16x8*>(Bs + (wc * 64 + n * 16 + fr) * 32 + ko);
#pragma unroll
    for (int m = 0; m < 4; ++m)
#pragma unroll
      for (int n = 0; n < 4; ++n)
        acc[m][n] = __builtin_amdgcn_mfma_f32_16x16x32_bf16(af[m], bfr[n], acc[m][n], 0, 0, 0);
    __syncthreads();
  }

  if (n0 < 512) {
    // ---- K epilogue: coalesced [b,h,m,d] writes
#pragma unroll
    for (int m = 0; m < 4; ++m) {
#pragma unroll
      for (int n = 0; n < 4; ++n) {
        int col = n0 + wc * 64 + n * 16 + fr;
        const size_t cbase = ((size_t)(col >> 6)) * (784 * 64) + (col & 63);
#pragma unroll
        for (int r = 0; r < 4; ++r) {
          int row = m0 + wr * 64 + m * 16 + rh * 4 + r;
          int b = row / 784, n1 = row - (row / 784) * 784;
          Kb[((size_t)b * 8) * (784 * 64) + cbase + (size_t)n1 * 64] = __float2bfloat16(acc[m][n][r]);
        }
      }
    }
  } else {
    // ---- V epilogue: LDS-staged transpose -> Vt [b*8+h][d][800]
    bf16* stage = smem;  // [128 cols][72 rows-padded]
#pragma unroll
    for (int p = 0; p < 2; ++p) {
      __syncthreads();
      if (wr == p) {
#pragma unroll
        for (int m = 0; m < 4; ++m) {
#pragma unroll
          for (int n = 0; n < 4; ++n) {
            int coll = wc * 64 + n * 16 + fr;
            int rowl = m * 16 + rh * 4;
            unsigned int u0 = (unsigned int)b2u(acc[m][n][0]) | ((unsigned int)b2u(acc[m][n][1]) << 16);
            unsigned int u1 = (unsigned int)b2u(acc[m][n][2]) | ((unsigned int)b2u(acc[m][n][3]) << 16);
            *reinterpret_cast<uint2*>(stage + coll * 72 + rowl) = make_uint2(u0, u1);
          }
        }
      }
      __syncthreads();
      const int rbase = m0 + p * 64;
      for (int i = tid; i < 1024; i += 256) {
        int cc = i >> 3, tc = i & 7;
        int colg = n0 + cc;  // >= 512
        int h = (colg >> 6) & 7, d = colg & 63;
        int rs = rbase + tc * 8;
        int b = rs / 784, n1 = rs - b * 784;
        bf16x8 val = *reinterpret_cast<const bf16x8*>(stage + cc * 72 + tc * 8);
        bf16* dst = Vt + (((size_t)b * 8 + h) * 64 + d) * 800 + n1;
        if (n1 <= 776) {
          *reinterpret_cast<bf16x8*>(dst) = val;
        } else {
#pragma unroll
          for (int jj = 0; jj < 8; ++jj) {
            int rr = rs + jj;
            int bb2 = rr / 784, nn1 = rr - bb2 * 784;
            bf16 hv;
            *reinterpret_cast<short*>(&hv) = val[jj];
            Vt[(((size_t)bb2 * 8 + h) * 64 + d) * 800 + nn1] = hv;
          }
        }
      }
    }
  }
}

// ---------------------------------------------------------------- Q MFMA GEMM
__global__ __launch_bounds__(256) void q_mfma(const bf16* __restrict__ A,
                                              const bf16* __restrict__ Bt,
                                              bf16* __restrict__ Qb) {
  __shared__ __align__(16) bf16 As[128 * 32];
  __shared__ __align__(16) bf16 Bs[128 * 32];
  const int tid = threadIdx.x;
  const int lane = tid & 63;
  const int w = tid >> 6, wr = w >> 1, wc = w & 1;
  const int m0 = blockIdx.y * 128, n0 = blockIdx.x * 128;

  f32x4 acc[4][4];
#pragma unroll
  for (int m = 0; m < 4; ++m)
#pragma unroll
    for (int n = 0; n < 4; ++n) acc[m][n] = f32x4{0.f, 0.f, 0.f, 0.f};

  const int s0 = tid, s1 = tid + 256;
  const bf16* Ag0 = A + (size_t)(m0 + (s0 >> 2)) * 512 + (s0 & 3) * 8;
  const bf16* Ag1 = A + (size_t)(m0 + (s1 >> 2)) * 512 + (s1 & 3) * 8;
  const bf16* Bg0 = Bt + (size_t)(n0 + (s0 >> 2)) * 512 + (s0 & 3) * 8;
  const bf16* Bg1 = Bt + (size_t)(n0 + (s1 >> 2)) * 512 + (s1 & 3) * 8;
  bf16* Al0 = As + s0 * 8;
  bf16* Al1 = As + s1 * 8;
  bf16* Bl0 = Bs + s0 * 8;
  bf16* Bl1 = Bs + s1 * 8;

  const int fr = lane & 15;
  const int ko = (lane >> 4) * 8;
  const int rh = lane >> 4;

  for (int k0 = 0; k0 < 512; k0 += 32) {
    GLD_LDS16(Ag0 + k0, Al0);
    GLD_LDS16(Ag1 + k0, Al1);
    GLD_LDS16(Bg0 + k0, Bl0);
    GLD_LDS16(Bg1 + k0, Bl1);
    __syncthreads();
    bf16x8 af[4], bfr[4];
#pragma unroll
    for (int m = 0; m < 4; ++m)
      af[m] = *reinterpret_cast<const bf16x8*>(As + (wr * 64 + m * 16 + fr) * 32 + ko);
#pragma unroll
    for (int n = 0; n < 4; ++n)
      bfr[n] = *reinterpret_cast<const bf16x8*>(Bs + (wc * 64 + n * 16 + fr) * 32 + ko);
#pragma unroll
    for (int m = 0; m < 4; ++m)
#pragma unroll
      for (int n = 0; n < 4; ++n)
        acc[m][n] = __builtin_amdgcn_mfma_f32_16x16x32_bf16(af[m], bfr[n], acc[m][n], 0, 0, 0);
    __syncthreads();
  }

#pragma unroll
  for (int m = 0; m < 4; ++m) {
#pragma unroll
    for (int n = 0; n < 4; ++n) {
      int col = n0 + wc * 64 + n * 16 + fr;  // 0..511: h=col>>6, d=col&63
      const size_t cbase = ((size_t)(col >> 6)) * (49 * 64) + (col & 63);
#pragma unroll
      for (int r = 0; r < 4; ++r) {
        int row = m0 + wr * 64 + m * 16 + rh * 4 + r;
        if (row < 3136) {
          int b = row / 49, rr = row - (row / 49) * 49;
          Qb[((size_t)b * 8) * (49 * 64) + cbase + (size_t)rr * 64] = __float2bfloat16(acc[m][n][r]);
        }
      }
    }
  }
}

// ---------------------------------------------------------------- proj MFMA GEMM
__global__ __launch_bounds__(256) void proj_mfma(const bf16* __restrict__ A,
                                                 const bf16* __restrict__ Bt,
                                                 const float* __restrict__ bias,
                                                 float* __restrict__ out) {
  __shared__ __align__(16) bf16 As[128 * 32];
  __shared__ __align__(16) bf16 Bs[128 * 32];
  const int tid = threadIdx.x;
  const int lane = tid & 63;
  const int w = tid >> 6, wr = w >> 1, wc = w & 1;
  const int m0 = blockIdx.y * 128, n0 = blockIdx.x * 128;

  f32x4 acc[4][4];
#pragma unroll
  for (int m = 0; m < 4; ++m)
#pragma unroll
    for (int n = 0; n < 4; ++n) acc[m][n] = f32x4{0.f, 0.f, 0.f, 0.f};

  const int s0 = tid, s1 = tid + 256;
  const bf16* Ag0 = A + (size_t)(m0 + (s0 >> 2)) * 1024 + (s0 & 3) * 8;
  const bf16* Ag1 = A + (size_t)(m0 + (s1 >> 2)) * 1024 + (s1 & 3) * 8;
  const bf16* Bg0 = Bt + (size_t)(n0 + (s0 >> 2)) * 512 + (s0 & 3) * 8;
  const bf16* Bg1 = Bt + (size_t)(n0 + (s1 >> 2)) * 512 + (s1 & 3) * 8;
  bf16* Al0 = As + s0 * 8;
  bf16* Al1 = As + s1 * 8;
  bf16* Bl0 = Bs + s0 * 8;
  bf16* Bl1 = Bs + s1 * 8;

  const int fr = lane & 15;
  const int ko = (lane >> 4) * 8;
  const int rh = lane >> 4;

  for (int k0 = 0; k0 < 1024; k0 += 32) {
    GLD_LDS16(Ag0 + k0, Al0);
    GLD_LDS16(Ag1 + k0, Al1);
    GLD_LDS16(Bg0 + (k0 & 511), Bl0);
    GLD_LDS16(Bg1 + (k0 & 511), Bl1);
    __syncthreads();
    bf16x8 af[4], bfr[4];
#pragma unroll
    for (int m = 0; m < 4; ++m)
      af[m] = *reinterpret_cast<const bf16x8*>(As + (wr * 64 + m * 16 + fr) * 32 + ko);
#pragma unroll
    for (int n = 0; n < 4; ++n)
      bfr[n] = *reinterpret_cast<const bf16x8*>(Bs + (wc * 64 + n * 16 + fr) * 32 + ko);
#pragma unroll
    for (int m = 0; m < 4; ++m)
#pragma unroll
      for (int n = 0; n < 4; ++n)
        acc[m][n] = __builtin_amdgcn_mfma_f32_16x16x32_bf16(af[m], bfr[n], acc[m][n], 0, 0, 0);
    __syncthreads();
  }

#pragma unroll
  for (int m = 0; m < 4; ++m) {
#pragma unroll
    for (int n = 0; n < 4; ++n) {
      int col = n0 + wc * 64 + n * 16 + fr;
      float bv = bias[col];
#pragma unroll
      for (int r = 0; r < 4; ++r) {
        int row = m0 + wr * 64 + m * 16 + rh * 4 + r;
        if (row < 3136) {
          int b = row / 49, rr = row - (row / 49) * 49;
          out[((size_t)b * 512 + col) * 49 + rr] = acc[m][n][r] + bv;
        }
      }
    }
  }
}

// ---------------------------------------------------------------- attention
// one block = (b,h, chunk of 7 q-rows). MFMA QK^T + MFMA PV with 4-deep
// register load queues; float-domain bisection top-k; sW aliases sLog.
__global__ __launch_bounds__(256, 6) void attn_kernel(const bf16* __restrict__ Qb,
                                                      const bf16* __restrict__ K,
                                                      const bf16* __restrict__ Vt,
                                                      const float* __restrict__ aw1p,
                                                      const float* __restrict__ aw2p,
                                                      bf16* __restrict__ aoutHL) {
  // XCD swizzle: 3584 = 8*448; XCD c gets wk in [c*448,(c+1)*448) => bh in [c*64,(c+1)*64)
  const int lin = blockIdx.x;
  const int wk = (lin & 7) * 448 + (lin >> 3);
  const int bh = wk / 7;
  const int chunk = wk - bh * 7;
  const int b = bh >> 3, h = bh & 7;
  const int r0 = chunk * 7;
  const int tid = threadIdx.x;
  const int lane = tid & 63, w = tid >> 6;
  __shared__ __align__(16) bf16 sQb[16][72];        // 2304 B, rows 7..15 zero
  __shared__ __align__(16) unsigned char sMem[21952];  // union: sLog f32[7][784] / sW bf16[8][808]
  float* sLog = reinterpret_cast<float*>(sMem);
  bf16* sW = reinterpret_cast<bf16*>(sMem);
  // LDS total ~24.3 KB -> 6 blocks/CU

  // stage Q (bf16 direct, zero-padded rows)
  const bf16* Qp = Qb + ((size_t)bh * 49 + r0) * 64;
  for (int i = tid; i < 1024; i += 256) {
    int r = i >> 6, d = i & 63;
    sQb[r][d] = (r < 7) ? Qp[r * 64 + d] : __float2bfloat16(0.f);
  }
  __syncthreads();

  // ---- QK^T via MFMA with a 4-deep K register queue
  const bf16* Kp = K + (size_t)bh * (784 * 64);
  const int fr = lane & 15, ko = (lane >> 4) * 8, rh = lane >> 4;
  {
    const bf16x8 aq0 = *reinterpret_cast<const bf16x8*>(&sQb[fr][ko]);
    const bf16x8 aq1 = *reinterpret_cast<const bf16x8*>(&sQb[fr][32 + ko]);
    const int rbase = rh * 4;
    const bf16* kbase = Kp + (size_t)fr * 64 + ko;
    bf16x8 kq0[4], kq1[4];
#pragma unroll
    for (int s = 0; s < 4; ++s) {
      int nt = w + s * 4;
      int ntc = nt < 49 ? nt : 48;
      const bf16* kr = kbase + (size_t)ntc * 1024;
      kq0[s] = *reinterpret_cast<const bf16x8*>(kr);
      kq1[s] = *reinterpret_cast<const bf16x8*>(kr + 32);
    }
#pragma unroll
    for (int i = 0; i < 13; ++i) {
      const int s = i & 3;
      const int nt = w + i * 4;
      if (nt < 49) {
        f32x4 acc = {0.f, 0.f, 0.f, 0.f};
        acc = __builtin_amdgcn_mfma_f32_16x16x32_bf16(aq0, kq0[s], acc, 0, 0, 0);
        acc = __builtin_amdgcn_mfma_f32_16x16x32_bf16(aq1, kq1[s], acc, 0, 0, 0);
#pragma unroll
        for (int r = 0; r < 4; ++r) {
          int row = rbase + r;
          if (row < 7) sLog[row * 784 + nt * 16 + fr] = acc[r] * 0.125f;
        }
      }
      const int ntn = w + (i + 4) * 4;
      if (ntn < 49) {
        const bf16* kr = kbase + (size_t)ntn * 1024;
        kq0[s] = *reinterpret_cast<const bf16x8*>(kr);
        kq1[s] = *reinterpret_cast<const bf16x8*>(kr + 32);
      }
    }
  }
  __syncthreads();

  // ---- load logits for this wave's two rows into registers
  const int ra = w;
  const int rb = (w + 4 < 7) ? (w + 4) : w;  // wave 3 duplicates its row (benign)
  float va[13], vb[13];
#pragma unroll
  for (int i = 0; i < 13; ++i) {
    int m = lane + i * 64;
    va[i] = (m < 784) ? sLog[ra * 784 + m] : -INFINITY;
    vb[i] = (m < 784) ? sLog[rb * 784 + m] : -INFINITY;
  }
  __syncthreads();  // sLog fully consumed; sW aliasing writes may begin

  // row max
  float mxa = va[0], mxb = vb[0];
#pragma unroll
  for (int i = 1; i < 13; ++i) {
    mxa = fmaxf(mxa, va[i]);
    mxb = fmaxf(mxb, vb[i]);
  }
#pragma unroll
  for (int off = 32; off; off >>= 1) {
    mxa = fmaxf(mxa, __shfl_xor(mxa, off, 64));
    mxb = fmaxf(mxb, __shfl_xor(mxb, off, 64));
  }

  // ---- 4 bisection chains in key space, compares in the float domain.
  // v >= unkey(cand) <=> key(v) >= cand (monotone bijection on finite floats).
  // Early exit when count==k is exact; ties fall to full bisection -> >= kth
  // semantics identical to reference.
  unsigned int t1a = 0u, t2a = 0u, t1b = 0u, t2b = 0u;
  bool d1a = false, d2a = false, d1b = false, d2b = false;
  for (int bit = 31; bit >= 0; --bit) {
    const unsigned int mb = 1u << bit;
    if (!d1a) {
      float cf = unkey(t1a | mb);
      int n = 0;
#pragma unroll
      for (int i = 0; i < 13; ++i) n += __popcll(__ballot(va[i] >= cf));
      if (n >= 392) { t1a |= mb; d1a = (n == 392); }
    }
    if (!d2a) {
      float cf = unkey(t2a | mb);
      int n = 0;
#pragma unroll
      for (int i = 0; i < 13; ++i) n += __popcll(__ballot(va[i] >= cf));
      if (n >= 261) { t2a |= mb; d2a = (n == 261); }
    }
    if (!d1b) {
      float cf = unkey(t1b | mb);
      int n = 0;
#pragma unroll
      for (int i = 0; i < 13; ++i) n += __popcll(__ballot(vb[i] >= cf));
      if (n >= 392) { t1b |= mb; d1b = (n == 392); }
    }
    if (!d2b) {
      float cf = unkey(t2b | mb);
      int n = 0;
#pragma unroll
      for (int i = 0; i < 13; ++i) n += __popcll(__ballot(vb[i] >= cf));
      if (n >= 261) { t2b |= mb; d2b = (n == 261); }
    }
    if (d1a & d2a & d1b & d2b) break;
  }
  const float T1a = unkey(t1a), T2a = unkey(t2a);
  const float T1b = unkey(t1b), T2b = unkey(t2b);

  // ---- fused exp + z + weights (e kept in registers)
  const float aw1 = aw1p[0], aw2 = aw2p[0];
  float ea[13], eb[13];
  float z1a = 0.f, z2a = 0.f, z1b = 0.f, z2b = 0.f;
#pragma unroll
  for (int i = 0; i < 13; ++i) {
    ea[i] = __expf(va[i] - mxa);  // pads: exp(-inf)=0
    eb[i] = __expf(vb[i] - mxb);
    if (va[i] >= T1a) z1a += ea[i];
    if (va[i] >= T2a) z2a += ea[i];
    if (vb[i] >= T1b) z1b += eb[i];
    if (vb[i] >= T2b) z2b += eb[i];
  }
#pragma unroll
  for (int off = 32; off; off >>= 1) {
    z1a += __shfl_xor(z1a, off, 64);
    z2a += __shfl_xor(z2a, off, 64);
    z1b += __shfl_xor(z1b, off, 64);
    z2b += __shfl_xor(z2b, off, 64);
  }
  const float a1a = aw1 / z1a, a2a = aw2 / z2a;
  const float a1b = aw1 / z1b, a2b = aw2 / z2b;
#pragma unroll
  for (int i = 0; i < 13; ++i) {
    int m = lane + i * 64;
    if (m < 784) {
      float wa = ea[i] * (((va[i] >= T1a) ? a1a : 0.f) + ((va[i] >= T2a) ? a2a : 0.f));
      sW[ra * 808 + m] = __float2bfloat16(wa);
      float wb = eb[i] * (((vb[i] >= T1b) ? a1b : 0.f) + ((vb[i] >= T2b) ? a2b : 0.f));
      sW[rb * 808 + m] = __float2bfloat16(wb);
    }
  }
  if (lane < 16) {
    sW[ra * 808 + 784 + lane] = __float2bfloat16(0.f);
    sW[rb * 808 + 784 + lane] = __float2bfloat16(0.f);
  }
  if (w == 3)
    for (int i = lane; i < 808; i += 64) sW[7 * 808 + i] = __float2bfloat16(0.f);

  // ---- PV V-queue prefetch issued BEFORE the barrier (latency hides under it)
  const bf16* vbase = Vt + ((size_t)bh * 64 + w * 16 + fr) * 800;
  bf16x8 vq[4];
#pragma unroll
  for (int s = 0; s < 4; ++s)
    vq[s] = *reinterpret_cast<const bf16x8*>(vbase + s * 32 + ko);
  __syncthreads();

  // ---- PV via MFMA: out[16][64] = W[16][800] x V^T; wave w owns d-tile w*16..
  // A-operand rows 7..15 are zero => alias to zeroed row 7 (LDS broadcast).
  // Two accumulator chains (even/odd) halve the dependent-MFMA latency.
  const bf16* wrow = sW + (fr < 7 ? fr : 7) * 808;
  f32x4 acc0 = {0.f, 0.f, 0.f, 0.f}, acc1 = {0.f, 0.f, 0.f, 0.f};
#pragma unroll
  for (int ks = 0; ks < 25; ++ks) {
    const int s = ks & 3;
    bf16x8 a = *reinterpret_cast<const bf16x8*>(wrow + ks * 32 + ko);
    if (ks & 1)
      acc1 = __builtin_amdgcn_mfma_f32_16x16x32_bf16(a, vq[s], acc1, 0, 0, 0);
    else
      acc0 = __builtin_amdgcn_mfma_f32_16x16x32_bf16(a, vq[s], acc0, 0, 0, 0);
    if (ks + 4 < 25)
      vq[s] = *reinterpret_cast<const bf16x8*>(vbase + (ks + 4) * 32 + ko);
  }
  acc0 += acc1;
#pragma unroll
  for (int r = 0; r < 4; ++r) {
    int row = rh * 4 + r;
    if (row < 7) {
      float v = acc0[r];
      bf16 hi = __float2bfloat16(v);
      bf16 lo = __float2bfloat16(v - __bfloat162float(hi));
      size_t base = ((size_t)(b * 49 + r0 + row)) * 1024 + h * 64 + w * 16 + fr;
      aoutHL[base] = hi;
      aoutHL[base + 512] = lo;
    }
  }
}

// ---------------------------------------------------------------- launch
extern "C" void kernel_launch(void* const* d_in, const int* in_sizes, int n_in, void* d_out,
                              int out_size, void* d_ws, size_t ws_size, hipStream_t stream) {
  const float* x = (const float*)d_in[0];
  const float* y = (const float*)d_in[1];
  const float* Wq = (const float*)d_in[2];
  const float* Wkv = (const float*)d_in[3];
  const float* Wproj = (const float*)d_in[4];
  const float* bproj = (const float*)d_in[5];
  const float* gamma = (const float*)d_in[6];
  const float* beta = (const float*)d_in[7];
  const float* aw1 = (const float*)d_in[8];
  const float* aw2 = (const float*)d_in[9];
  float* out = (float*)d_out;

  char* w = (char*)d_ws;
  const size_t SZ = 51380224ull;    // 64*784*512*2 bytes
  const size_t SZV = 52428800ull;   // 64*8*64*800*2 bytes (V^T, padded stride 800)
  bf16* pooledT = (bf16*)(w);       // [50176][512]; dead after lnrow
  bf16* yln = (bf16*)(w + SZ);      // [50176][512]; dead after kv gemm
  bf16* Kb = (bf16*)(w);            // reuses pooledT slot (after lnrow)
  bf16* Vt = (bf16*)(w + 2 * SZ);
  size_t off = 2 * SZ + SZV;
  bf16* xsTb = (bf16*)(w + off);    off += 3276800;   // [3200][512] bf16 (64 pad rows)
  bf16* Qb = (bf16*)(w + off);      off += 3276800;   // [B,8,49,64] bf16
  bf16* aoutHL = (bf16*)(w + off);  off += 6553600;   // [3200][1024] bf16 (hi|lo)
  bf16* wkvT = (bf16*)(w + off);    off += 1048576;   // [1024][512] bf16
  bf16* wqT = (bf16*)(w + off);     off += 524288;    // [512][512] bf16
  bf16* wpT = (bf16*)(w + off);     off += 524288;    // [512][512] bf16
  // peak ws use: ~170.4 MB

  wt_kernel<<<dim3(32, 16), dim3(256), 0, stream>>>(Wkv, wkvT, 1024);
  wt_kernel<<<dim3(16, 16), dim3(256), 0, stream>>>(Wq, wqT, 512);
  wt_kernel<<<dim3(16, 16), dim3(256), 0, stream>>>(Wproj, wpT, 512);
  pool2t_kernel<<<dim3(4096), dim3(256), 0, stream>>>(y, pooledT);
  vtpad_kernel<<<dim3(2048), dim3(256), 0, stream>>>(Vt);
  lnrow_kernel<<<dim3(12544), dim3(256), 0, stream>>>(pooledT, gamma, beta, yln);
  xst_kernel<<<dim3(6272), dim3(256), 0, stream>>>(x, xsTb);
  q_mfma<<<dim3(4, 25), dim3(256), 0, stream>>>(xsTb, wqT, Qb);
  kv_mfma<<<dim3(8, 392), dim3(256), 18432, stream>>>(yln, wkvT, Kb, Vt);
  attn_kernel<<<dim3(3584), dim3(256), 0, stream>>>(Qb, Kb, Vt, aw1, aw2, aoutHL);
  proj_mfma<<<dim3(4, 25), dim3(256), 0, stream>>>(aoutHL, wpT, bproj, out);
}

// Round 9
// 327.652 us; speedup vs baseline: 8.7580x; 1.0566x over previous
//
#include <hip/hip_runtime.h>
#include <hip/hip_bf16.h>

// MSCN fused pipeline, MI355X gfx950. Round 8: attn 7-blocks/CU (no sQb,
// clamped A-rows, 22KB LDS) + fused prep kernel (wt x3 / xst / vtpad).
// B=64, C=512, H=W=7 (N=49), HY=WY=28 (N1=784), heads=8, d=64, SCALE=0.125
// kc1 = 784//2 = 392, kc2 = 784//3 = 261

typedef __hip_bfloat16 bf16;
using bf16x8 = __attribute__((ext_vector_type(8))) short;  // 8 bf16 = 4 VGPRs
using f32x4 = __attribute__((ext_vector_type(4))) float;

#define DI __device__ __forceinline__

DI unsigned short b2u(float f) {
  bf16 h = __float2bfloat16(f);
  return *reinterpret_cast<unsigned short*>(&h);
}
DI float u2f(short s) { return __uint_as_float(((unsigned int)(unsigned short)s) << 16); }

// inverse of the monotone float->uint key map (key = sign? ~u : u|0x80000000)
DI float unkey(unsigned int k) {
  unsigned int u = (k & 0x80000000u) ? (k & 0x7FFFFFFFu) : ~k;
  return __uint_as_float(u);
}

// ---------------------------------------------------------------- pool (integral image, transposed out)
__global__ __launch_bounds__(256) void pool2t_kernel(const float* __restrict__ y,
                                                     bf16* __restrict__ pooledT) {
  const int b = blockIdx.x >> 6, cg = blockIdx.x & 63;
  const float* src = y + ((size_t)b * 512 + cg * 8) * 784;
  bf16* drow = pooledT + ((size_t)b * 784) * 512 + cg * 8;
  __shared__ float I[8][870];  // [plane][29 rows * 30 cols], I[r+1][c+1] = inclusive psum
  const int tid = threadIdx.x;
  for (int i = tid; i < 6272; i += 256) {
    int p = i / 784, j = i - p * 784;
    int r = j / 28, c = j - r * 28;
    I[p][(r + 1) * 30 + c + 1] = src[p * 784 + j];
  }
  for (int i = tid; i < 8 * 58; i += 256) {
    int p = i / 58, e = i - p * 58;
    if (e < 30) I[p][e] = 0.f;           // row 0
    else I[p][(e - 29) * 30] = 0.f;      // col 0, rows 1..28
  }
  __syncthreads();
  if (tid < 224) {  // row prefix
    int p = tid / 28, r = tid - (tid / 28) * 28;
    float run = 0.f;
    float* row = &I[p][(r + 1) * 30 + 1];
#pragma unroll
    for (int c = 0; c < 28; ++c) { run += row[c]; row[c] = run; }
  }
  __syncthreads();
  if (tid < 224) {  // col prefix
    int p = tid / 28, c = tid - (tid / 28) * 28;
    float run = 0.f;
    float* col = &I[p][30 + c + 1];
#pragma unroll
    for (int r = 0; r < 28; ++r) { run += col[r * 30]; col[r * 30] = run; }
  }
  __syncthreads();
  for (int j = tid; j < 784; j += 256) {
    int r = j / 28, c = j - (j / 28) * 28;
    int r0[3], r1[3], c0[3], c1[3];
#pragma unroll
    for (int pk = 1; pk <= 3; ++pk) {
      r0[pk - 1] = max(r - pk, 0) * 30;
      r1[pk - 1] = (min(r + pk, 27) + 1) * 30;
      c0[pk - 1] = max(c - pk, 0);
      c1[pk - 1] = min(c + pk, 27) + 1;
    }
    unsigned int u[4];
#pragma unroll
    for (int q = 0; q < 4; ++q) {
      float vv[2];
#pragma unroll
      for (int t = 0; t < 2; ++t) {
        const float* Ip = I[q * 2 + t];
        float acc = 0.f;
#pragma unroll
        for (int k = 0; k < 3; ++k) {
          float s = Ip[r1[k] + c1[k]] - Ip[r0[k] + c1[k]] - Ip[r1[k] + c0[k]] + Ip[r0[k] + c0[k]];
          acc += s * ((k == 0) ? (1.f / 9.f) : (k == 1) ? (1.f / 25.f) : (1.f / 49.f));
        }
        vv[t] = acc;
      }
      u[q] = (unsigned int)b2u(vv[0]) | ((unsigned int)b2u(vv[1]) << 16);
    }
    *reinterpret_cast<uint4*>(drow + (size_t)j * 512) = make_uint4(u[0], u[1], u[2], u[3]);
  }
}

// ---------------------------------------------------------------- row LayerNorm
__global__ __launch_bounds__(256) void lnrow_kernel(const bf16* __restrict__ pooledT,
                                                    const float* __restrict__ gamma,
                                                    const float* __restrict__ beta,
                                                    bf16* __restrict__ yln) {
  const int row = blockIdx.x * 4 + (threadIdx.x >> 6);
  const int lane = threadIdx.x & 63;
  bf16x8 raw = *reinterpret_cast<const bf16x8*>(pooledT + (size_t)row * 512 + lane * 8);
  float v[8];
  float s = 0.f, s2 = 0.f;
#pragma unroll
  for (int j = 0; j < 8; ++j) {
    v[j] = u2f(raw[j]);
    s += v[j];
    s2 += v[j] * v[j];
  }
#pragma unroll
  for (int off = 32; off; off >>= 1) {
    s += __shfl_xor(s, off, 64);
    s2 += __shfl_xor(s2, off, 64);
  }
  float mu = s * (1.f / 512.f);
  float rs = rsqrtf(s2 * (1.f / 512.f) - mu * mu + 1e-5f);
  float4 g0 = *reinterpret_cast<const float4*>(gamma + lane * 8);
  float4 g1 = *reinterpret_cast<const float4*>(gamma + lane * 8 + 4);
  float4 e0 = *reinterpret_cast<const float4*>(beta + lane * 8);
  float4 e1 = *reinterpret_cast<const float4*>(beta + lane * 8 + 4);
  float gg[8] = {g0.x, g0.y, g0.z, g0.w, g1.x, g1.y, g1.z, g1.w};
  float bb[8] = {e0.x, e0.y, e0.z, e0.w, e1.x, e1.y, e1.z, e1.w};
  unsigned int u[4];
#pragma unroll
  for (int q = 0; q < 4; ++q) {
    float o0 = (v[2 * q] - mu) * rs * gg[2 * q] + bb[2 * q];
    float o1 = (v[2 * q + 1] - mu) * rs * gg[2 * q + 1] + bb[2 * q + 1];
    u[q] = (unsigned int)b2u(o0) | ((unsigned int)b2u(o1) << 16);
  }
  *reinterpret_cast<uint4*>(yln + (size_t)row * 512 + lane * 8) = make_uint4(u[0], u[1], u[2], u[3]);
}

// ---------------------------------------------------------------- fused prep
// blocks [0,512): WkvT; [512,768): WqT; [768,1024): WprojT; [1024,7296): xst;
// [7296,9344): vtpad.
__global__ __launch_bounds__(256) void prep_kernel(const float* __restrict__ Wkv,
                                                   const float* __restrict__ Wq,
                                                   const float* __restrict__ Wproj,
                                                   const float* __restrict__ x,
                                                   bf16* __restrict__ wkvT, bf16* __restrict__ wqT,
                                                   bf16* __restrict__ wpT, bf16* __restrict__ xsTb,
                                                   bf16* __restrict__ Vt) {
  __shared__ float t[32][33];
  const int blk = blockIdx.x;
  const int tid = threadIdx.x;
  if (blk < 1024) {
    const float* W;
    bf16* WT;
    int N, bx, by;
    if (blk < 512) { W = Wkv; WT = wkvT; N = 1024; bx = blk & 31; by = blk >> 5; }
    else if (blk < 768) { W = Wq; WT = wqT; N = 512; bx = (blk - 512) & 15; by = (blk - 512) >> 4; }
    else { W = Wproj; WT = wpT; N = 512; bx = (blk - 768) & 15; by = (blk - 768) >> 4; }
    const int n0 = bx * 32, k0 = by * 32;
    for (int i = tid; i < 1024; i += 256) {
      int kr = i >> 5, nc = i & 31;
      t[kr][nc] = W[(size_t)(k0 + kr) * N + n0 + nc];
    }
    __syncthreads();
    for (int i = tid; i < 1024; i += 256) {
      int nr = i >> 5, kc = i & 31;
      WT[(size_t)(n0 + nr) * 512 + k0 + kc] = __float2bfloat16(t[kc][nr]);
    }
  } else if (blk < 7296) {
    int idx = (blk - 1024) * 256 + tid;
    int c = idx & 511;
    int rem = idx >> 9;
    int r = rem % 49, b = rem / 49;
    xsTb[idx] = __float2bfloat16(x[((size_t)b * 512 + c) * 49 + r]);
  } else {
    int idx = (blk - 7296) * 256 + tid;  // 524288 total
    int row = idx >> 4, c = idx & 15;
    Vt[(size_t)row * 800 + 784 + c] = __float2bfloat16(0.f);
  }
}

// ---------------------------------------------------------------- kv MFMA GEMM
#define GLD_LDS16(g, l)                                                              \
  __builtin_amdgcn_global_load_lds((const __attribute__((address_space(1))) unsigned int*)(g), \
                                   (__attribute__((address_space(3))) unsigned int*)(l), 16, 0, 0)

__global__ __launch_bounds__(256) void kv_mfma(const bf16* __restrict__ A,
                                               const bf16* __restrict__ Bt,
                                               bf16* __restrict__ Kb, bf16* __restrict__ Vt) {
  extern __shared__ __align__(16) bf16 smem[];  // 18432 B dynamic
  bf16* As = smem;                              // [128*32]
  bf16* Bs = smem + 128 * 32;                   // [128*32]
  const int tid = threadIdx.x;
  const int lane = tid & 63;
  const int w = tid >> 6, wr = w >> 1, wc = w & 1;

  // XCD swizzle: XCD c handles y-tiles [c*49, c*49+49), all 8 x-tiles (A-tile L2 reuse)
  const int lin = blockIdx.y * 8 + blockIdx.x;
  const int c8 = lin & 7, j = lin >> 3;
  const int ex = j & 7, ey = c8 * 49 + (j >> 3);
  const int m0 = ey * 128, n0 = ex * 128;

  f32x4 acc[4][4];
#pragma unroll
  for (int m = 0; m < 4; ++m)
#pragma unroll
    for (int n = 0; n < 4; ++n) acc[m][n] = f32x4{0.f, 0.f, 0.f, 0.f};

  const int s0 = tid, s1 = tid + 256;  // 16B segments; seg s: row=s>>2, koff=(s&3)*8
  const bf16* Ag0 = A + (size_t)(m0 + (s0 >> 2)) * 512 + (s0 & 3) * 8;
  const bf16* Ag1 = A + (size_t)(m0 + (s1 >> 2)) * 512 + (s1 & 3) * 8;
  const bf16* Bg0 = Bt + (size_t)(n0 + (s0 >> 2)) * 512 + (s0 & 3) * 8;
  const bf16* Bg1 = Bt + (size_t)(n0 + (s1 >> 2)) * 512 + (s1 & 3) * 8;
  bf16* Al0 = As + s0 * 8;
  bf16* Al1 = As + s1 * 8;
  bf16* Bl0 = Bs + s0 * 8;
  bf16* Bl1 = Bs + s1 * 8;

  const int fr = lane & 15;        // fragment row/col within 16
  const int ko = (lane >> 4) * 8;  // k offset within 32
  const int rh = lane >> 4;

  for (int k0 = 0; k0 < 512; k0 += 32) {
    GLD_LDS16(Ag0 + k0, Al0);
    GLD_LDS16(Ag1 + k0, Al1);
    GLD_LDS16(Bg0 + k0, Bl0);
    GLD_LDS16(Bg1 + k0, Bl1);
    __syncthreads();  // vmcnt drained before barrier
    bf16x8 af[4], bfr[4];
#pragma unroll
    for (int m = 0; m < 4; ++m)
      af[m] = *reinterpret_cast<const bf16x8*>(As + (wr * 64 + m * 16 + fr) * 32 + ko);
#pragma unroll
    for (int n = 0; n < 4; ++n)
      bfr[n] = *reinterpret_cast<const bf16x8*>(Bs + (wc * 64 + n * 16 + fr) * 32 + ko);
#pragma unroll
    for (int m = 0; m < 4; ++m)
#pragma unroll
      for (int n = 0; n < 4; ++n)
        acc[m][n] = __builtin_amdgcn_mfma_f32_16x16x32_bf16(af[m], bfr[n], acc[m][n], 0, 0, 0);
    __syncthreads();
  }

  if (n0 < 512) {
    // ---- K epilogue: coalesced [b,h,m,d] writes
#pragma unroll
    for (int m = 0; m < 4; ++m) {
#pragma unroll
      for (int n = 0; n < 4; ++n) {
        int col = n0 + wc * 64 + n * 16 + fr;
        const size_t cbase = ((size_t)(col >> 6)) * (784 * 64) + (col & 63);
#pragma unroll
        for (int r = 0; r < 4; ++r) {
          int row = m0 + wr * 64 + m * 16 + rh * 4 + r;
          int b = row / 784, n1 = row - (row / 784) * 784;
          Kb[((size_t)b * 8) * (784 * 64) + cbase + (size_t)n1 * 64] = __float2bfloat16(acc[m][n][r]);
        }
      }
    }
  } else {
    // ---- V epilogue: LDS-staged transpose -> Vt [b*8+h][d][800]
    bf16* stage = smem;  // [128 cols][72 rows-padded]
#pragma unroll
    for (int p = 0; p < 2; ++p) {
      __syncthreads();
      if (wr == p) {
#pragma unroll
        for (int m = 0; m < 4; ++m) {
#pragma unroll
          for (int n = 0; n < 4; ++n) {
            int coll = wc * 64 + n * 16 + fr;
            int rowl = m * 16 + rh * 4;
            unsigned int u0 = (unsigned int)b2u(acc[m][n][0]) | ((unsigned int)b2u(acc[m][n][1]) << 16);
            unsigned int u1 = (unsigned int)b2u(acc[m][n][2]) | ((unsigned int)b2u(acc[m][n][3]) << 16);
            *reinterpret_cast<uint2*>(stage + coll * 72 + rowl) = make_uint2(u0, u1);
          }
        }
      }
      __syncthreads();
      const int rbase = m0 + p * 64;
      for (int i = tid; i < 1024; i += 256) {
        int cc = i >> 3, tc = i & 7;
        int colg = n0 + cc;  // >= 512
        int h = (colg >> 6) & 7, d = colg & 63;
        int rs = rbase + tc * 8;
        int b = rs / 784, n1 = rs - b * 784;
        bf16x8 val = *reinterpret_cast<const bf16x8*>(stage + cc * 72 + tc * 8);
        bf16* dst = Vt + (((size_t)b * 8 + h) * 64 + d) * 800 + n1;
        if (n1 <= 776) {
          *reinterpret_cast<bf16x8*>(dst) = val;
        } else {
#pragma unroll
          for (int jj = 0; jj < 8; ++jj) {
            int rr = rs + jj;
            int bb2 = rr / 784, nn1 = rr - bb2 * 784;
            bf16 hv;
            *reinterpret_cast<short*>(&hv) = val[jj];
            Vt[(((size_t)bb2 * 8 + h) * 64 + d) * 800 + nn1] = hv;
          }
        }
      }
    }
  }
}

// ---------------------------------------------------------------- Q MFMA GEMM
__global__ __launch_bounds__(256) void q_mfma(const bf16* __restrict__ A,
                                              const bf16* __restrict__ Bt,
                                              bf16* __restrict__ Qb) {
  __shared__ __align__(16) bf16 As[128 * 32];
  __shared__ __align__(16) bf16 Bs[128 * 32];
  const int tid = threadIdx.x;
  const int lane = tid & 63;
  const int w = tid >> 6, wr = w >> 1, wc = w & 1;
  const int m0 = blockIdx.y * 128, n0 = blockIdx.x * 128;

  f32x4 acc[4][4];
#pragma unroll
  for (int m = 0; m < 4; ++m)
#pragma unroll
    for (int n = 0; n < 4; ++n) acc[m][n] = f32x4{0.f, 0.f, 0.f, 0.f};

  const int s0 = tid, s1 = tid + 256;
  const bf16* Ag0 = A + (size_t)(m0 + (s0 >> 2)) * 512 + (s0 & 3) * 8;
  const bf16* Ag1 = A + (size_t)(m0 + (s1 >> 2)) * 512 + (s1 & 3) * 8;
  const bf16* Bg0 = Bt + (size_t)(n0 + (s0 >> 2)) * 512 + (s0 & 3) * 8;
  const bf16* Bg1 = Bt + (size_t)(n0 + (s1 >> 2)) * 512 + (s1 & 3) * 8;
  bf16* Al0 = As + s0 * 8;
  bf16* Al1 = As + s1 * 8;
  bf16* Bl0 = Bs + s0 * 8;
  bf16* Bl1 = Bs + s1 * 8;

  const int fr = lane & 15;
  const int ko = (lane >> 4) * 8;
  const int rh = lane >> 4;

  for (int k0 = 0; k0 < 512; k0 += 32) {
    GLD_LDS16(Ag0 + k0, Al0);
    GLD_LDS16(Ag1 + k0, Al1);
    GLD_LDS16(Bg0 + k0, Bl0);
    GLD_LDS16(Bg1 + k0, Bl1);
    __syncthreads();
    bf16x8 af[4], bfr[4];
#pragma unroll
    for (int m = 0; m < 4; ++m)
      af[m] = *reinterpret_cast<const bf16x8*>(As + (wr * 64 + m * 16 + fr) * 32 + ko);
#pragma unroll
    for (int n = 0; n < 4; ++n)
      bfr[n] = *reinterpret_cast<const bf16x8*>(Bs + (wc * 64 + n * 16 + fr) * 32 + ko);
#pragma unroll
    for (int m = 0; m < 4; ++m)
#pragma unroll
      for (int n = 0; n < 4; ++n)
        acc[m][n] = __builtin_amdgcn_mfma_f32_16x16x32_bf16(af[m], bfr[n], acc[m][n], 0, 0, 0);
    __syncthreads();
  }

#pragma unroll
  for (int m = 0; m < 4; ++m) {
#pragma unroll
    for (int n = 0; n < 4; ++n) {
      int col = n0 + wc * 64 + n * 16 + fr;  // 0..511: h=col>>6, d=col&63
      const size_t cbase = ((size_t)(col >> 6)) * (49 * 64) + (col & 63);
#pragma unroll
      for (int r = 0; r < 4; ++r) {
        int row = m0 + wr * 64 + m * 16 + rh * 4 + r;
        if (row < 3136) {
          int b = row / 49, rr = row - (row / 49) * 49;
          Qb[((size_t)b * 8) * (49 * 64) + cbase + (size_t)rr * 64] = __float2bfloat16(acc[m][n][r]);
        }
      }
    }
  }
}

// ---------------------------------------------------------------- proj MFMA GEMM
__global__ __launch_bounds__(256) void proj_mfma(const bf16* __restrict__ A,
                                                 const bf16* __restrict__ Bt,
                                                 const float* __restrict__ bias,
                                                 float* __restrict__ out) {
  __shared__ __align__(16) bf16 As[128 * 32];
  __shared__ __align__(16) bf16 Bs[128 * 32];
  const int tid = threadIdx.x;
  const int lane = tid & 63;
  const int w = tid >> 6, wr = w >> 1, wc = w & 1;
  const int m0 = blockIdx.y * 128, n0 = blockIdx.x * 128;

  f32x4 acc[4][4];
#pragma unroll
  for (int m = 0; m < 4; ++m)
#pragma unroll
    for (int n = 0; n < 4; ++n) acc[m][n] = f32x4{0.f, 0.f, 0.f, 0.f};

  const int s0 = tid, s1 = tid + 256;
  const bf16* Ag0 = A + (size_t)(m0 + (s0 >> 2)) * 1024 + (s0 & 3) * 8;
  const bf16* Ag1 = A + (size_t)(m0 + (s1 >> 2)) * 1024 + (s1 & 3) * 8;
  const bf16* Bg0 = Bt + (size_t)(n0 + (s0 >> 2)) * 512 + (s0 & 3) * 8;
  const bf16* Bg1 = Bt + (size_t)(n0 + (s1 >> 2)) * 512 + (s1 & 3) * 8;
  bf16* Al0 = As + s0 * 8;
  bf16* Al1 = As + s1 * 8;
  bf16* Bl0 = Bs + s0 * 8;
  bf16* Bl1 = Bs + s1 * 8;

  const int fr = lane & 15;
  const int ko = (lane >> 4) * 8;
  const int rh = lane >> 4;

  for (int k0 = 0; k0 < 1024; k0 += 32) {
    GLD_LDS16(Ag0 + k0, Al0);
    GLD_LDS16(Ag1 + k0, Al1);
    GLD_LDS16(Bg0 + (k0 & 511), Bl0);
    GLD_LDS16(Bg1 + (k0 & 511), Bl1);
    __syncthreads();
    bf16x8 af[4], bfr[4];
#pragma unroll
    for (int m = 0; m < 4; ++m)
      af[m] = *reinterpret_cast<const bf16x8*>(As + (wr * 64 + m * 16 + fr) * 32 + ko);
#pragma unroll
    for (int n = 0; n < 4; ++n)
      bfr[n] = *reinterpret_cast<const bf16x8*>(Bs + (wc * 64 + n * 16 + fr) * 32 + ko);
#pragma unroll
    for (int m = 0; m < 4; ++m)
#pragma unroll
      for (int n = 0; n < 4; ++n)
        acc[m][n] = __builtin_amdgcn_mfma_f32_16x16x32_bf16(af[m], bfr[n], acc[m][n], 0, 0, 0);
    __syncthreads();
  }

#pragma unroll
  for (int m = 0; m < 4; ++m) {
#pragma unroll
    for (int n = 0; n < 4; ++n) {
      int col = n0 + wc * 64 + n * 16 + fr;
      float bv = bias[col];
#pragma unroll
      for (int r = 0; r < 4; ++r) {
        int row = m0 + wr * 64 + m * 16 + rh * 4 + r;
        if (row < 3136) {
          int b = row / 49, rr = row - (row / 49) * 49;
          out[((size_t)b * 512 + col) * 49 + rr] = acc[m][n][r] + bv;
        }
      }
    }
  }
}

// ---------------------------------------------------------------- attention
// one block = (b,h, chunk of 7 q-rows). MFMA QK^T + MFMA PV with register
// load queues; float-domain bisection top-k; sW aliases sLog; 22KB LDS.
// A-fragment rows >=7 are CLAMPED loads (garbage C rows 7..15 are discarded:
// MFMA output row f depends only on A row f).
__global__ __launch_bounds__(256, 7) void attn_kernel(const bf16* __restrict__ Qb,
                                                      const bf16* __restrict__ K,
                                                      const bf16* __restrict__ Vt,
                                                      const float* __restrict__ aw1p,
                                                      const float* __restrict__ aw2p,
                                                      bf16* __restrict__ aoutHL) {
  // XCD swizzle: 3584 = 8*448; XCD c gets wk in [c*448,(c+1)*448) => bh in [c*64,(c+1)*64)
  const int lin = blockIdx.x;
  const int wk = (lin & 7) * 448 + (lin >> 3);
  const int bh = wk / 7;
  const int chunk = wk - bh * 7;
  const int b = bh >> 3, h = bh & 7;
  const int r0 = chunk * 7;
  const int tid = threadIdx.x;
  const int lane = tid & 63, w = tid >> 6;
  __shared__ __align__(16) unsigned char sMem[21952];  // union: sLog f32[7][784] / sW bf16[8][808]
  float* sLog = reinterpret_cast<float*>(sMem);
  bf16* sW = reinterpret_cast<bf16*>(sMem);
  // LDS total ~22 KB -> 7 blocks/CU (14 blocks/CU dispatched = exactly 2 batches)

  const int fr = lane & 15, ko = (lane >> 4) * 8, rh = lane >> 4;

  // ---- Q fragment: direct global load, row clamped (rows 7..15 garbage-OK)
  const bf16* Qp = Qb + ((size_t)bh * 49 + r0) * 64;
  const int qrow = (fr < 7) ? fr : 6;
  const bf16x8 aq0 = *reinterpret_cast<const bf16x8*>(Qp + qrow * 64 + ko);
  const bf16x8 aq1 = *reinterpret_cast<const bf16x8*>(Qp + qrow * 64 + 32 + ko);

  // ---- QK^T via MFMA with a 4-deep K register queue
  const bf16* Kp = K + (size_t)bh * (784 * 64);
  {
    const int rbase = rh * 4;
    const bf16* kbase = Kp + (size_t)fr * 64 + ko;
    bf16x8 kq0[4], kq1[4];
#pragma unroll
    for (int s = 0; s < 4; ++s) {
      int nt = w + s * 4;
      int ntc = nt < 49 ? nt : 48;
      const bf16* kr = kbase + (size_t)ntc * 1024;
      kq0[s] = *reinterpret_cast<const bf16x8*>(kr);
      kq1[s] = *reinterpret_cast<const bf16x8*>(kr + 32);
    }
#pragma unroll
    for (int i = 0; i < 13; ++i) {
      const int s = i & 3;
      const int nt = w + i * 4;
      if (nt < 49) {
        f32x4 acc = {0.f, 0.f, 0.f, 0.f};
        acc = __builtin_amdgcn_mfma_f32_16x16x32_bf16(aq0, kq0[s], acc, 0, 0, 0);
        acc = __builtin_amdgcn_mfma_f32_16x16x32_bf16(aq1, kq1[s], acc, 0, 0, 0);
#pragma unroll
        for (int r = 0; r < 4; ++r) {
          int row = rbase + r;
          if (row < 7) sLog[row * 784 + nt * 16 + fr] = acc[r] * 0.125f;
        }
      }
      const int ntn = w + (i + 4) * 4;
      if (ntn < 49) {
        const bf16* kr = kbase + (size_t)ntn * 1024;
        kq0[s] = *reinterpret_cast<const bf16x8*>(kr);
        kq1[s] = *reinterpret_cast<const bf16x8*>(kr + 32);
      }
    }
  }
  __syncthreads();

  // ---- load logits for this wave's two rows into registers
  const int ra = w;
  const int rb = (w + 4 < 7) ? (w + 4) : w;  // wave 3 duplicates its row (benign)
  float va[13], vb[13];
#pragma unroll
  for (int i = 0; i < 13; ++i) {
    int m = lane + i * 64;
    va[i] = (m < 784) ? sLog[ra * 784 + m] : -INFINITY;
    vb[i] = (m < 784) ? sLog[rb * 784 + m] : -INFINITY;
  }
  __syncthreads();  // sLog fully consumed; sW aliasing writes may begin

  // row max
  float mxa = va[0], mxb = vb[0];
#pragma unroll
  for (int i = 1; i < 13; ++i) {
    mxa = fmaxf(mxa, va[i]);
    mxb = fmaxf(mxb, vb[i]);
  }
#pragma unroll
  for (int off = 32; off; off >>= 1) {
    mxa = fmaxf(mxa, __shfl_xor(mxa, off, 64));
    mxb = fmaxf(mxb, __shfl_xor(mxb, off, 64));
  }

  // ---- 4 bisection chains in key space, compares in the float domain.
  // v >= unkey(cand) <=> key(v) >= cand (monotone bijection on finite floats).
  // Early exit when count==k is exact; ties fall to full bisection -> >= kth
  // semantics identical to reference.
  unsigned int t1a = 0u, t2a = 0u, t1b = 0u, t2b = 0u;
  bool d1a = false, d2a = false, d1b = false, d2b = false;
  for (int bit = 31; bit >= 0; --bit) {
    const unsigned int mb = 1u << bit;
    if (!d1a) {
      float cf = unkey(t1a | mb);
      int n = 0;
#pragma unroll
      for (int i = 0; i < 13; ++i) n += __popcll(__ballot(va[i] >= cf));
      if (n >= 392) { t1a |= mb; d1a = (n == 392); }
    }
    if (!d2a) {
      float cf = unkey(t2a | mb);
      int n = 0;
#pragma unroll
      for (int i = 0; i < 13; ++i) n += __popcll(__ballot(va[i] >= cf));
      if (n >= 261) { t2a |= mb; d2a = (n == 261); }
    }
    if (!d1b) {
      float cf = unkey(t1b | mb);
      int n = 0;
#pragma unroll
      for (int i = 0; i < 13; ++i) n += __popcll(__ballot(vb[i] >= cf));
      if (n >= 392) { t1b |= mb; d1b = (n == 392); }
    }
    if (!d2b) {
      float cf = unkey(t2b | mb);
      int n = 0;
#pragma unroll
      for (int i = 0; i < 13; ++i) n += __popcll(__ballot(vb[i] >= cf));
      if (n >= 261) { t2b |= mb; d2b = (n == 261); }
    }
    if (d1a & d2a & d1b & d2b) break;
  }
  const float T1a = unkey(t1a), T2a = unkey(t2a);
  const float T1b = unkey(t1b), T2b = unkey(t2b);

  // ---- fused exp + z + weights (e kept in registers)
  const float aw1 = aw1p[0], aw2 = aw2p[0];
  float ea[13], eb[13];
  float z1a = 0.f, z2a = 0.f, z1b = 0.f, z2b = 0.f;
#pragma unroll
  for (int i = 0; i < 13; ++i) {
    ea[i] = __expf(va[i] - mxa);  // pads: exp(-inf)=0
    eb[i] = __expf(vb[i] - mxb);
    if (va[i] >= T1a) z1a += ea[i];
    if (va[i] >= T2a) z2a += ea[i];
    if (vb[i] >= T1b) z1b += eb[i];
    if (vb[i] >= T2b) z2b += eb[i];
  }
#pragma unroll
  for (int off = 32; off; off >>= 1) {
    z1a += __shfl_xor(z1a, off, 64);
    z2a += __shfl_xor(z2a, off, 64);
    z1b += __shfl_xor(z1b, off, 64);
    z2b += __shfl_xor(z2b, off, 64);
  }
  const float a1a = aw1 / z1a, a2a = aw2 / z2a;
  const float a1b = aw1 / z1b, a2b = aw2 / z2b;
#pragma unroll
  for (int i = 0; i < 13; ++i) {
    int m = lane + i * 64;
    if (m < 784) {
      float wa = ea[i] * (((va[i] >= T1a) ? a1a : 0.f) + ((va[i] >= T2a) ? a2a : 0.f));
      sW[ra * 808 + m] = __float2bfloat16(wa);
      float wb = eb[i] * (((vb[i] >= T1b) ? a1b : 0.f) + ((vb[i] >= T2b) ? a2b : 0.f));
      sW[rb * 808 + m] = __float2bfloat16(wb);
    }
  }
  if (lane < 16) {
    sW[ra * 808 + 784 + lane] = __float2bfloat16(0.f);
    sW[rb * 808 + 784 + lane] = __float2bfloat16(0.f);
  }

  // ---- PV V-queue prefetch issued BEFORE the barrier (latency hides under it)
  const bf16* vbase = Vt + ((size_t)bh * 64 + w * 16 + fr) * 800;
  bf16x8 vq[4];
#pragma unroll
  for (int s = 0; s < 4; ++s)
    vq[s] = *reinterpret_cast<const bf16x8*>(vbase + s * 32 + ko);
  __syncthreads();

  // ---- PV via MFMA: out[16][64] = W[16][800] x V^T; wave w owns d-tile w*16..
  // A rows 7..15 clamped to row 7 (allocated; may be garbage -> C rows >=7
  // discarded). Two accumulator chains halve the dependent-MFMA latency.
  const bf16* wrow = sW + ((fr < 7) ? fr : 7) * 808;
  f32x4 acc0 = {0.f, 0.f, 0.f, 0.f}, acc1 = {0.f, 0.f, 0.f, 0.f};
#pragma unroll
  for (int ks = 0; ks < 25; ++ks) {
    const int s = ks & 3;
    bf16x8 a = *reinterpret_cast<const bf16x8*>(wrow + ks * 32 + ko);
    if (ks & 1)
      acc1 = __builtin_amdgcn_mfma_f32_16x16x32_bf16(a, vq[s], acc1, 0, 0, 0);
    else
      acc0 = __builtin_amdgcn_mfma_f32_16x16x32_bf16(a, vq[s], acc0, 0, 0, 0);
    if (ks + 4 < 25)
      vq[s] = *reinterpret_cast<const bf16x8*>(vbase + (ks + 4) * 32 + ko);
  }
  acc0 += acc1;
#pragma unroll
  for (int r = 0; r < 4; ++r) {
    int row = rh * 4 + r;
    if (row < 7) {
      float v = acc0[r];
      bf16 hi = __float2bfloat16(v);
      bf16 lo = __float2bfloat16(v - __bfloat162float(hi));
      size_t base = ((size_t)(b * 49 + r0 + row)) * 1024 + h * 64 + w * 16 + fr;
      aoutHL[base] = hi;
      aoutHL[base + 512] = lo;
    }
  }
}

// ---------------------------------------------------------------- launch
extern "C" void kernel_launch(void* const* d_in, const int* in_sizes, int n_in, void* d_out,
                              int out_size, void* d_ws, size_t ws_size, hipStream_t stream) {
  const float* x = (const float*)d_in[0];
  const float* y = (const float*)d_in[1];
  const float* Wq = (const float*)d_in[2];
  const float* Wkv = (const float*)d_in[3];
  const float* Wproj = (const float*)d_in[4];
  const float* bproj = (const float*)d_in[5];
  const float* gamma = (const float*)d_in[6];
  const float* beta = (const float*)d_in[7];
  const float* aw1 = (const float*)d_in[8];
  const float* aw2 = (const float*)d_in[9];
  float* out = (float*)d_out;

  char* w = (char*)d_ws;
  const size_t SZ = 51380224ull;    // 64*784*512*2 bytes
  const size_t SZV = 52428800ull;   // 64*8*64*800*2 bytes (V^T, padded stride 800)
  bf16* pooledT = (bf16*)(w);       // [50176][512]; dead after lnrow
  bf16* yln = (bf16*)(w + SZ);      // [50176][512]; dead after kv gemm
  bf16* Kb = (bf16*)(w);            // reuses pooledT slot (after lnrow)
  bf16* Vt = (bf16*)(w + 2 * SZ);
  size_t off = 2 * SZ + SZV;
  bf16* xsTb = (bf16*)(w + off);    off += 3276800;   // [3200][512] bf16 (64 pad rows)
  bf16* Qb = (bf16*)(w + off);      off += 3276800;   // [B,8,49,64] bf16
  bf16* aoutHL = (bf16*)(w + off);  off += 6553600;   // [3200][1024] bf16 (hi|lo)
  bf16* wkvT = (bf16*)(w + off);    off += 1048576;   // [1024][512] bf16
  bf16* wqT = (bf16*)(w + off);     off += 524288;    // [512][512] bf16
  bf16* wpT = (bf16*)(w + off);     off += 524288;    // [512][512] bf16
  // peak ws use: ~170.4 MB

  prep_kernel<<<dim3(9344), dim3(256), 0, stream>>>(Wkv, Wq, Wproj, x, wkvT, wqT, wpT, xsTb, Vt);
  pool2t_kernel<<<dim3(4096), dim3(256), 0, stream>>>(y, pooledT);
  lnrow_kernel<<<dim3(12544), dim3(256), 0, stream>>>(pooledT, gamma, beta, yln);
  q_mfma<<<dim3(4, 25), dim3(256), 0, stream>>>(xsTb, wqT, Qb);
  kv_mfma<<<dim3(8, 392), dim3(256), 18432, stream>>>(yln, wkvT, Kb, Vt);
  attn_kernel<<<dim3(3584), dim3(256), 0, stream>>>(Qb, Kb, Vt, aw1, aw2, aoutHL);
  proj_mfma<<<dim3(4, 25), dim3(256), 0, stream>>>(aoutHL, wpT, bproj, out);
}

// Round 10
// 301.310 us; speedup vs baseline: 9.5236x; 1.0874x over previous
//
#include <hip/hip_runtime.h>
#include <hip/hip_bf16.h>

// MSCN fused pipeline, MI355X gfx950. Round 9: pool write XCD-merge swizzle,
// prep+pool / lnrow+q_mfma kernel merges, attn sLog bank-conflict pad.
// B=64, C=512, H=W=7 (N=49), HY=WY=28 (N1=784), heads=8, d=64, SCALE=0.125
// kc1 = 784//2 = 392, kc2 = 784//3 = 261

typedef __hip_bfloat16 bf16;
using bf16x8 = __attribute__((ext_vector_type(8))) short;  // 8 bf16 = 4 VGPRs
using f32x4 = __attribute__((ext_vector_type(4))) float;

#define DI __device__ __forceinline__

DI unsigned short b2u(float f) {
  bf16 h = __float2bfloat16(f);
  return *reinterpret_cast<unsigned short*>(&h);
}
DI float u2f(short s) { return __uint_as_float(((unsigned int)(unsigned short)s) << 16); }

// inverse of the monotone float->uint key map (key = sign? ~u : u|0x80000000)
DI float unkey(unsigned int k) {
  unsigned int u = (k & 0x80000000u) ? (k & 0x7FFFFFFFu) : ~k;
  return __uint_as_float(u);
}

#define GLD_LDS16(g, l)                                                              \
  __builtin_amdgcn_global_load_lds((const __attribute__((address_space(1))) unsigned int*)(g), \
                                   (__attribute__((address_space(3))) unsigned int*)(l), 16, 0, 0)

// ---------------------------------------------------------------- prep + pool (merged)
// blocks [0,512): WkvT; [512,768): WqT; [768,1024): WprojT; [1024,7296): xst;
// [7296,9344): vtpad; [9344,13440): pool2t (XCD-swizzled so all cg of one b
// share an XCD -> partial 64B-line writes merge in that XCD's L2).
__global__ __launch_bounds__(256) void prep_pool_kernel(
    const float* __restrict__ Wkv, const float* __restrict__ Wq, const float* __restrict__ Wproj,
    const float* __restrict__ x, const float* __restrict__ y, bf16* __restrict__ wkvT,
    bf16* __restrict__ wqT, bf16* __restrict__ wpT, bf16* __restrict__ xsTb,
    bf16* __restrict__ Vt, bf16* __restrict__ pooledT) {
  __shared__ float t[32][33];
  __shared__ float I[8][870];
  const int blk = blockIdx.x;
  const int tid = threadIdx.x;
  if (blk < 1024) {
    const float* W;
    bf16* WT;
    int N, bx, by;
    if (blk < 512) { W = Wkv; WT = wkvT; N = 1024; bx = blk & 31; by = blk >> 5; }
    else if (blk < 768) { W = Wq; WT = wqT; N = 512; bx = (blk - 512) & 15; by = (blk - 512) >> 4; }
    else { W = Wproj; WT = wpT; N = 512; bx = (blk - 768) & 15; by = (blk - 768) >> 4; }
    const int n0 = bx * 32, k0 = by * 32;
    for (int i = tid; i < 1024; i += 256) {
      int kr = i >> 5, nc = i & 31;
      t[kr][nc] = W[(size_t)(k0 + kr) * N + n0 + nc];
    }
    __syncthreads();
    for (int i = tid; i < 1024; i += 256) {
      int nr = i >> 5, kc = i & 31;
      WT[(size_t)(n0 + nr) * 512 + k0 + kc] = __float2bfloat16(t[kc][nr]);
    }
  } else if (blk < 7296) {
    int idx = (blk - 1024) * 256 + tid;
    int c = idx & 511;
    int rem = idx >> 9;
    int r = rem % 49, b = rem / 49;
    xsTb[idx] = __float2bfloat16(x[((size_t)b * 512 + c) * 49 + r]);
  } else if (blk < 9344) {
    int idx = (blk - 7296) * 256 + tid;  // 524288 total
    int row = idx >> 4, c = idx & 15;
    Vt[(size_t)row * 800 + 784 + c] = __float2bfloat16(0.f);
  } else {
    // pool: integral image, transposed out. XCD swizzle: p%8 is this block's
    // XCD; give XCD q the contiguous work range [q*512,(q+1)*512) covering
    // whole b's (64 cg each) so same-64B-line writes merge in one L2.
    const int p = blk - 9344;  // [0,4096)
    const int wk = (p & 7) * 512 + (p >> 3);
    const int b = wk >> 6, cg = wk & 63;
    const float* src = y + ((size_t)b * 512 + cg * 8) * 784;
    bf16* drow = pooledT + ((size_t)b * 784) * 512 + cg * 8;
    for (int i = tid; i < 6272; i += 256) {
      int pp = i / 784, j = i - pp * 784;
      int r = j / 28, c = j - r * 28;
      I[pp][(r + 1) * 30 + c + 1] = src[pp * 784 + j];
    }
    for (int i = tid; i < 8 * 58; i += 256) {
      int pp = i / 58, e = i - pp * 58;
      if (e < 30) I[pp][e] = 0.f;           // row 0
      else I[pp][(e - 29) * 30] = 0.f;      // col 0, rows 1..28
    }
    __syncthreads();
    if (tid < 224) {  // row prefix
      int pp = tid / 28, r = tid - (tid / 28) * 28;
      float run = 0.f;
      float* row = &I[pp][(r + 1) * 30 + 1];
#pragma unroll
      for (int c = 0; c < 28; ++c) { run += row[c]; row[c] = run; }
    }
    __syncthreads();
    if (tid < 224) {  // col prefix
      int pp = tid / 28, c = tid - (tid / 28) * 28;
      float run = 0.f;
      float* col = &I[pp][30 + c + 1];
#pragma unroll
      for (int r = 0; r < 28; ++r) { run += col[r * 30]; col[r * 30] = run; }
    }
    __syncthreads();
    for (int j = tid; j < 784; j += 256) {
      int r = j / 28, c = j - (j / 28) * 28;
      int r0[3], r1[3], c0[3], c1[3];
#pragma unroll
      for (int pk = 1; pk <= 3; ++pk) {
        r0[pk - 1] = max(r - pk, 0) * 30;
        r1[pk - 1] = (min(r + pk, 27) + 1) * 30;
        c0[pk - 1] = max(c - pk, 0);
        c1[pk - 1] = min(c + pk, 27) + 1;
      }
      unsigned int u[4];
#pragma unroll
      for (int q = 0; q < 4; ++q) {
        float vv[2];
#pragma unroll
        for (int tt = 0; tt < 2; ++tt) {
          const float* Ip = I[q * 2 + tt];
          float acc = 0.f;
#pragma unroll
          for (int k = 0; k < 3; ++k) {
            float s = Ip[r1[k] + c1[k]] - Ip[r0[k] + c1[k]] - Ip[r1[k] + c0[k]] + Ip[r0[k] + c0[k]];
            acc += s * ((k == 0) ? (1.f / 9.f) : (k == 1) ? (1.f / 25.f) : (1.f / 49.f));
          }
          vv[tt] = acc;
        }
        u[q] = (unsigned int)b2u(vv[0]) | ((unsigned int)b2u(vv[1]) << 16);
      }
      *reinterpret_cast<uint4*>(drow + (size_t)j * 512) = make_uint4(u[0], u[1], u[2], u[3]);
    }
  }
}

// ---------------------------------------------------------------- lnrow + q_mfma (merged)
// blocks [0,100): q_mfma (bx=blk&3, by=blk>>2); [100,12644): row LayerNorm.
__global__ __launch_bounds__(256) void ln_q_kernel(const bf16* __restrict__ pooledT,
                                                   const float* __restrict__ gamma,
                                                   const float* __restrict__ beta,
                                                   bf16* __restrict__ yln,
                                                   const bf16* __restrict__ A,
                                                   const bf16* __restrict__ Bt,
                                                   bf16* __restrict__ Qb) {
  __shared__ __align__(16) bf16 As[128 * 32];
  __shared__ __align__(16) bf16 Bs[128 * 32];
  const int blk = blockIdx.x;
  const int tid = threadIdx.x;
  if (blk < 100) {
    const int lane = tid & 63;
    const int w = tid >> 6, wr = w >> 1, wc = w & 1;
    const int m0 = (blk >> 2) * 128, n0 = (blk & 3) * 128;
    f32x4 acc[4][4];
#pragma unroll
    for (int m = 0; m < 4; ++m)
#pragma unroll
      for (int n = 0; n < 4; ++n) acc[m][n] = f32x4{0.f, 0.f, 0.f, 0.f};
    const int s0 = tid, s1 = tid + 256;
    const bf16* Ag0 = A + (size_t)(m0 + (s0 >> 2)) * 512 + (s0 & 3) * 8;
    const bf16* Ag1 = A + (size_t)(m0 + (s1 >> 2)) * 512 + (s1 & 3) * 8;
    const bf16* Bg0 = Bt + (size_t)(n0 + (s0 >> 2)) * 512 + (s0 & 3) * 8;
    const bf16* Bg1 = Bt + (size_t)(n0 + (s1 >> 2)) * 512 + (s1 & 3) * 8;
    bf16* Al0 = As + s0 * 8;
    bf16* Al1 = As + s1 * 8;
    bf16* Bl0 = Bs + s0 * 8;
    bf16* Bl1 = Bs + s1 * 8;
    const int fr = lane & 15;
    const int ko = (lane >> 4) * 8;
    const int rh = lane >> 4;
    for (int k0 = 0; k0 < 512; k0 += 32) {
      GLD_LDS16(Ag0 + k0, Al0);
      GLD_LDS16(Ag1 + k0, Al1);
      GLD_LDS16(Bg0 + k0, Bl0);
      GLD_LDS16(Bg1 + k0, Bl1);
      __syncthreads();
      bf16x8 af[4], bfr[4];
#pragma unroll
      for (int m = 0; m < 4; ++m)
        af[m] = *reinterpret_cast<const bf16x8*>(As + (wr * 64 + m * 16 + fr) * 32 + ko);
#pragma unroll
      for (int n = 0; n < 4; ++n)
        bfr[n] = *reinterpret_cast<const bf16x8*>(Bs + (wc * 64 + n * 16 + fr) * 32 + ko);
#pragma unroll
      for (int m = 0; m < 4; ++m)
#pragma unroll
        for (int n = 0; n < 4; ++n)
          acc[m][n] = __builtin_amdgcn_mfma_f32_16x16x32_bf16(af[m], bfr[n], acc[m][n], 0, 0, 0);
      __syncthreads();
    }
#pragma unroll
    for (int m = 0; m < 4; ++m) {
#pragma unroll
      for (int n = 0; n < 4; ++n) {
        int col = n0 + wc * 64 + n * 16 + fr;  // 0..511: h=col>>6, d=col&63
        const size_t cbase = ((size_t)(col >> 6)) * (49 * 64) + (col & 63);
#pragma unroll
        for (int r = 0; r < 4; ++r) {
          int row = m0 + wr * 64 + m * 16 + rh * 4 + r;
          if (row < 3136) {
            int b = row / 49, rr = row - (row / 49) * 49;
            Qb[((size_t)b * 8) * (49 * 64) + cbase + (size_t)rr * 64] = __float2bfloat16(acc[m][n][r]);
          }
        }
      }
    }
  } else {
    const int row = (blk - 100) * 4 + (tid >> 6);
    const int lane = tid & 63;
    bf16x8 raw = *reinterpret_cast<const bf16x8*>(pooledT + (size_t)row * 512 + lane * 8);
    float v[8];
    float s = 0.f, s2 = 0.f;
#pragma unroll
    for (int j = 0; j < 8; ++j) {
      v[j] = u2f(raw[j]);
      s += v[j];
      s2 += v[j] * v[j];
    }
#pragma unroll
    for (int off = 32; off; off >>= 1) {
      s += __shfl_xor(s, off, 64);
      s2 += __shfl_xor(s2, off, 64);
    }
    float mu = s * (1.f / 512.f);
    float rs = rsqrtf(s2 * (1.f / 512.f) - mu * mu + 1e-5f);
    float4 g0 = *reinterpret_cast<const float4*>(gamma + lane * 8);
    float4 g1 = *reinterpret_cast<const float4*>(gamma + lane * 8 + 4);
    float4 e0 = *reinterpret_cast<const float4*>(beta + lane * 8);
    float4 e1 = *reinterpret_cast<const float4*>(beta + lane * 8 + 4);
    float gg[8] = {g0.x, g0.y, g0.z, g0.w, g1.x, g1.y, g1.z, g1.w};
    float bb[8] = {e0.x, e0.y, e0.z, e0.w, e1.x, e1.y, e1.z, e1.w};
    unsigned int u[4];
#pragma unroll
    for (int q = 0; q < 4; ++q) {
      float o0 = (v[2 * q] - mu) * rs * gg[2 * q] + bb[2 * q];
      float o1 = (v[2 * q + 1] - mu) * rs * gg[2 * q + 1] + bb[2 * q + 1];
      u[q] = (unsigned int)b2u(o0) | ((unsigned int)b2u(o1) << 16);
    }
    *reinterpret_cast<uint4*>(yln + (size_t)row * 512 + lane * 8) =
        make_uint4(u[0], u[1], u[2], u[3]);
  }
}

// ---------------------------------------------------------------- kv MFMA GEMM
__global__ __launch_bounds__(256) void kv_mfma(const bf16* __restrict__ A,
                                               const bf16* __restrict__ Bt,
                                               bf16* __restrict__ Kb, bf16* __restrict__ Vt) {
  extern __shared__ __align__(16) bf16 smem[];  // 18432 B dynamic
  bf16* As = smem;                              // [128*32]
  bf16* Bs = smem + 128 * 32;                   // [128*32]
  const int tid = threadIdx.x;
  const int lane = tid & 63;
  const int w = tid >> 6, wr = w >> 1, wc = w & 1;

  // XCD swizzle: XCD c handles y-tiles [c*49, c*49+49), all 8 x-tiles (A-tile L2 reuse)
  const int lin = blockIdx.y * 8 + blockIdx.x;
  const int c8 = lin & 7, j = lin >> 3;
  const int ex = j & 7, ey = c8 * 49 + (j >> 3);
  const int m0 = ey * 128, n0 = ex * 128;

  f32x4 acc[4][4];
#pragma unroll
  for (int m = 0; m < 4; ++m)
#pragma unroll
    for (int n = 0; n < 4; ++n) acc[m][n] = f32x4{0.f, 0.f, 0.f, 0.f};

  const int s0 = tid, s1 = tid + 256;  // 16B segments; seg s: row=s>>2, koff=(s&3)*8
  const bf16* Ag0 = A + (size_t)(m0 + (s0 >> 2)) * 512 + (s0 & 3) * 8;
  const bf16* Ag1 = A + (size_t)(m0 + (s1 >> 2)) * 512 + (s1 & 3) * 8;
  const bf16* Bg0 = Bt + (size_t)(n0 + (s0 >> 2)) * 512 + (s0 & 3) * 8;
  const bf16* Bg1 = Bt + (size_t)(n0 + (s1 >> 2)) * 512 + (s1 & 3) * 8;
  bf16* Al0 = As + s0 * 8;
  bf16* Al1 = As + s1 * 8;
  bf16* Bl0 = Bs + s0 * 8;
  bf16* Bl1 = Bs + s1 * 8;

  const int fr = lane & 15;        // fragment row/col within 16
  const int ko = (lane >> 4) * 8;  // k offset within 32
  const int rh = lane >> 4;

  for (int k0 = 0; k0 < 512; k0 += 32) {
    GLD_LDS16(Ag0 + k0, Al0);
    GLD_LDS16(Ag1 + k0, Al1);
    GLD_LDS16(Bg0 + k0, Bl0);
    GLD_LDS16(Bg1 + k0, Bl1);
    __syncthreads();  // vmcnt drained before barrier
    bf16x8 af[4], bfr[4];
#pragma unroll
    for (int m = 0; m < 4; ++m)
      af[m] = *reinterpret_cast<const bf16x8*>(As + (wr * 64 + m * 16 + fr) * 32 + ko);
#pragma unroll
    for (int n = 0; n < 4; ++n)
      bfr[n] = *reinterpret_cast<const bf16x8*>(Bs + (wc * 64 + n * 16 + fr) * 32 + ko);
#pragma unroll
    for (int m = 0; m < 4; ++m)
#pragma unroll
      for (int n = 0; n < 4; ++n)
        acc[m][n] = __builtin_amdgcn_mfma_f32_16x16x32_bf16(af[m], bfr[n], acc[m][n], 0, 0, 0);
    __syncthreads();
  }

  if (n0 < 512) {
    // ---- K epilogue: coalesced [b,h,m,d] writes
#pragma unroll
    for (int m = 0; m < 4; ++m) {
#pragma unroll
      for (int n = 0; n < 4; ++n) {
        int col = n0 + wc * 64 + n * 16 + fr;
        const size_t cbase = ((size_t)(col >> 6)) * (784 * 64) + (col & 63);
#pragma unroll
        for (int r = 0; r < 4; ++r) {
          int row = m0 + wr * 64 + m * 16 + rh * 4 + r;
          int b = row / 784, n1 = row - (row / 784) * 784;
          Kb[((size_t)b * 8) * (784 * 64) + cbase + (size_t)n1 * 64] = __float2bfloat16(acc[m][n][r]);
        }
      }
    }
  } else {
    // ---- V epilogue: LDS-staged transpose -> Vt [b*8+h][d][800]
    bf16* stage = smem;  // [128 cols][72 rows-padded]
#pragma unroll
    for (int p = 0; p < 2; ++p) {
      __syncthreads();
      if (wr == p) {
#pragma unroll
        for (int m = 0; m < 4; ++m) {
#pragma unroll
          for (int n = 0; n < 4; ++n) {
            int coll = wc * 64 + n * 16 + fr;
            int rowl = m * 16 + rh * 4;
            unsigned int u0 = (unsigned int)b2u(acc[m][n][0]) | ((unsigned int)b2u(acc[m][n][1]) << 16);
            unsigned int u1 = (unsigned int)b2u(acc[m][n][2]) | ((unsigned int)b2u(acc[m][n][3]) << 16);
            *reinterpret_cast<uint2*>(stage + coll * 72 + rowl) = make_uint2(u0, u1);
          }
        }
      }
      __syncthreads();
      const int rbase = m0 + p * 64;
      for (int i = tid; i < 1024; i += 256) {
        int cc = i >> 3, tc = i & 7;
        int colg = n0 + cc;  // >= 512
        int h = (colg >> 6) & 7, d = colg & 63;
        int rs = rbase + tc * 8;
        int b = rs / 784, n1 = rs - b * 784;
        bf16x8 val = *reinterpret_cast<const bf16x8*>(stage + cc * 72 + tc * 8);
        bf16* dst = Vt + (((size_t)b * 8 + h) * 64 + d) * 800 + n1;
        if (n1 <= 776) {
          *reinterpret_cast<bf16x8*>(dst) = val;
        } else {
#pragma unroll
          for (int jj = 0; jj < 8; ++jj) {
            int rr = rs + jj;
            int bb2 = rr / 784, nn1 = rr - bb2 * 784;
            bf16 hv;
            *reinterpret_cast<short*>(&hv) = val[jj];
            Vt[(((size_t)bb2 * 8 + h) * 64 + d) * 800 + nn1] = hv;
          }
        }
      }
    }
  }
}

// ---------------------------------------------------------------- proj MFMA GEMM
__global__ __launch_bounds__(256) void proj_mfma(const bf16* __restrict__ A,
                                                 const bf16* __restrict__ Bt,
                                                 const float* __restrict__ bias,
                                                 float* __restrict__ out) {
  __shared__ __align__(16) bf16 As[128 * 32];
  __shared__ __align__(16) bf16 Bs[128 * 32];
  const int tid = threadIdx.x;
  const int lane = tid & 63;
  const int w = tid >> 6, wr = w >> 1, wc = w & 1;
  const int m0 = blockIdx.y * 128, n0 = blockIdx.x * 128;

  f32x4 acc[4][4];
#pragma unroll
  for (int m = 0; m < 4; ++m)
#pragma unroll
    for (int n = 0; n < 4; ++n) acc[m][n] = f32x4{0.f, 0.f, 0.f, 0.f};

  const int s0 = tid, s1 = tid + 256;
  const bf16* Ag0 = A + (size_t)(m0 + (s0 >> 2)) * 1024 + (s0 & 3) * 8;
  const bf16* Ag1 = A + (size_t)(m0 + (s1 >> 2)) * 1024 + (s1 & 3) * 8;
  const bf16* Bg0 = Bt + (size_t)(n0 + (s0 >> 2)) * 512 + (s0 & 3) * 8;
  const bf16* Bg1 = Bt + (size_t)(n0 + (s1 >> 2)) * 512 + (s1 & 3) * 8;
  bf16* Al0 = As + s0 * 8;
  bf16* Al1 = As + s1 * 8;
  bf16* Bl0 = Bs + s0 * 8;
  bf16* Bl1 = Bs + s1 * 8;

  const int fr = lane & 15;
  const int ko = (lane >> 4) * 8;
  const int rh = lane >> 4;

  for (int k0 = 0; k0 < 1024; k0 += 32) {
    GLD_LDS16(Ag0 + k0, Al0);
    GLD_LDS16(Ag1 + k0, Al1);
    GLD_LDS16(Bg0 + (k0 & 511), Bl0);
    GLD_LDS16(Bg1 + (k0 & 511), Bl1);
    __syncthreads();
    bf16x8 af[4], bfr[4];
#pragma unroll
    for (int m = 0; m < 4; ++m)
      af[m] = *reinterpret_cast<const bf16x8*>(As + (wr * 64 + m * 16 + fr) * 32 + ko);
#pragma unroll
    for (int n = 0; n < 4; ++n)
      bfr[n] = *reinterpret_cast<const bf16x8*>(Bs + (wc * 64 + n * 16 + fr) * 32 + ko);
#pragma unroll
    for (int m = 0; m < 4; ++m)
#pragma unroll
      for (int n = 0; n < 4; ++n)
        acc[m][n] = __builtin_amdgcn_mfma_f32_16x16x32_bf16(af[m], bfr[n], acc[m][n], 0, 0, 0);
    __syncthreads();
  }

#pragma unroll
  for (int m = 0; m < 4; ++m) {
#pragma unroll
    for (int n = 0; n < 4; ++n) {
      int col = n0 + wc * 64 + n * 16 + fr;
      float bv = bias[col];
#pragma unroll
      for (int r = 0; r < 4; ++r) {
        int row = m0 + wr * 64 + m * 16 + rh * 4 + r;
        if (row < 3136) {
          int b = row / 49, rr = row - (row / 49) * 49;
          out[((size_t)b * 512 + col) * 49 + rr] = acc[m][n][r] + bv;
        }
      }
    }
  }
}

// ---------------------------------------------------------------- attention
// one block = (b,h, chunk of 7 q-rows). MFMA QK^T + MFMA PV with register
// load queues; float-domain bisection top-k; sW aliases sLog (row stride 786
// f32 -> row offset = 8 banks mod 32, breaking the 4-way store conflict).
__global__ __launch_bounds__(256, 7) void attn_kernel(const bf16* __restrict__ Qb,
                                                      const bf16* __restrict__ K,
                                                      const bf16* __restrict__ Vt,
                                                      const float* __restrict__ aw1p,
                                                      const float* __restrict__ aw2p,
                                                      bf16* __restrict__ aoutHL) {
  // XCD swizzle: 3584 = 8*448; XCD c gets wk in [c*448,(c+1)*448) => bh in [c*64,(c+1)*64)
  const int lin = blockIdx.x;
  const int wk = (lin & 7) * 448 + (lin >> 3);
  const int bh = wk / 7;
  const int chunk = wk - bh * 7;
  const int b = bh >> 3, h = bh & 7;
  const int r0 = chunk * 7;
  const int tid = threadIdx.x;
  const int lane = tid & 63, w = tid >> 6;
  __shared__ __align__(16) unsigned char sMem[22008];  // union: sLog f32[7][786] / sW bf16[8][808]
  float* sLog = reinterpret_cast<float*>(sMem);
  bf16* sW = reinterpret_cast<bf16*>(sMem);
  // LDS ~22.0 KB -> 7 blocks/CU

  const int fr = lane & 15, ko = (lane >> 4) * 8, rh = lane >> 4;

  // ---- Q fragment: direct global load, row clamped (rows 7..15 garbage-OK)
  const bf16* Qp = Qb + ((size_t)bh * 49 + r0) * 64;
  const int qrow = (fr < 7) ? fr : 6;
  const bf16x8 aq0 = *reinterpret_cast<const bf16x8*>(Qp + qrow * 64 + ko);
  const bf16x8 aq1 = *reinterpret_cast<const bf16x8*>(Qp + qrow * 64 + 32 + ko);

  // ---- QK^T via MFMA with a 4-deep K register queue
  const bf16* Kp = K + (size_t)bh * (784 * 64);
  {
    const int rbase = rh * 4;
    const bf16* kbase = Kp + (size_t)fr * 64 + ko;
    bf16x8 kq0[4], kq1[4];
#pragma unroll
    for (int s = 0; s < 4; ++s) {
      int nt = w + s * 4;
      int ntc = nt < 49 ? nt : 48;
      const bf16* kr = kbase + (size_t)ntc * 1024;
      kq0[s] = *reinterpret_cast<const bf16x8*>(kr);
      kq1[s] = *reinterpret_cast<const bf16x8*>(kr + 32);
    }
#pragma unroll
    for (int i = 0; i < 13; ++i) {
      const int s = i & 3;
      const int nt = w + i * 4;
      if (nt < 49) {
        f32x4 acc = {0.f, 0.f, 0.f, 0.f};
        acc = __builtin_amdgcn_mfma_f32_16x16x32_bf16(aq0, kq0[s], acc, 0, 0, 0);
        acc = __builtin_amdgcn_mfma_f32_16x16x32_bf16(aq1, kq1[s], acc, 0, 0, 0);
#pragma unroll
        for (int r = 0; r < 4; ++r) {
          int row = rbase + r;
          if (row < 7) sLog[row * 786 + nt * 16 + fr] = acc[r] * 0.125f;
        }
      }
      const int ntn = w + (i + 4) * 4;
      if (ntn < 49) {
        const bf16* kr = kbase + (size_t)ntn * 1024;
        kq0[s] = *reinterpret_cast<const bf16x8*>(kr);
        kq1[s] = *reinterpret_cast<const bf16x8*>(kr + 32);
      }
    }
  }
  __syncthreads();

  // ---- load logits for this wave's two rows into registers
  const int ra = w;
  const int rb = (w + 4 < 7) ? (w + 4) : w;  // wave 3 duplicates its row (benign)
  float va[13], vb[13];
#pragma unroll
  for (int i = 0; i < 13; ++i) {
    int m = lane + i * 64;
    va[i] = (m < 784) ? sLog[ra * 786 + m] : -INFINITY;
    vb[i] = (m < 784) ? sLog[rb * 786 + m] : -INFINITY;
  }
  __syncthreads();  // sLog fully consumed; sW aliasing writes may begin

  // row max
  float mxa = va[0], mxb = vb[0];
#pragma unroll
  for (int i = 1; i < 13; ++i) {
    mxa = fmaxf(mxa, va[i]);
    mxb = fmaxf(mxb, vb[i]);
  }
#pragma unroll
  for (int off = 32; off; off >>= 1) {
    mxa = fmaxf(mxa, __shfl_xor(mxa, off, 64));
    mxb = fmaxf(mxb, __shfl_xor(mxb, off, 64));
  }

  // ---- 4 bisection chains in key space, compares in the float domain.
  // v >= unkey(cand) <=> key(v) >= cand (monotone bijection on finite floats).
  // Early exit when count==k is exact; ties fall to full bisection -> >= kth
  // semantics identical to reference.
  unsigned int t1a = 0u, t2a = 0u, t1b = 0u, t2b = 0u;
  bool d1a = false, d2a = false, d1b = false, d2b = false;
  for (int bit = 31; bit >= 0; --bit) {
    const unsigned int mb = 1u << bit;
    if (!d1a) {
      float cf = unkey(t1a | mb);
      int n = 0;
#pragma unroll
      for (int i = 0; i < 13; ++i) n += __popcll(__ballot(va[i] >= cf));
      if (n >= 392) { t1a |= mb; d1a = (n == 392); }
    }
    if (!d2a) {
      float cf = unkey(t2a | mb);
      int n = 0;
#pragma unroll
      for (int i = 0; i < 13; ++i) n += __popcll(__ballot(va[i] >= cf));
      if (n >= 261) { t2a |= mb; d2a = (n == 261); }
    }
    if (!d1b) {
      float cf = unkey(t1b | mb);
      int n = 0;
#pragma unroll
      for (int i = 0; i < 13; ++i) n += __popcll(__ballot(vb[i] >= cf));
      if (n >= 392) { t1b |= mb; d1b = (n == 392); }
    }
    if (!d2b) {
      float cf = unkey(t2b | mb);
      int n = 0;
#pragma unroll
      for (int i = 0; i < 13; ++i) n += __popcll(__ballot(vb[i] >= cf));
      if (n >= 261) { t2b |= mb; d2b = (n == 261); }
    }
    if (d1a & d2a & d1b & d2b) break;
  }
  const float T1a = unkey(t1a), T2a = unkey(t2a);
  const float T1b = unkey(t1b), T2b = unkey(t2b);

  // ---- fused exp + z + weights (e kept in registers)
  const float aw1 = aw1p[0], aw2 = aw2p[0];
  float ea[13], eb[13];
  float z1a = 0.f, z2a = 0.f, z1b = 0.f, z2b = 0.f;
#pragma unroll
  for (int i = 0; i < 13; ++i) {
    ea[i] = __expf(va[i] - mxa);  // pads: exp(-inf)=0
    eb[i] = __expf(vb[i] - mxb);
    if (va[i] >= T1a) z1a += ea[i];
    if (va[i] >= T2a) z2a += ea[i];
    if (vb[i] >= T1b) z1b += eb[i];
    if (vb[i] >= T2b) z2b += eb[i];
  }
#pragma unroll
  for (int off = 32; off; off >>= 1) {
    z1a += __shfl_xor(z1a, off, 64);
    z2a += __shfl_xor(z2a, off, 64);
    z1b += __shfl_xor(z1b, off, 64);
    z2b += __shfl_xor(z2b, off, 64);
  }
  const float a1a = aw1 / z1a, a2a = aw2 / z2a;
  const float a1b = aw1 / z1b, a2b = aw2 / z2b;
#pragma unroll
  for (int i = 0; i < 13; ++i) {
    int m = lane + i * 64;
    if (m < 784) {
      float wa = ea[i] * (((va[i] >= T1a) ? a1a : 0.f) + ((va[i] >= T2a) ? a2a : 0.f));
      sW[ra * 808 + m] = __float2bfloat16(wa);
      float wb = eb[i] * (((vb[i] >= T1b) ? a1b : 0.f) + ((vb[i] >= T2b) ? a2b : 0.f));
      sW[rb * 808 + m] = __float2bfloat16(wb);
    }
  }
  if (lane < 16) {
    sW[ra * 808 + 784 + lane] = __float2bfloat16(0.f);
    sW[rb * 808 + 784 + lane] = __float2bfloat16(0.f);
  }

  // ---- PV V-queue prefetch issued BEFORE the barrier (latency hides under it)
  const bf16* vbase = Vt + ((size_t)bh * 64 + w * 16 + fr) * 800;
  bf16x8 vq[4];
#pragma unroll
  for (int s = 0; s < 4; ++s)
    vq[s] = *reinterpret_cast<const bf16x8*>(vbase + s * 32 + ko);
  __syncthreads();

  // ---- PV via MFMA: out[16][64] = W[16][800] x V^T; wave w owns d-tile w*16..
  // A rows 7..15 clamped to row 7 (allocated; may be garbage -> C rows >=7
  // discarded). Two accumulator chains halve the dependent-MFMA latency.
  const bf16* wrow = sW + ((fr < 7) ? fr : 7) * 808;
  f32x4 acc0 = {0.f, 0.f, 0.f, 0.f}, acc1 = {0.f, 0.f, 0.f, 0.f};
#pragma unroll
  for (int ks = 0; ks < 25; ++ks) {
    const int s = ks & 3;
    bf16x8 a = *reinterpret_cast<const bf16x8*>(wrow + ks * 32 + ko);
    if (ks & 1)
      acc1 = __builtin_amdgcn_mfma_f32_16x16x32_bf16(a, vq[s], acc1, 0, 0, 0);
    else
      acc0 = __builtin_amdgcn_mfma_f32_16x16x32_bf16(a, vq[s], acc0, 0, 0, 0);
    if (ks + 4 < 25)
      vq[s] = *reinterpret_cast<const bf16x8*>(vbase + (ks + 4) * 32 + ko);
  }
  acc0 += acc1;
#pragma unroll
  for (int r = 0; r < 4; ++r) {
    int row = rh * 4 + r;
    if (row < 7) {
      float v = acc0[r];
      bf16 hi = __float2bfloat16(v);
      bf16 lo = __float2bfloat16(v - __bfloat162float(hi));
      size_t base = ((size_t)(b * 49 + r0 + row)) * 1024 + h * 64 + w * 16 + fr;
      aoutHL[base] = hi;
      aoutHL[base + 512] = lo;
    }
  }
}

// ---------------------------------------------------------------- launch
extern "C" void kernel_launch(void* const* d_in, const int* in_sizes, int n_in, void* d_out,
                              int out_size, void* d_ws, size_t ws_size, hipStream_t stream) {
  const float* x = (const float*)d_in[0];
  const float* y = (const float*)d_in[1];
  const float* Wq = (const float*)d_in[2];
  const float* Wkv = (const float*)d_in[3];
  const float* Wproj = (const float*)d_in[4];
  const float* bproj = (const float*)d_in[5];
  const float* gamma = (const float*)d_in[6];
  const float* beta = (const float*)d_in[7];
  const float* aw1 = (const float*)d_in[8];
  const float* aw2 = (const float*)d_in[9];
  float* out = (float*)d_out;

  char* w = (char*)d_ws;
  const size_t SZ = 51380224ull;    // 64*784*512*2 bytes
  const size_t SZV = 52428800ull;   // 64*8*64*800*2 bytes (V^T, padded stride 800)
  bf16* pooledT = (bf16*)(w);       // [50176][512]; dead after lnrow
  bf16* yln = (bf16*)(w + SZ);      // [50176][512]; dead after kv gemm
  bf16* Kb = (bf16*)(w);            // reuses pooledT slot (after lnrow)
  bf16* Vt = (bf16*)(w + 2 * SZ);
  size_t off = 2 * SZ + SZV;
  bf16* xsTb = (bf16*)(w + off);    off += 3276800;   // [3200][512] bf16 (64 pad rows)
  bf16* Qb = (bf16*)(w + off);      off += 3276800;   // [B,8,49,64] bf16
  bf16* aoutHL = (bf16*)(w + off);  off += 6553600;   // [3200][1024] bf16 (hi|lo)
  bf16* wkvT = (bf16*)(w + off);    off += 1048576;   // [1024][512] bf16
  bf16* wqT = (bf16*)(w + off);     off += 524288;    // [512][512] bf16
  bf16* wpT = (bf16*)(w + off);     off += 524288;    // [512][512] bf16
  // peak ws use: ~170.4 MB

  prep_pool_kernel<<<dim3(13440), dim3(256), 0, stream>>>(Wkv, Wq, Wproj, x, y, wkvT, wqT, wpT,
                                                          xsTb, Vt, pooledT);
  ln_q_kernel<<<dim3(12644), dim3(256), 0, stream>>>(pooledT, gamma, beta, yln, xsTb, wqT, Qb);
  kv_mfma<<<dim3(8, 392), dim3(256), 18432, stream>>>(yln, wkvT, Kb, Vt);
  attn_kernel<<<dim3(3584), dim3(256), 0, stream>>>(Qb, Kb, Vt, aw1, aw2, aoutHL);
  proj_mfma<<<dim3(4, 25), dim3(256), 0, stream>>>(aoutHL, wpT, bproj, out);
}

// Round 11
// 298.840 us; speedup vs baseline: 9.6023x; 1.0083x over previous
//
#include <hip/hip_runtime.h>
#include <hip/hip_bf16.h>

// MSCN fused pipeline, MI355X gfx950. Round 10: pool via wave-parallel 2D
// prefix scan (shfl row-scan + register col-scan), LDS union -> 6 blocks/CU.
// B=64, C=512, H=W=7 (N=49), HY=WY=28 (N1=784), heads=8, d=64, SCALE=0.125
// kc1 = 784//2 = 392, kc2 = 784//3 = 261

typedef __hip_bfloat16 bf16;
using bf16x8 = __attribute__((ext_vector_type(8))) short;  // 8 bf16 = 4 VGPRs
using f32x4 = __attribute__((ext_vector_type(4))) float;

#define DI __device__ __forceinline__

DI unsigned short b2u(float f) {
  bf16 h = __float2bfloat16(f);
  return *reinterpret_cast<unsigned short*>(&h);
}
DI float u2f(short s) { return __uint_as_float(((unsigned int)(unsigned short)s) << 16); }

// inverse of the monotone float->uint key map (key = sign? ~u : u|0x80000000)
DI float unkey(unsigned int k) {
  unsigned int u = (k & 0x80000000u) ? (k & 0x7FFFFFFFu) : ~k;
  return __uint_as_float(u);
}

#define GLD_LDS16(g, l)                                                              \
  __builtin_amdgcn_global_load_lds((const __attribute__((address_space(1))) unsigned int*)(g), \
                                   (__attribute__((address_space(3))) unsigned int*)(l), 16, 0, 0)

// ---------------------------------------------------------------- prep + pool (merged)
// blocks [0,512): WkvT; [512,768): WqT; [768,1024): WprojT; [1024,7296): xst;
// [7296,9344): vtpad; [9344,13440): pool (XCD-swizzled, wave-parallel scan).
__global__ __launch_bounds__(256) void prep_pool_kernel(
    const float* __restrict__ Wkv, const float* __restrict__ Wq, const float* __restrict__ Wproj,
    const float* __restrict__ x, const float* __restrict__ y, bf16* __restrict__ wkvT,
    bf16* __restrict__ wqT, bf16* __restrict__ wpT, bf16* __restrict__ xsTb,
    bf16* __restrict__ Vt, bf16* __restrict__ pooledT) {
  __shared__ __align__(16) unsigned char pMem[26912];  // union: t f32[32][33] / I f32[8][841]
  const int blk = blockIdx.x;
  const int tid = threadIdx.x;
  if (blk < 1024) {
    float(*t)[33] = reinterpret_cast<float(*)[33]>(pMem);
    const float* W;
    bf16* WT;
    int N, bx, by;
    if (blk < 512) { W = Wkv; WT = wkvT; N = 1024; bx = blk & 31; by = blk >> 5; }
    else if (blk < 768) { W = Wq; WT = wqT; N = 512; bx = (blk - 512) & 15; by = (blk - 512) >> 4; }
    else { W = Wproj; WT = wpT; N = 512; bx = (blk - 768) & 15; by = (blk - 768) >> 4; }
    const int n0 = bx * 32, k0 = by * 32;
    for (int i = tid; i < 1024; i += 256) {
      int kr = i >> 5, nc = i & 31;
      t[kr][nc] = W[(size_t)(k0 + kr) * N + n0 + nc];
    }
    __syncthreads();
    for (int i = tid; i < 1024; i += 256) {
      int nr = i >> 5, kc = i & 31;
      WT[(size_t)(n0 + nr) * 512 + k0 + kc] = __float2bfloat16(t[kc][nr]);
    }
  } else if (blk < 7296) {
    int idx = (blk - 1024) * 256 + tid;
    int c = idx & 511;
    int rem = idx >> 9;
    int r = rem % 49, b = rem / 49;
    xsTb[idx] = __float2bfloat16(x[((size_t)b * 512 + c) * 49 + r]);
  } else if (blk < 9344) {
    int idx = (blk - 7296) * 256 + tid;  // 524288 total
    int row = idx >> 4, c = idx & 15;
    Vt[(size_t)row * 800 + 784 + c] = __float2bfloat16(0.f);
  } else {
    // pool: wave-parallel 2D prefix scan. XCD swizzle: all 64 cg-blocks of a
    // given b land on one XCD so partial 64B-line writes merge in its L2.
    float(*I)[841] = reinterpret_cast<float(*)[841]>(pMem);  // [plane][29*29], stride 29
    const int p = blk - 9344;  // [0,4096)
    const int wk = (p & 7) * 512 + (p >> 3);
    const int b = wk >> 6, cg = wk & 63;
    const float* srcb = y + ((size_t)b * 512 + cg * 8) * 784;
    bf16* drow = pooledT + ((size_t)b * 784) * 512 + cg * 8;
    // boundary zeros: row 0 (29) + col 0 rows 1..28 (28) per plane
    for (int i = tid; i < 8 * 57; i += 256) {
      int q = i / 57, e = i - q * 57;
      I[q][(e < 29) ? e : (e - 28) * 29] = 0.f;
    }
    // scan: half-wave (32 lanes) per plane; lane c<28 owns column c.
    {
      const int w = tid >> 6, lane = tid & 63;
      const int hl = lane >> 5, c = lane & 31;
      const int pp = w * 2 + hl;
      if (c < 28) {
        const float* sp = srcb + (size_t)pp * 784;
        float run = 0.f;
        for (int r = 0; r < 28; ++r) {
          float v = sp[r * 28 + c];
#pragma unroll
          for (int d = 1; d < 28; d <<= 1) {
            float tt = __shfl_up(v, d, 32);
            if (c >= d) v += tt;
          }
          run += v;  // run = inclusive 2D prefix at (r, c)
          I[pp][(r + 1) * 29 + c + 1] = run;
        }
      }
    }
    __syncthreads();
    // box sums: 12 lookups per (plane, pixel); 16B store covers 8 planes
    for (int j = tid; j < 784; j += 256) {
      int r = j / 28, c = j - (j / 28) * 28;
      int r0[3], r1[3], c0[3], c1[3];
#pragma unroll
      for (int pk = 1; pk <= 3; ++pk) {
        r0[pk - 1] = max(r - pk, 0) * 29;
        r1[pk - 1] = (min(r + pk, 27) + 1) * 29;
        c0[pk - 1] = max(c - pk, 0);
        c1[pk - 1] = min(c + pk, 27) + 1;
      }
      unsigned int u[4];
#pragma unroll
      for (int q = 0; q < 4; ++q) {
        float vv[2];
#pragma unroll
        for (int tt = 0; tt < 2; ++tt) {
          const float* Ip = I[q * 2 + tt];
          float acc = 0.f;
#pragma unroll
          for (int k = 0; k < 3; ++k) {
            float s = Ip[r1[k] + c1[k]] - Ip[r0[k] + c1[k]] - Ip[r1[k] + c0[k]] + Ip[r0[k] + c0[k]];
            acc += s * ((k == 0) ? (1.f / 9.f) : (k == 1) ? (1.f / 25.f) : (1.f / 49.f));
          }
          vv[tt] = acc;
        }
        u[q] = (unsigned int)b2u(vv[0]) | ((unsigned int)b2u(vv[1]) << 16);
      }
      *reinterpret_cast<uint4*>(drow + (size_t)j * 512) = make_uint4(u[0], u[1], u[2], u[3]);
    }
  }
}

// ---------------------------------------------------------------- lnrow + q_mfma (merged)
// blocks [0,100): q_mfma (bx=blk&3, by=blk>>2); [100,12644): row LayerNorm.
__global__ __launch_bounds__(256) void ln_q_kernel(const bf16* __restrict__ pooledT,
                                                   const float* __restrict__ gamma,
                                                   const float* __restrict__ beta,
                                                   bf16* __restrict__ yln,
                                                   const bf16* __restrict__ A,
                                                   const bf16* __restrict__ Bt,
                                                   bf16* __restrict__ Qb) {
  __shared__ __align__(16) bf16 As[128 * 32];
  __shared__ __align__(16) bf16 Bs[128 * 32];
  const int blk = blockIdx.x;
  const int tid = threadIdx.x;
  if (blk < 100) {
    const int lane = tid & 63;
    const int w = tid >> 6, wr = w >> 1, wc = w & 1;
    const int m0 = (blk >> 2) * 128, n0 = (blk & 3) * 128;
    f32x4 acc[4][4];
#pragma unroll
    for (int m = 0; m < 4; ++m)
#pragma unroll
      for (int n = 0; n < 4; ++n) acc[m][n] = f32x4{0.f, 0.f, 0.f, 0.f};
    const int s0 = tid, s1 = tid + 256;
    const bf16* Ag0 = A + (size_t)(m0 + (s0 >> 2)) * 512 + (s0 & 3) * 8;
    const bf16* Ag1 = A + (size_t)(m0 + (s1 >> 2)) * 512 + (s1 & 3) * 8;
    const bf16* Bg0 = Bt + (size_t)(n0 + (s0 >> 2)) * 512 + (s0 & 3) * 8;
    const bf16* Bg1 = Bt + (size_t)(n0 + (s1 >> 2)) * 512 + (s1 & 3) * 8;
    bf16* Al0 = As + s0 * 8;
    bf16* Al1 = As + s1 * 8;
    bf16* Bl0 = Bs + s0 * 8;
    bf16* Bl1 = Bs + s1 * 8;
    const int fr = lane & 15;
    const int ko = (lane >> 4) * 8;
    const int rh = lane >> 4;
    for (int k0 = 0; k0 < 512; k0 += 32) {
      GLD_LDS16(Ag0 + k0, Al0);
      GLD_LDS16(Ag1 + k0, Al1);
      GLD_LDS16(Bg0 + k0, Bl0);
      GLD_LDS16(Bg1 + k0, Bl1);
      __syncthreads();
      bf16x8 af[4], bfr[4];
#pragma unroll
      for (int m = 0; m < 4; ++m)
        af[m] = *reinterpret_cast<const bf16x8*>(As + (wr * 64 + m * 16 + fr) * 32 + ko);
#pragma unroll
      for (int n = 0; n < 4; ++n)
        bfr[n] = *reinterpret_cast<const bf16x8*>(Bs + (wc * 64 + n * 16 + fr) * 32 + ko);
#pragma unroll
      for (int m = 0; m < 4; ++m)
#pragma unroll
        for (int n = 0; n < 4; ++n)
          acc[m][n] = __builtin_amdgcn_mfma_f32_16x16x32_bf16(af[m], bfr[n], acc[m][n], 0, 0, 0);
      __syncthreads();
    }
#pragma unroll
    for (int m = 0; m < 4; ++m) {
#pragma unroll
      for (int n = 0; n < 4; ++n) {
        int col = n0 + wc * 64 + n * 16 + fr;  // 0..511: h=col>>6, d=col&63
        const size_t cbase = ((size_t)(col >> 6)) * (49 * 64) + (col & 63);
#pragma unroll
        for (int r = 0; r < 4; ++r) {
          int row = m0 + wr * 64 + m * 16 + rh * 4 + r;
          if (row < 3136) {
            int b = row / 49, rr = row - (row / 49) * 49;
            Qb[((size_t)b * 8) * (49 * 64) + cbase + (size_t)rr * 64] = __float2bfloat16(acc[m][n][r]);
          }
        }
      }
    }
  } else {
    const int row = (blk - 100) * 4 + (tid >> 6);
    const int lane = tid & 63;
    bf16x8 raw = *reinterpret_cast<const bf16x8*>(pooledT + (size_t)row * 512 + lane * 8);
    float v[8];
    float s = 0.f, s2 = 0.f;
#pragma unroll
    for (int j = 0; j < 8; ++j) {
      v[j] = u2f(raw[j]);
      s += v[j];
      s2 += v[j] * v[j];
    }
#pragma unroll
    for (int off = 32; off; off >>= 1) {
      s += __shfl_xor(s, off, 64);
      s2 += __shfl_xor(s2, off, 64);
    }
    float mu = s * (1.f / 512.f);
    float rs = rsqrtf(s2 * (1.f / 512.f) - mu * mu + 1e-5f);
    float4 g0 = *reinterpret_cast<const float4*>(gamma + lane * 8);
    float4 g1 = *reinterpret_cast<const float4*>(gamma + lane * 8 + 4);
    float4 e0 = *reinterpret_cast<const float4*>(beta + lane * 8);
    float4 e1 = *reinterpret_cast<const float4*>(beta + lane * 8 + 4);
    float gg[8] = {g0.x, g0.y, g0.z, g0.w, g1.x, g1.y, g1.z, g1.w};
    float bb[8] = {e0.x, e0.y, e0.z, e0.w, e1.x, e1.y, e1.z, e1.w};
    unsigned int u[4];
#pragma unroll
    for (int q = 0; q < 4; ++q) {
      float o0 = (v[2 * q] - mu) * rs * gg[2 * q] + bb[2 * q];
      float o1 = (v[2 * q + 1] - mu) * rs * gg[2 * q + 1] + bb[2 * q + 1];
      u[q] = (unsigned int)b2u(o0) | ((unsigned int)b2u(o1) << 16);
    }
    *reinterpret_cast<uint4*>(yln + (size_t)row * 512 + lane * 8) =
        make_uint4(u[0], u[1], u[2], u[3]);
  }
}

// ---------------------------------------------------------------- kv MFMA GEMM
__global__ __launch_bounds__(256) void kv_mfma(const bf16* __restrict__ A,
                                               const bf16* __restrict__ Bt,
                                               bf16* __restrict__ Kb, bf16* __restrict__ Vt) {
  extern __shared__ __align__(16) bf16 smem[];  // 18432 B dynamic
  bf16* As = smem;                              // [128*32]
  bf16* Bs = smem + 128 * 32;                   // [128*32]
  const int tid = threadIdx.x;
  const int lane = tid & 63;
  const int w = tid >> 6, wr = w >> 1, wc = w & 1;

  // XCD swizzle: XCD c handles y-tiles [c*49, c*49+49), all 8 x-tiles (A-tile L2 reuse)
  const int lin = blockIdx.y * 8 + blockIdx.x;
  const int c8 = lin & 7, j = lin >> 3;
  const int ex = j & 7, ey = c8 * 49 + (j >> 3);
  const int m0 = ey * 128, n0 = ex * 128;

  f32x4 acc[4][4];
#pragma unroll
  for (int m = 0; m < 4; ++m)
#pragma unroll
    for (int n = 0; n < 4; ++n) acc[m][n] = f32x4{0.f, 0.f, 0.f, 0.f};

  const int s0 = tid, s1 = tid + 256;  // 16B segments; seg s: row=s>>2, koff=(s&3)*8
  const bf16* Ag0 = A + (size_t)(m0 + (s0 >> 2)) * 512 + (s0 & 3) * 8;
  const bf16* Ag1 = A + (size_t)(m0 + (s1 >> 2)) * 512 + (s1 & 3) * 8;
  const bf16* Bg0 = Bt + (size_t)(n0 + (s0 >> 2)) * 512 + (s0 & 3) * 8;
  const bf16* Bg1 = Bt + (size_t)(n0 + (s1 >> 2)) * 512 + (s1 & 3) * 8;
  bf16* Al0 = As + s0 * 8;
  bf16* Al1 = As + s1 * 8;
  bf16* Bl0 = Bs + s0 * 8;
  bf16* Bl1 = Bs + s1 * 8;

  const int fr = lane & 15;        // fragment row/col within 16
  const int ko = (lane >> 4) * 8;  // k offset within 32
  const int rh = lane >> 4;

  for (int k0 = 0; k0 < 512; k0 += 32) {
    GLD_LDS16(Ag0 + k0, Al0);
    GLD_LDS16(Ag1 + k0, Al1);
    GLD_LDS16(Bg0 + k0, Bl0);
    GLD_LDS16(Bg1 + k0, Bl1);
    __syncthreads();  // vmcnt drained before barrier
    bf16x8 af[4], bfr[4];
#pragma unroll
    for (int m = 0; m < 4; ++m)
      af[m] = *reinterpret_cast<const bf16x8*>(As + (wr * 64 + m * 16 + fr) * 32 + ko);
#pragma unroll
    for (int n = 0; n < 4; ++n)
      bfr[n] = *reinterpret_cast<const bf16x8*>(Bs + (wc * 64 + n * 16 + fr) * 32 + ko);
#pragma unroll
    for (int m = 0; m < 4; ++m)
#pragma unroll
      for (int n = 0; n < 4; ++n)
        acc[m][n] = __builtin_amdgcn_mfma_f32_16x16x32_bf16(af[m], bfr[n], acc[m][n], 0, 0, 0);
    __syncthreads();
  }

  if (n0 < 512) {
    // ---- K epilogue: coalesced [b,h,m,d] writes
#pragma unroll
    for (int m = 0; m < 4; ++m) {
#pragma unroll
      for (int n = 0; n < 4; ++n) {
        int col = n0 + wc * 64 + n * 16 + fr;
        const size_t cbase = ((size_t)(col >> 6)) * (784 * 64) + (col & 63);
#pragma unroll
        for (int r = 0; r < 4; ++r) {
          int row = m0 + wr * 64 + m * 16 + rh * 4 + r;
          int b = row / 784, n1 = row - (row / 784) * 784;
          Kb[((size_t)b * 8) * (784 * 64) + cbase + (size_t)n1 * 64] = __float2bfloat16(acc[m][n][r]);
        }
      }
    }
  } else {
    // ---- V epilogue: LDS-staged transpose -> Vt [b*8+h][d][800]
    bf16* stage = smem;  // [128 cols][72 rows-padded]
#pragma unroll
    for (int p = 0; p < 2; ++p) {
      __syncthreads();
      if (wr == p) {
#pragma unroll
        for (int m = 0; m < 4; ++m) {
#pragma unroll
          for (int n = 0; n < 4; ++n) {
            int coll = wc * 64 + n * 16 + fr;
            int rowl = m * 16 + rh * 4;
            unsigned int u0 = (unsigned int)b2u(acc[m][n][0]) | ((unsigned int)b2u(acc[m][n][1]) << 16);
            unsigned int u1 = (unsigned int)b2u(acc[m][n][2]) | ((unsigned int)b2u(acc[m][n][3]) << 16);
            *reinterpret_cast<uint2*>(stage + coll * 72 + rowl) = make_uint2(u0, u1);
          }
        }
      }
      __syncthreads();
      const int rbase = m0 + p * 64;
      for (int i = tid; i < 1024; i += 256) {
        int cc = i >> 3, tc = i & 7;
        int colg = n0 + cc;  // >= 512
        int h = (colg >> 6) & 7, d = colg & 63;
        int rs = rbase + tc * 8;
        int b = rs / 784, n1 = rs - b * 784;
        bf16x8 val = *reinterpret_cast<const bf16x8*>(stage + cc * 72 + tc * 8);
        bf16* dst = Vt + (((size_t)b * 8 + h) * 64 + d) * 800 + n1;
        if (n1 <= 776) {
          *reinterpret_cast<bf16x8*>(dst) = val;
        } else {
#pragma unroll
          for (int jj = 0; jj < 8; ++jj) {
            int rr = rs + jj;
            int bb2 = rr / 784, nn1 = rr - bb2 * 784;
            bf16 hv;
            *reinterpret_cast<short*>(&hv) = val[jj];
            Vt[(((size_t)bb2 * 8 + h) * 64 + d) * 800 + nn1] = hv;
          }
        }
      }
    }
  }
}

// ---------------------------------------------------------------- proj MFMA GEMM
__global__ __launch_bounds__(256) void proj_mfma(const bf16* __restrict__ A,
                                                 const bf16* __restrict__ Bt,
                                                 const float* __restrict__ bias,
                                                 float* __restrict__ out) {
  __shared__ __align__(16) bf16 As[128 * 32];
  __shared__ __align__(16) bf16 Bs[128 * 32];
  const int tid = threadIdx.x;
  const int lane = tid & 63;
  const int w = tid >> 6, wr = w >> 1, wc = w & 1;
  const int m0 = blockIdx.y * 128, n0 = blockIdx.x * 128;

  f32x4 acc[4][4];
#pragma unroll
  for (int m = 0; m < 4; ++m)
#pragma unroll
    for (int n = 0; n < 4; ++n) acc[m][n] = f32x4{0.f, 0.f, 0.f, 0.f};

  const int s0 = tid, s1 = tid + 256;
  const bf16* Ag0 = A + (size_t)(m0 + (s0 >> 2)) * 1024 + (s0 & 3) * 8;
  const bf16* Ag1 = A + (size_t)(m0 + (s1 >> 2)) * 1024 + (s1 & 3) * 8;
  const bf16* Bg0 = Bt + (size_t)(n0 + (s0 >> 2)) * 512 + (s0 & 3) * 8;
  const bf16* Bg1 = Bt + (size_t)(n0 + (s1 >> 2)) * 512 + (s1 & 3) * 8;
  bf16* Al0 = As + s0 * 8;
  bf16* Al1 = As + s1 * 8;
  bf16* Bl0 = Bs + s0 * 8;
  bf16* Bl1 = Bs + s1 * 8;

  const int fr = lane & 15;
  const int ko = (lane >> 4) * 8;
  const int rh = lane >> 4;

  for (int k0 = 0; k0 < 1024; k0 += 32) {
    GLD_LDS16(Ag0 + k0, Al0);
    GLD_LDS16(Ag1 + k0, Al1);
    GLD_LDS16(Bg0 + (k0 & 511), Bl0);
    GLD_LDS16(Bg1 + (k0 & 511), Bl1);
    __syncthreads();
    bf16x8 af[4], bfr[4];
#pragma unroll
    for (int m = 0; m < 4; ++m)
      af[m] = *reinterpret_cast<const bf16x8*>(As + (wr * 64 + m * 16 + fr) * 32 + ko);
#pragma unroll
    for (int n = 0; n < 4; ++n)
      bfr[n] = *reinterpret_cast<const bf16x8*>(Bs + (wc * 64 + n * 16 + fr) * 32 + ko);
#pragma unroll
    for (int m = 0; m < 4; ++m)
#pragma unroll
      for (int n = 0; n < 4; ++n)
        acc[m][n] = __builtin_amdgcn_mfma_f32_16x16x32_bf16(af[m], bfr[n], acc[m][n], 0, 0, 0);
    __syncthreads();
  }

#pragma unroll
  for (int m = 0; m < 4; ++m) {
#pragma unroll
    for (int n = 0; n < 4; ++n) {
      int col = n0 + wc * 64 + n * 16 + fr;
      float bv = bias[col];
#pragma unroll
      for (int r = 0; r < 4; ++r) {
        int row = m0 + wr * 64 + m * 16 + rh * 4 + r;
        if (row < 3136) {
          int b = row / 49, rr = row - (row / 49) * 49;
          out[((size_t)b * 512 + col) * 49 + rr] = acc[m][n][r] + bv;
        }
      }
    }
  }
}

// ---------------------------------------------------------------- attention
// one block = (b,h, chunk of 7 q-rows). MFMA QK^T + MFMA PV with register
// load queues; float-domain bisection top-k; sW aliases sLog (row stride 786
// f32 -> row offset = 8 banks mod 32, breaking the 4-way store conflict).
__global__ __launch_bounds__(256, 7) void attn_kernel(const bf16* __restrict__ Qb,
                                                      const bf16* __restrict__ K,
                                                      const bf16* __restrict__ Vt,
                                                      const float* __restrict__ aw1p,
                                                      const float* __restrict__ aw2p,
                                                      bf16* __restrict__ aoutHL) {
  // XCD swizzle: 3584 = 8*448; XCD c gets wk in [c*448,(c+1)*448) => bh in [c*64,(c+1)*64)
  const int lin = blockIdx.x;
  const int wk = (lin & 7) * 448 + (lin >> 3);
  const int bh = wk / 7;
  const int chunk = wk - bh * 7;
  const int b = bh >> 3, h = bh & 7;
  const int r0 = chunk * 7;
  const int tid = threadIdx.x;
  const int lane = tid & 63, w = tid >> 6;
  __shared__ __align__(16) unsigned char sMem[22008];  // union: sLog f32[7][786] / sW bf16[8][808]
  float* sLog = reinterpret_cast<float*>(sMem);
  bf16* sW = reinterpret_cast<bf16*>(sMem);
  // LDS ~22.0 KB -> 7 blocks/CU

  const int fr = lane & 15, ko = (lane >> 4) * 8, rh = lane >> 4;

  // ---- Q fragment: direct global load, row clamped (rows 7..15 garbage-OK)
  const bf16* Qp = Qb + ((size_t)bh * 49 + r0) * 64;
  const int qrow = (fr < 7) ? fr : 6;
  const bf16x8 aq0 = *reinterpret_cast<const bf16x8*>(Qp + qrow * 64 + ko);
  const bf16x8 aq1 = *reinterpret_cast<const bf16x8*>(Qp + qrow * 64 + 32 + ko);

  // ---- QK^T via MFMA with a 4-deep K register queue
  const bf16* Kp = K + (size_t)bh * (784 * 64);
  {
    const int rbase = rh * 4;
    const bf16* kbase = Kp + (size_t)fr * 64 + ko;
    bf16x8 kq0[4], kq1[4];
#pragma unroll
    for (int s = 0; s < 4; ++s) {
      int nt = w + s * 4;
      int ntc = nt < 49 ? nt : 48;
      const bf16* kr = kbase + (size_t)ntc * 1024;
      kq0[s] = *reinterpret_cast<const bf16x8*>(kr);
      kq1[s] = *reinterpret_cast<const bf16x8*>(kr + 32);
    }
#pragma unroll
    for (int i = 0; i < 13; ++i) {
      const int s = i & 3;
      const int nt = w + i * 4;
      if (nt < 49) {
        f32x4 acc = {0.f, 0.f, 0.f, 0.f};
        acc = __builtin_amdgcn_mfma_f32_16x16x32_bf16(aq0, kq0[s], acc, 0, 0, 0);
        acc = __builtin_amdgcn_mfma_f32_16x16x32_bf16(aq1, kq1[s], acc, 0, 0, 0);
#pragma unroll
        for (int r = 0; r < 4; ++r) {
          int row = rbase + r;
          if (row < 7) sLog[row * 786 + nt * 16 + fr] = acc[r] * 0.125f;
        }
      }
      const int ntn = w + (i + 4) * 4;
      if (ntn < 49) {
        const bf16* kr = kbase + (size_t)ntn * 1024;
        kq0[s] = *reinterpret_cast<const bf16x8*>(kr);
        kq1[s] = *reinterpret_cast<const bf16x8*>(kr + 32);
      }
    }
  }
  __syncthreads();

  // ---- load logits for this wave's two rows into registers
  const int ra = w;
  const int rb = (w + 4 < 7) ? (w + 4) : w;  // wave 3 duplicates its row (benign)
  float va[13], vb[13];
#pragma unroll
  for (int i = 0; i < 13; ++i) {
    int m = lane + i * 64;
    va[i] = (m < 784) ? sLog[ra * 786 + m] : -INFINITY;
    vb[i] = (m < 784) ? sLog[rb * 786 + m] : -INFINITY;
  }
  __syncthreads();  // sLog fully consumed; sW aliasing writes may begin

  // row max
  float mxa = va[0], mxb = vb[0];
#pragma unroll
  for (int i = 1; i < 13; ++i) {
    mxa = fmaxf(mxa, va[i]);
    mxb = fmaxf(mxb, vb[i]);
  }
#pragma unroll
  for (int off = 32; off; off >>= 1) {
    mxa = fmaxf(mxa, __shfl_xor(mxa, off, 64));
    mxb = fmaxf(mxb, __shfl_xor(mxb, off, 64));
  }

  // ---- 4 bisection chains in key space, compares in the float domain.
  // v >= unkey(cand) <=> key(v) >= cand (monotone bijection on finite floats).
  // Early exit when count==k is exact; ties fall to full bisection -> >= kth
  // semantics identical to reference.
  unsigned int t1a = 0u, t2a = 0u, t1b = 0u, t2b = 0u;
  bool d1a = false, d2a = false, d1b = false, d2b = false;
  for (int bit = 31; bit >= 0; --bit) {
    const unsigned int mb = 1u << bit;
    if (!d1a) {
      float cf = unkey(t1a | mb);
      int n = 0;
#pragma unroll
      for (int i = 0; i < 13; ++i) n += __popcll(__ballot(va[i] >= cf));
      if (n >= 392) { t1a |= mb; d1a = (n == 392); }
    }
    if (!d2a) {
      float cf = unkey(t2a | mb);
      int n = 0;
#pragma unroll
      for (int i = 0; i < 13; ++i) n += __popcll(__ballot(va[i] >= cf));
      if (n >= 261) { t2a |= mb; d2a = (n == 261); }
    }
    if (!d1b) {
      float cf = unkey(t1b | mb);
      int n = 0;
#pragma unroll
      for (int i = 0; i < 13; ++i) n += __popcll(__ballot(vb[i] >= cf));
      if (n >= 392) { t1b |= mb; d1b = (n == 392); }
    }
    if (!d2b) {
      float cf = unkey(t2b | mb);
      int n = 0;
#pragma unroll
      for (int i = 0; i < 13; ++i) n += __popcll(__ballot(vb[i] >= cf));
      if (n >= 261) { t2b |= mb; d2b = (n == 261); }
    }
    if (d1a & d2a & d1b & d2b) break;
  }
  const float T1a = unkey(t1a), T2a = unkey(t2a);
  const float T1b = unkey(t1b), T2b = unkey(t2b);

  // ---- fused exp + z + weights (e kept in registers)
  const float aw1 = aw1p[0], aw2 = aw2p[0];
  float ea[13], eb[13];
  float z1a = 0.f, z2a = 0.f, z1b = 0.f, z2b = 0.f;
#pragma unroll
  for (int i = 0; i < 13; ++i) {
    ea[i] = __expf(va[i] - mxa);  // pads: exp(-inf)=0
    eb[i] = __expf(vb[i] - mxb);
    if (va[i] >= T1a) z1a += ea[i];
    if (va[i] >= T2a) z2a += ea[i];
    if (vb[i] >= T1b) z1b += eb[i];
    if (vb[i] >= T2b) z2b += eb[i];
  }
#pragma unroll
  for (int off = 32; off; off >>= 1) {
    z1a += __shfl_xor(z1a, off, 64);
    z2a += __shfl_xor(z2a, off, 64);
    z1b += __shfl_xor(z1b, off, 64);
    z2b += __shfl_xor(z2b, off, 64);
  }
  const float a1a = aw1 / z1a, a2a = aw2 / z2a;
  const float a1b = aw1 / z1b, a2b = aw2 / z2b;
#pragma unroll
  for (int i = 0; i < 13; ++i) {
    int m = lane + i * 64;
    if (m < 784) {
      float wa = ea[i] * (((va[i] >= T1a) ? a1a : 0.f) + ((va[i] >= T2a) ? a2a : 0.f));
      sW[ra * 808 + m] = __float2bfloat16(wa);
      float wb = eb[i] * (((vb[i] >= T1b) ? a1b : 0.f) + ((vb[i] >= T2b) ? a2b : 0.f));
      sW[rb * 808 + m] = __float2bfloat16(wb);
    }
  }
  if (lane < 16) {
    sW[ra * 808 + 784 + lane] = __float2bfloat16(0.f);
    sW[rb * 808 + 784 + lane] = __float2bfloat16(0.f);
  }

  // ---- PV V-queue prefetch issued BEFORE the barrier (latency hides under it)
  const bf16* vbase = Vt + ((size_t)bh * 64 + w * 16 + fr) * 800;
  bf16x8 vq[4];
#pragma unroll
  for (int s = 0; s < 4; ++s)
    vq[s] = *reinterpret_cast<const bf16x8*>(vbase + s * 32 + ko);
  __syncthreads();

  // ---- PV via MFMA: out[16][64] = W[16][800] x V^T; wave w owns d-tile w*16..
  // A rows 7..15 clamped to row 7 (allocated; may be garbage -> C rows >=7
  // discarded). Two accumulator chains halve the dependent-MFMA latency.
  const bf16* wrow = sW + ((fr < 7) ? fr : 7) * 808;
  f32x4 acc0 = {0.f, 0.f, 0.f, 0.f}, acc1 = {0.f, 0.f, 0.f, 0.f};
#pragma unroll
  for (int ks = 0; ks < 25; ++ks) {
    const int s = ks & 3;
    bf16x8 a = *reinterpret_cast<const bf16x8*>(wrow + ks * 32 + ko);
    if (ks & 1)
      acc1 = __builtin_amdgcn_mfma_f32_16x16x32_bf16(a, vq[s], acc1, 0, 0, 0);
    else
      acc0 = __builtin_amdgcn_mfma_f32_16x16x32_bf16(a, vq[s], acc0, 0, 0, 0);
    if (ks + 4 < 25)
      vq[s] = *reinterpret_cast<const bf16x8*>(vbase + (ks + 4) * 32 + ko);
  }
  acc0 += acc1;
#pragma unroll
  for (int r = 0; r < 4; ++r) {
    int row = rh * 4 + r;
    if (row < 7) {
      float v = acc0[r];
      bf16 hi = __float2bfloat16(v);
      bf16 lo = __float2bfloat16(v - __bfloat162float(hi));
      size_t base = ((size_t)(b * 49 + r0 + row)) * 1024 + h * 64 + w * 16 + fr;
      aoutHL[base] = hi;
      aoutHL[base + 512] = lo;
    }
  }
}

// ---------------------------------------------------------------- launch
extern "C" void kernel_launch(void* const* d_in, const int* in_sizes, int n_in, void* d_out,
                              int out_size, void* d_ws, size_t ws_size, hipStream_t stream) {
  const float* x = (const float*)d_in[0];
  const float* y = (const float*)d_in[1];
  const float* Wq = (const float*)d_in[2];
  const float* Wkv = (const float*)d_in[3];
  const float* Wproj = (const float*)d_in[4];
  const float* bproj = (const float*)d_in[5];
  const float* gamma = (const float*)d_in[6];
  const float* beta = (const float*)d_in[7];
  const float* aw1 = (const float*)d_in[8];
  const float* aw2 = (const float*)d_in[9];
  float* out = (float*)d_out;

  char* w = (char*)d_ws;
  const size_t SZ = 51380224ull;    // 64*784*512*2 bytes
  const size_t SZV = 52428800ull;   // 64*8*64*800*2 bytes (V^T, padded stride 800)
  bf16* pooledT = (bf16*)(w);       // [50176][512]; dead after lnrow
  bf16* yln = (bf16*)(w + SZ);      // [50176][512]; dead after kv gemm
  bf16* Kb = (bf16*)(w);            // reuses pooledT slot (after lnrow)
  bf16* Vt = (bf16*)(w + 2 * SZ);
  size_t off = 2 * SZ + SZV;
  bf16* xsTb = (bf16*)(w + off);    off += 3276800;   // [3200][512] bf16 (64 pad rows)
  bf16* Qb = (bf16*)(w + off);      off += 3276800;   // [B,8,49,64] bf16
  bf16* aoutHL = (bf16*)(w + off);  off += 6553600;   // [3200][1024] bf16 (hi|lo)
  bf16* wkvT = (bf16*)(w + off);    off += 1048576;   // [1024][512] bf16
  bf16* wqT = (bf16*)(w + off);     off += 524288;    // [512][512] bf16
  bf16* wpT = (bf16*)(w + off);     off += 524288;    // [512][512] bf16
  // peak ws use: ~170.4 MB

  prep_pool_kernel<<<dim3(13440), dim3(256), 0, stream>>>(Wkv, Wq, Wproj, x, y, wkvT, wqT, wpT,
                                                          xsTb, Vt, pooledT);
  ln_q_kernel<<<dim3(12644), dim3(256), 0, stream>>>(pooledT, gamma, beta, yln, xsTb, wqT, Qb);
  kv_mfma<<<dim3(8, 392), dim3(256), 18432, stream>>>(yln, wkvT, Kb, Vt);
  attn_kernel<<<dim3(3584), dim3(256), 0, stream>>>(Qb, Kb, Vt, aw1, aw2, aoutHL);
  proj_mfma<<<dim3(4, 25), dim3(256), 0, stream>>>(aoutHL, wpT, bproj, out);
}